// Round 1
// baseline (2063.004 us; speedup 1.0000x reference)
//
#include <hip/hip_runtime.h>
#include <hip/hip_bf16.h>

typedef __hip_bfloat16 bf16;

#define DD   512
#define NT   1536
#define NH   4
#define DHD  128
#define NBINS 100
#define MAXI 5
#define NL   3
#define RSQRT_DH 0.08838834764831845f   // 1/sqrt(128)

// ---- workspace layout (float offsets) ----
#define OFF_X      ((size_t)0)
#define OFF_QKV    (OFF_X    + (size_t)NT*DD)        // N x 3D
#define OFF_ATT    (OFF_QKV  + (size_t)NT*3*DD)      // attn_out N x D
#define OFF_CTX    (OFF_ATT  + (size_t)NT*DD)        // pre-out-proj ctx
#define OFF_K2     (OFF_CTX  + (size_t)NT*DD)
#define OFF_QP0    (OFF_K2   + (size_t)NT*DD)
#define OFF_Q0     (OFF_QP0  + (size_t)NT*DD)
#define OFF_H0     (OFF_Q0   + (size_t)NT*DD)        // N x 384 (3 layers x 128)
#define OFF_HR     (OFF_H0   + (size_t)NT*384)       // 5 x N x 128
#define OFF_LG     (OFF_HR   + (size_t)MAXI*NT*128)  // 7680 x 200
#define OFF_AARR   (OFF_LG   + (size_t)MAXI*NT*200)  // H x N
#define OFF_BARR   (OFF_AARR + (size_t)NH*NT)
#define OFF_AV     (OFF_BARR + (size_t)NH*NT)        // D
#define OFF_BV     (OFF_AV   + (size_t)DD)
#define OFF_SOFF   (OFF_BV   + (size_t)DD)           // 5 x N
#define OFF_EOFF   (OFF_SOFF + (size_t)MAXI*NT)
#define OFF_RST    (OFF_EOFF + (size_t)MAXI*NT)      // H*N x 2 (max, 1/den)
#define OFF_POOL   (OFF_RST  + (size_t)NH*NT*2)      // D
#define OFF_SCAL   (OFF_POOL + (size_t)DD)           // 64 scalars
#define OFF_S      (OFF_SCAL + (size_t)64)           // bf16 region H*N*N (counted as H*N*N/2 floats)
// scalar indices within OFF_SCAL
#define SC_START 0
#define SC_END   5
#define SC_DSDE  10
#define SC_TMIN  20
#define SC_TMAX  21

// -------------------------------------------------------------------------
__global__ void k_init(float* ws) {
    int i = blockIdx.x * 256 + threadIdx.x;
    if (i < DD) ws[OFF_POOL + i] = 0.f;
}

__global__ void k_tgrid(const float* __restrict__ t, float* ws) {
    __shared__ float smn[256], smx[256];
    int tid = threadIdx.x;
    float mn = 1e30f, mx = -1e30f;
    for (int i = tid; i < NT; i += 256) { float v = t[i]; mn = fminf(mn, v); mx = fmaxf(mx, v); }
    smn[tid] = mn; smx[tid] = mx; __syncthreads();
    for (int s = 128; s; s >>= 1) {
        if (tid < s) { smn[tid] = fminf(smn[tid], smn[tid + s]); smx[tid] = fmaxf(smx[tid], smx[tid + s]); }
        __syncthreads();
    }
    if (tid == 0) {
        float tmin = smn[0], tmax = smx[0];
        ws[OFF_SCAL + SC_TMIN] = tmin; ws[OFF_SCAL + SC_TMAX] = tmax;
        for (int i = 0; i < MAXI; i++) {
            ws[OFF_SCAL + SC_START + i] = tmin + (tmax - tmin) * (float)i / 5.0f;
            ws[OFF_SCAL + SC_END + i]   = tmin + (tmax - tmin) * (float)(i + 1) / 5.0f;
        }
    }
}

__global__ void k_x(const float* __restrict__ emb, const float* __restrict__ t,
                    const float* __restrict__ wt, const float* __restrict__ bt, float* ws) {
    int idx = blockIdx.x * 256 + threadIdx.x;  // < NT*DD
    int n = idx >> 9, j = idx & 511;
    ws[OFF_X + idx] = emb[idx] + t[n] * wt[j] + bt[j];
}

// C[M,Ncol] = alpha * A[M,K] @ B[Ncol,K]^T (+ bias), optional per-z offsets, optional bf16 out
template <int BF16OUT>
__global__ __launch_bounds__(256) void k_gemm_nt(
    const float* __restrict__ A, int lda, int aZ,
    const float* __restrict__ B, int ldb, int bZ,
    void* __restrict__ Cv, int ldc, long long cZ,
    int M, int Ncol, int K, float alpha, const float* __restrict__ bias)
{
    int z = blockIdx.z;
    A += (size_t)z * aZ; B += (size_t)z * bZ;
    int tid = threadIdx.x;
    int m0 = blockIdx.y * 64, n0 = blockIdx.x * 64;
    __shared__ __align__(16) float As[16][68];
    __shared__ __align__(16) float Bs[16][68];
    float acc[4][4] = {};
    int ty = tid >> 4, tx = tid & 15;
    for (int k0 = 0; k0 < K; k0 += 16) {
#pragma unroll
        for (int i = 0; i < 4; i++) {
            int idx = tid + 256 * i;
            int mm = idx >> 4, kk = idx & 15;
            int gm = m0 + mm;
            As[kk][mm] = (gm < M) ? A[(size_t)gm * lda + k0 + kk] : 0.f;
            int gn = n0 + mm;
            Bs[kk][mm] = (gn < Ncol) ? B[(size_t)gn * ldb + k0 + kk] : 0.f;
        }
        __syncthreads();
#pragma unroll
        for (int kk = 0; kk < 16; kk++) {
            float4 a4 = *(const float4*)&As[kk][ty * 4];
            float4 b4 = *(const float4*)&Bs[kk][tx * 4];
            float av_[4] = {a4.x, a4.y, a4.z, a4.w};
            float bv_[4] = {b4.x, b4.y, b4.z, b4.w};
#pragma unroll
            for (int ii = 0; ii < 4; ii++)
#pragma unroll
                for (int jj = 0; jj < 4; jj++) acc[ii][jj] += av_[ii] * bv_[jj];
        }
        __syncthreads();
    }
#pragma unroll
    for (int ii = 0; ii < 4; ii++) {
        int gm = m0 + ty * 4 + ii;
        if (gm >= M) continue;
#pragma unroll
        for (int jj = 0; jj < 4; jj++) {
            int gn = n0 + tx * 4 + jj;
            if (gn >= Ncol) continue;
            float v = acc[ii][jj] * alpha + (bias ? bias[gn] : 0.f);
            if (BF16OUT) ((bf16*)Cv)[cZ * z + (size_t)gm * ldc + gn] = __float2bfloat16(v);
            else         ((float*)Cv)[cZ * z + (size_t)gm * ldc + gn] = v;
        }
    }
}

// per-row softmax stats over bf16 score matrix (H*N rows, NT cols)
__global__ __launch_bounds__(256) void k_rstats(const bf16* __restrict__ S, float* ws) {
    int wave = threadIdx.x >> 6, lane = threadIdx.x & 63;
    int row = blockIdx.x * 4 + wave;  // < NH*NT
    const bf16* p = S + (size_t)row * NT;
    float v[24], m = -1e30f;
#pragma unroll
    for (int t = 0; t < 24; t++) { v[t] = __bfloat162float(p[t * 64 + lane]); m = fmaxf(m, v[t]); }
    for (int off = 32; off; off >>= 1) m = fmaxf(m, __shfl_xor(m, off));
    float s = 0.f;
#pragma unroll
    for (int t = 0; t < 24; t++) s += __expf(v[t] - m);
    for (int off = 32; off; off >>= 1) s += __shfl_xor(s, off);
    if (lane == 0) { ws[OFF_RST + 2 * row] = m; ws[OFF_RST + 2 * row + 1] = 1.f / s; }
}

// ctx[:, h*128:(h+1)*128] = softmax(S_h) @ V_h
__global__ __launch_bounds__(256) void k_av(float* ws, const bf16* __restrict__ S) {
    int h = blockIdx.z;
    int m0 = blockIdx.y * 32;
    __shared__ __align__(16) float Ws[32][36];
    __shared__ __align__(16) float Vs[32][132];
    int tid = threadIdx.x;
    int ty = tid >> 5, tx = tid & 31;
    float acc[4][4] = {};
    const bf16* Sh = S + (size_t)h * NT * NT;
    const float* rst = ws + OFF_RST;
    const float* qkv = ws + OFF_QKV;
    for (int k0 = 0; k0 < NT; k0 += 32) {
#pragma unroll
        for (int i = 0; i < 4; i++) {
            int idx = tid + 256 * i;
            int mm = idx >> 5, kk = idx & 31;
            int row = m0 + mm;
            float s = __bfloat162float(Sh[(size_t)row * NT + k0 + kk]);
            float mr = rst[2 * (h * NT + row)], ri = rst[2 * (h * NT + row) + 1];
            Ws[kk][mm] = __expf(s - mr) * ri;
        }
#pragma unroll
        for (int i = 0; i < 16; i++) {
            int idx = tid + 256 * i;
            int nn = idx & 127, kk = idx >> 7;
            Vs[kk][nn] = qkv[(size_t)(k0 + kk) * (3 * DD) + 2 * DD + h * DHD + nn];
        }
        __syncthreads();
#pragma unroll
        for (int kk = 0; kk < 32; kk++) {
            float4 a4 = *(const float4*)&Ws[kk][ty * 4];
            float4 b4 = *(const float4*)&Vs[kk][tx * 4];
            float av_[4] = {a4.x, a4.y, a4.z, a4.w};
            float bv_[4] = {b4.x, b4.y, b4.z, b4.w};
#pragma unroll
            for (int ii = 0; ii < 4; ii++)
#pragma unroll
                for (int jj = 0; jj < 4; jj++) acc[ii][jj] += av_[ii] * bv_[jj];
        }
        __syncthreads();
    }
    float* ctx = ws + OFF_CTX;
#pragma unroll
    for (int ii = 0; ii < 4; ii++) {
        int gm = m0 + ty * 4 + ii;
#pragma unroll
        for (int jj = 0; jj < 4; jj++)
            ctx[(size_t)gm * DD + h * DHD + tx * 4 + jj] = acc[ii][jj];
    }
}

__global__ void k_pool(float* ws) {
    int col = blockIdx.x * 256 + threadIdx.x;
    int r0 = blockIdx.y * 128;
    const float* att = ws + OFF_ATT;
    float s = 0.f;
    for (int r = 0; r < 128; r++) s += att[(size_t)(r0 + r) * DD + col];
    atomicAdd(&ws[OFF_POOL + col], s);
}

// pooled -> ic MLP -> argmax -> mask output (exact fp32, discrete path)
__global__ void k_head(const float* __restrict__ icw1, const float* __restrict__ icb1,
                       const float* __restrict__ icw2, const float* __restrict__ icb2,
                       float* ws, float* out) {
    __shared__ float h1[128];
    __shared__ float lg[MAXI];
    int tid = threadIdx.x;  // 128 threads
    float a = 0.f;
    for (int c = 0; c < DD; c++) a += icw1[(size_t)tid * DD + c] * ws[OFF_POOL + c];
    h1[tid] = fmaxf(a * (1.0f / NT) + icb1[tid], 0.f);
    __syncthreads();
    if (tid < MAXI) {
        float s = icb2[tid];
        for (int j = 0; j < 128; j++) s += icw2[tid * 128 + j] * h1[j];
        lg[tid] = s;
    }
    __syncthreads();
    if (tid == 0) {
        int best = 0; float bv = lg[0];
        for (int m = 1; m < MAXI; m++) if (lg[m] > bv) { bv = lg[m]; best = m; }
        int ni = best + 1;
        for (int i = 0; i < MAXI; i++) out[10 + i] = (i < ni) ? 1.f : 0.f;
    }
}

// avec = wq @ qp_w[:,512], bvec = wq @ qp_w[:,513]
__global__ void k_uv(const float* __restrict__ in_w, const float* __restrict__ qp_w, float* ws) {
    __shared__ float su[DD], sv[DD];
    int tid = threadIdx.x;
    for (int c = tid; c < DD; c += 256) { su[c] = qp_w[c * 514 + 512]; sv[c] = qp_w[c * 514 + 513]; }
    __syncthreads();
    int j = blockIdx.x * 256 + tid;
    float a = 0.f, b = 0.f;
    for (int c = 0; c < DD; c++) { float w = in_w[(size_t)j * DD + c]; a += w * su[c]; b += w * sv[c]; }
    ws[OFF_AV + j] = a; ws[OFF_BV + j] = b;
}

// A[h,n] = avec_h . K2[n,h*128:] / sqrt(DH);  B likewise
__global__ __launch_bounds__(256) void k_ab(float* ws) {
    int wave = threadIdx.x >> 6, lane = threadIdx.x & 63;
    int row = blockIdx.x * 4 + wave;   // = h*NT + n, < NH*NT
    int h = row / NT, n = row % NT;
    const float* k2 = ws + OFF_K2 + (size_t)n * DD + h * DHD;
    const float* av = ws + OFF_AV + h * DHD;
    const float* bv = ws + OFF_BV + h * DHD;
    int d = lane * 2;
    float a = av[d] * k2[d] + av[d + 1] * k2[d + 1];
    float b = bv[d] * k2[d] + bv[d + 1] * k2[d + 1];
    for (int off = 32; off; off >>= 1) { a += __shfl_xor(a, off); b += __shfl_xor(b, off); }
    if (lane == 0) { ws[OFF_AARR + row] = a * RSQRT_DH; ws[OFF_BARR + row] = b * RSQRT_DH; }
}

// Hrelu[i,n,j] = relu(H0[n, l*128+j] + s_i*w1[l,j,512] + e_i*w1[l,j,513])
__global__ void k_hrelu(const float* __restrict__ rw1, int l, float* ws) {
    int idx = blockIdx.x * 256 + threadIdx.x;  // < MAXI*NT*128
    int i = idx / (NT * 128);
    int rem = idx % (NT * 128);
    int n = rem >> 7, j = rem & 127;
    float s = ws[OFF_SCAL + SC_START + i], e = ws[OFF_SCAL + SC_END + i];
    const float* wr = rw1 + (size_t)(l * 128 + j) * 514;
    float v = ws[OFF_H0 + (size_t)n * 384 + l * 128 + j] + s * wr[512] + e * wr[513];
    ws[OFF_HR + idx] = fmaxf(v, 0.f);
}

// per (interval,row): softmax over 100 bins dotted with weight_params, both halves
__global__ __launch_bounds__(256) void k_softdot(const float* __restrict__ wp, float* ws) {
    int wave = threadIdx.x >> 6, lane = threadIdx.x & 63;
    int r = blockIdx.x * 4 + wave;   // < MAXI*NT
    if (blockIdx.x == 0 && threadIdx.x < 10) ws[OFF_SCAL + SC_DSDE + threadIdx.x] = 0.f;
    const float* L = ws + OFF_LG + (size_t)r * 200;
#pragma unroll
    for (int half = 0; half < 2; half++) {
        const float* Lh = L + half * NBINS;
        float x1 = (lane < NBINS) ? Lh[lane] : -1e30f;
        float x2 = (lane + 64 < NBINS) ? Lh[lane + 64] : -1e30f;
        float m = fmaxf(x1, x2);
        for (int off = 32; off; off >>= 1) m = fmaxf(m, __shfl_xor(m, off));
        float p1 = (lane < NBINS) ? __expf(x1 - m) : 0.f;
        float p2 = (lane + 64 < NBINS) ? __expf(x2 - m) : 0.f;
        float den = p1 + p2;
        float num = p1 * ((lane < NBINS) ? wp[lane] : 0.f) + p2 * ((lane + 64 < NBINS) ? wp[lane + 64] : 0.f);
        for (int off = 32; off; off >>= 1) { den += __shfl_xor(den, off); num += __shfl_xor(num, off); }
        if (lane == 0) ws[(half ? OFF_EOFF : OFF_SOFF) + r] = num / den;
    }
}

// per (interval h q) row: softmax(S0 + s*A + e*B) dotted with s_off/e_off; block-reduce; atomic
__global__ __launch_bounds__(256) void k_bigred(const bf16* __restrict__ S0, float* ws) {
    __shared__ float sds[4], sde[4];
    int wave = threadIdx.x >> 6, lane = threadIdx.x & 63;
    int r = blockIdx.x * 4 + wave;     // < MAXI*NH*NT; NH*NT divisible by 4 -> same i per block
    int i = r / (NH * NT);
    int hq = r % (NH * NT);
    int h = hq / NT;
    float s_i = ws[OFF_SCAL + SC_START + i], e_i = ws[OFF_SCAL + SC_END + i];
    const bf16* p = S0 + (size_t)hq * NT;
    const float* Ar = ws + OFF_AARR + h * NT;
    const float* Br = ws + OFF_BARR + h * NT;
    const float* so = ws + OFF_SOFF + i * NT;
    const float* eo = ws + OFF_EOFF + i * NT;
    float v[24], m = -1e30f;
#pragma unroll
    for (int t = 0; t < 24; t++) {
        int k = t * 64 + lane;
        v[t] = __bfloat162float(p[k]) + s_i * Ar[k] + e_i * Br[k];
        m = fmaxf(m, v[t]);
    }
    for (int off = 32; off; off >>= 1) m = fmaxf(m, __shfl_xor(m, off));
    float den = 0.f, ns = 0.f, ne = 0.f;
#pragma unroll
    for (int t = 0; t < 24; t++) {
        int k = t * 64 + lane;
        float pe = __expf(v[t] - m);
        den += pe; ns += pe * so[k]; ne += pe * eo[k];
    }
    for (int off = 32; off; off >>= 1) {
        den += __shfl_xor(den, off); ns += __shfl_xor(ns, off); ne += __shfl_xor(ne, off);
    }
    if (lane == 0) { sds[wave] = ns / den; sde[wave] = ne / den; }
    __syncthreads();
    if (threadIdx.x == 0) {
        atomicAdd(&ws[OFF_SCAL + SC_DSDE + i],        sds[0] + sds[1] + sds[2] + sds[3]);
        atomicAdd(&ws[OFF_SCAL + SC_DSDE + MAXI + i], sde[0] + sde[1] + sde[2] + sde[3]);
    }
}

__global__ void k_update(float* ws) {
    int tid = threadIdx.x;
    if (tid < MAXI) {
        ws[OFF_SCAL + SC_START + tid] += ws[OFF_SCAL + SC_DSDE + tid] * 0.25f;        // 1/H
        ws[OFF_SCAL + SC_END + tid]   += ws[OFF_SCAL + SC_DSDE + MAXI + tid] * 0.25f;
    }
}

__global__ void k_final(const float* __restrict__ ws, float* out) {
    int tid = threadIdx.x;
    if (tid < MAXI) {
        out[2 * tid]     = ws[OFF_SCAL + SC_START + tid];
        out[2 * tid + 1] = ws[OFF_SCAL + SC_END + tid];
    }
}

// -------------------------------------------------------------------------
extern "C" void kernel_launch(void* const* d_in, const int* in_sizes, int n_in,
                              void* d_out, int out_size, void* d_ws, size_t ws_size,
                              hipStream_t stream) {
    const float* emb    = (const float*)d_in[0];
    const float* tpos   = (const float*)d_in[1];
    const float* W_time = (const float*)d_in[3];
    const float* b_time = (const float*)d_in[4];
    const float* in_w   = (const float*)d_in[5];
    const float* in_b   = (const float*)d_in[6];
    const float* out_w  = (const float*)d_in[7];
    const float* out_b  = (const float*)d_in[8];
    const float* ic_w1  = (const float*)d_in[9];
    const float* ic_b1  = (const float*)d_in[10];
    const float* ic_w2  = (const float*)d_in[11];
    const float* ic_b2  = (const float*)d_in[12];
    const float* ref_w1 = (const float*)d_in[13];
    const float* ref_b1 = (const float*)d_in[14];
    const float* ref_w2 = (const float*)d_in[15];
    const float* ref_b2 = (const float*)d_in[16];
    const float* wp     = (const float*)d_in[17];
    const float* qp_w   = (const float*)d_in[18];
    const float* qp_b   = (const float*)d_in[19];
    float* ws  = (float*)d_ws;
    float* out = (float*)d_out;
    bf16* S = (bf16*)(ws + OFF_S);

    k_init<<<2, 256, 0, stream>>>(ws);
    k_tgrid<<<1, 256, 0, stream>>>(tpos, ws);
    k_x<<<NT * DD / 256, 256, 0, stream>>>(emb, tpos, W_time, b_time, ws);

    // qkv = x @ in_w^T + in_b   (1536 x 1536, K=512)
    k_gemm_nt<0><<<dim3(24, 24, 1), 256, 0, stream>>>(
        ws + OFF_X, DD, 0, in_w, DD, 0, ws + OFF_QKV, 3 * DD, 0, NT, 3 * DD, DD, 1.f, in_b);
    // scores per head -> S (bf16)
    k_gemm_nt<1><<<dim3(24, 24, NH), 256, 0, stream>>>(
        ws + OFF_QKV, 3 * DD, DHD, ws + OFF_QKV + DD, 3 * DD, DHD,
        S, NT, (long long)NT * NT, NT, NT, DHD, RSQRT_DH, nullptr);
    k_rstats<<<NH * NT / 4, 256, 0, stream>>>(S, ws);
    k_av<<<dim3(1, NT / 32, NH), 256, 0, stream>>>(ws, S);
    // attn_out = ctx @ out_w^T + out_b
    k_gemm_nt<0><<<dim3(8, 24, 1), 256, 0, stream>>>(
        ws + OFF_CTX, DD, 0, out_w, DD, 0, ws + OFF_ATT, DD, 0, NT, DD, DD, 1.f, out_b);

    k_pool<<<dim3(2, 12), 256, 0, stream>>>(ws);
    k_head<<<1, 128, 0, stream>>>(ic_w1, ic_b1, ic_w2, ic_b2, ws, out);

    // K2 = attn_out @ wk^T + bk
    k_gemm_nt<0><<<dim3(8, 24, 1), 256, 0, stream>>>(
        ws + OFF_ATT, DD, 0, in_w + (size_t)DD * DD, DD, 0, ws + OFF_K2, DD, 0, NT, DD, DD, 1.f, in_b + DD);
    // QP0 = attn_out @ qp_w[:, :512]^T + qp_b   (ldb = 514)
    k_gemm_nt<0><<<dim3(8, 24, 1), 256, 0, stream>>>(
        ws + OFF_ATT, DD, 0, qp_w, 514, 0, ws + OFF_QP0, DD, 0, NT, DD, DD, 1.f, qp_b);
    // Q0 = QP0 @ wq^T + bq
    k_gemm_nt<0><<<dim3(8, 24, 1), 256, 0, stream>>>(
        ws + OFF_QP0, DD, 0, in_w, DD, 0, ws + OFF_Q0, DD, 0, NT, DD, DD, 1.f, in_b);
    // H0 = attn_out @ ref_w1[:, :, :512]^T + ref_b1   (384 rows, ldb=514)
    k_gemm_nt<0><<<dim3(6, 24, 1), 256, 0, stream>>>(
        ws + OFF_ATT, DD, 0, ref_w1, 514, 0, ws + OFF_H0, 384, 0, NT, 384, DD, 1.f, ref_b1);

    k_uv<<<2, 256, 0, stream>>>(in_w, qp_w, ws);
    k_ab<<<NH * NT / 4, 256, 0, stream>>>(ws);

    // S0 per head -> S (bf16), overwrites first-MHA scores (dead)
    k_gemm_nt<1><<<dim3(24, 24, NH), 256, 0, stream>>>(
        ws + OFF_Q0, DD, DHD, ws + OFF_K2, DD, DHD,
        S, NT, (long long)NT * NT, NT, NT, DHD, RSQRT_DH, nullptr);

    for (int l = 0; l < NL; l++) {
        k_hrelu<<<MAXI * NT * 128 / 256, 256, 0, stream>>>(ref_w1, l, ws);
        k_gemm_nt<0><<<dim3(4, 120, 1), 256, 0, stream>>>(
            ws + OFF_HR, 128, 0, ref_w2 + (size_t)l * 200 * 128, 128, 0,
            ws + OFF_LG, 200, 0, MAXI * NT, 200, 128, 1.f, ref_b2 + l * 200);
        k_softdot<<<MAXI * NT / 4, 256, 0, stream>>>(wp, ws);
        k_bigred<<<MAXI * NH * NT / 4, 256, 0, stream>>>(S, ws);
        k_update<<<1, 32, 0, stream>>>(ws);
    }
    k_final<<<1, 32, 0, stream>>>(ws, out);
}

// Round 2
// 945.775 us; speedup vs baseline: 2.1813x; 2.1813x over previous
//
#include <hip/hip_runtime.h>
#include <hip/hip_bf16.h>

typedef __hip_bfloat16 bf16;

#define DD   512
#define NT   1536
#define NH   4
#define DHD  128
#define NBINS 100
#define MAXI 5
#define NL   3
#define RSQRT_DH 0.08838834764831845f   // 1/sqrt(128)

// ---- workspace layout (float offsets) ----
#define OFF_X      ((size_t)0)
#define OFF_QKV    (OFF_X    + (size_t)NT*DD)        // N x 3D
#define OFF_ATT    (OFF_QKV  + (size_t)NT*3*DD)      // attn_out N x D
#define OFF_CTX    (OFF_ATT  + (size_t)NT*DD)        // pre-out-proj ctx
#define OFF_K2     (OFF_CTX  + (size_t)NT*DD)
#define OFF_QP0    (OFF_K2   + (size_t)NT*DD)
#define OFF_Q0     (OFF_QP0  + (size_t)NT*DD)
#define OFF_H0     (OFF_Q0   + (size_t)NT*DD)        // N x 384 (3 layers x 128)
#define OFF_HR     (OFF_H0   + (size_t)NT*384)       // 5 x N x 128 ; reused per-layer as U[4][15][NT]
#define OFF_LG     (OFF_HR   + (size_t)MAXI*NT*128)  // 7680 x 200
#define OFF_AARR   (OFF_LG   + (size_t)MAXI*NT*200)  // H x N
#define OFF_BARR   (OFF_AARR + (size_t)NH*NT)
#define OFF_AV     (OFF_BARR + (size_t)NH*NT)        // D
#define OFF_BV     (OFF_AV   + (size_t)DD)
#define OFF_SOFF   (OFF_BV   + (size_t)DD)           // 5 x N
#define OFF_EOFF   (OFF_SOFF + (size_t)MAXI*NT)
#define OFF_RST    (OFF_EOFF + (size_t)MAXI*NT)      // H*N x 2 (max, 1/den)
#define OFF_POOL   (OFF_RST  + (size_t)NH*NT*2)      // D
#define OFF_SCAL   (OFF_POOL + (size_t)DD)           // 64 scalars
#define OFF_S      (OFF_SCAL + (size_t)64)           // bf16 region H*N*N
// scalar indices within OFF_SCAL
#define SC_START 0
#define SC_END   5
#define SC_DSDE  10
#define SC_TMIN  20
#define SC_TMAX  21

// -------------------------------------------------------------------------
__global__ void k_init(float* ws) {
    int i = blockIdx.x * 256 + threadIdx.x;
    if (i < DD) ws[OFF_POOL + i] = 0.f;
}

__global__ void k_tgrid(const float* __restrict__ t, float* ws) {
    __shared__ float smn[256], smx[256];
    int tid = threadIdx.x;
    float mn = 1e30f, mx = -1e30f;
    for (int i = tid; i < NT; i += 256) { float v = t[i]; mn = fminf(mn, v); mx = fmaxf(mx, v); }
    smn[tid] = mn; smx[tid] = mx; __syncthreads();
    for (int s = 128; s; s >>= 1) {
        if (tid < s) { smn[tid] = fminf(smn[tid], smn[tid + s]); smx[tid] = fmaxf(smx[tid], smx[tid + s]); }
        __syncthreads();
    }
    if (tid == 0) {
        float tmin = smn[0], tmax = smx[0];
        ws[OFF_SCAL + SC_TMIN] = tmin; ws[OFF_SCAL + SC_TMAX] = tmax;
        for (int i = 0; i < MAXI; i++) {
            ws[OFF_SCAL + SC_START + i] = tmin + (tmax - tmin) * (float)i / 5.0f;
            ws[OFF_SCAL + SC_END + i]   = tmin + (tmax - tmin) * (float)(i + 1) / 5.0f;
        }
    }
}

__global__ void k_x(const float* __restrict__ emb, const float* __restrict__ t,
                    const float* __restrict__ wt, const float* __restrict__ bt, float* ws) {
    int idx = blockIdx.x * 256 + threadIdx.x;  // < NT*DD
    int n = idx >> 9, j = idx & 511;
    ws[OFF_X + idx] = emb[idx] + t[n] * wt[j] + bt[j];
}

// C[M,Ncol] = alpha * A[M,K] @ B[Ncol,K]^T (+ bias), optional per-z offsets, optional bf16 out
template <int BF16OUT>
__global__ __launch_bounds__(256) void k_gemm_nt(
    const float* __restrict__ A, int lda, int aZ,
    const float* __restrict__ B, int ldb, int bZ,
    void* __restrict__ Cv, int ldc, long long cZ,
    int M, int Ncol, int K, float alpha, const float* __restrict__ bias)
{
    int z = blockIdx.z;
    A += (size_t)z * aZ; B += (size_t)z * bZ;
    int tid = threadIdx.x;
    int m0 = blockIdx.y * 64, n0 = blockIdx.x * 64;
    __shared__ __align__(16) float As[16][68];
    __shared__ __align__(16) float Bs[16][68];
    float acc[4][4] = {};
    int ty = tid >> 4, tx = tid & 15;
    for (int k0 = 0; k0 < K; k0 += 16) {
#pragma unroll
        for (int i = 0; i < 4; i++) {
            int idx = tid + 256 * i;
            int mm = idx >> 4, kk = idx & 15;
            int gm = m0 + mm;
            As[kk][mm] = (gm < M) ? A[(size_t)gm * lda + k0 + kk] : 0.f;
            int gn = n0 + mm;
            Bs[kk][mm] = (gn < Ncol) ? B[(size_t)gn * ldb + k0 + kk] : 0.f;
        }
        __syncthreads();
#pragma unroll
        for (int kk = 0; kk < 16; kk++) {
            float4 a4 = *(const float4*)&As[kk][ty * 4];
            float4 b4 = *(const float4*)&Bs[kk][tx * 4];
            float av_[4] = {a4.x, a4.y, a4.z, a4.w};
            float bv_[4] = {b4.x, b4.y, b4.z, b4.w};
#pragma unroll
            for (int ii = 0; ii < 4; ii++)
#pragma unroll
                for (int jj = 0; jj < 4; jj++) acc[ii][jj] += av_[ii] * bv_[jj];
        }
        __syncthreads();
    }
#pragma unroll
    for (int ii = 0; ii < 4; ii++) {
        int gm = m0 + ty * 4 + ii;
        if (gm >= M) continue;
#pragma unroll
        for (int jj = 0; jj < 4; jj++) {
            int gn = n0 + tx * 4 + jj;
            if (gn >= Ncol) continue;
            float v = acc[ii][jj] * alpha + (bias ? bias[gn] : 0.f);
            if (BF16OUT) ((bf16*)Cv)[cZ * z + (size_t)gm * ldc + gn] = __float2bfloat16(v);
            else         ((float*)Cv)[cZ * z + (size_t)gm * ldc + gn] = v;
        }
    }
}

// per-row softmax stats over bf16 score matrix (H*N rows, NT cols)
__global__ __launch_bounds__(256) void k_rstats(const bf16* __restrict__ S, float* ws) {
    int wave = threadIdx.x >> 6, lane = threadIdx.x & 63;
    int row = blockIdx.x * 4 + wave;  // < NH*NT
    const bf16* p = S + (size_t)row * NT;
    float v[24], m = -1e30f;
#pragma unroll
    for (int t = 0; t < 24; t++) { v[t] = __bfloat162float(p[t * 64 + lane]); m = fmaxf(m, v[t]); }
    for (int off = 32; off; off >>= 1) m = fmaxf(m, __shfl_xor(m, off));
    float s = 0.f;
#pragma unroll
    for (int t = 0; t < 24; t++) s += __expf(v[t] - m);
    for (int off = 32; off; off >>= 1) s += __shfl_xor(s, off);
    if (lane == 0) { ws[OFF_RST + 2 * row] = m; ws[OFF_RST + 2 * row + 1] = 1.f / s; }
}

// ctx[:, h*128:(h+1)*128] = softmax(S_h) @ V_h
__global__ __launch_bounds__(256) void k_av(float* ws, const bf16* __restrict__ S) {
    int h = blockIdx.z;
    int m0 = blockIdx.y * 32;
    __shared__ __align__(16) float Ws[32][36];
    __shared__ __align__(16) float Vs[32][132];
    int tid = threadIdx.x;
    int ty = tid >> 5, tx = tid & 31;
    float acc[4][4] = {};
    const bf16* Sh = S + (size_t)h * NT * NT;
    const float* rst = ws + OFF_RST;
    const float* qkv = ws + OFF_QKV;
    for (int k0 = 0; k0 < NT; k0 += 32) {
#pragma unroll
        for (int i = 0; i < 4; i++) {
            int idx = tid + 256 * i;
            int mm = idx >> 5, kk = idx & 31;
            int row = m0 + mm;
            float s = __bfloat162float(Sh[(size_t)row * NT + k0 + kk]);
            float mr = rst[2 * (h * NT + row)], ri = rst[2 * (h * NT + row) + 1];
            Ws[kk][mm] = __expf(s - mr) * ri;
        }
#pragma unroll
        for (int i = 0; i < 16; i++) {
            int idx = tid + 256 * i;
            int nn = idx & 127, kk = idx >> 7;
            Vs[kk][nn] = qkv[(size_t)(k0 + kk) * (3 * DD) + 2 * DD + h * DHD + nn];
        }
        __syncthreads();
#pragma unroll
        for (int kk = 0; kk < 32; kk++) {
            float4 a4 = *(const float4*)&Ws[kk][ty * 4];
            float4 b4 = *(const float4*)&Vs[kk][tx * 4];
            float av_[4] = {a4.x, a4.y, a4.z, a4.w};
            float bv_[4] = {b4.x, b4.y, b4.z, b4.w};
#pragma unroll
            for (int ii = 0; ii < 4; ii++)
#pragma unroll
                for (int jj = 0; jj < 4; jj++) acc[ii][jj] += av_[ii] * bv_[jj];
        }
        __syncthreads();
    }
    float* ctx = ws + OFF_CTX;
#pragma unroll
    for (int ii = 0; ii < 4; ii++) {
        int gm = m0 + ty * 4 + ii;
#pragma unroll
        for (int jj = 0; jj < 4; jj++)
            ctx[(size_t)gm * DD + h * DHD + tx * 4 + jj] = acc[ii][jj];
    }
}

__global__ void k_pool(float* ws) {
    int col = blockIdx.x * 256 + threadIdx.x;
    int r0 = blockIdx.y * 128;
    const float* att = ws + OFF_ATT;
    float s = 0.f;
    for (int r = 0; r < 128; r++) s += att[(size_t)(r0 + r) * DD + col];
    atomicAdd(&ws[OFF_POOL + col], s);
}

// pooled -> ic MLP -> argmax -> mask output (exact fp32, discrete path)
__global__ void k_head(const float* __restrict__ icw1, const float* __restrict__ icb1,
                       const float* __restrict__ icw2, const float* __restrict__ icb2,
                       float* ws, float* out) {
    __shared__ float h1[128];
    __shared__ float lg[MAXI];
    int tid = threadIdx.x;  // 128 threads
    float a = 0.f;
    for (int c = 0; c < DD; c++) a += icw1[(size_t)tid * DD + c] * ws[OFF_POOL + c];
    h1[tid] = fmaxf(a * (1.0f / NT) + icb1[tid], 0.f);
    __syncthreads();
    if (tid < MAXI) {
        float s = icb2[tid];
        for (int j = 0; j < 128; j++) s += icw2[tid * 128 + j] * h1[j];
        lg[tid] = s;
    }
    __syncthreads();
    if (tid == 0) {
        int best = 0; float bv = lg[0];
        for (int m = 1; m < MAXI; m++) if (lg[m] > bv) { bv = lg[m]; best = m; }
        int ni = best + 1;
        for (int i = 0; i < MAXI; i++) out[10 + i] = (i < ni) ? 1.f : 0.f;
    }
}

// avec = wq @ qp_w[:,512], bvec = wq @ qp_w[:,513]
__global__ void k_uv(const float* __restrict__ in_w, const float* __restrict__ qp_w, float* ws) {
    __shared__ float su[DD], sv[DD];
    int tid = threadIdx.x;
    for (int c = tid; c < DD; c += 256) { su[c] = qp_w[c * 514 + 512]; sv[c] = qp_w[c * 514 + 513]; }
    __syncthreads();
    int j = blockIdx.x * 256 + tid;
    float a = 0.f, b = 0.f;
    for (int c = 0; c < DD; c++) { float w = in_w[(size_t)j * DD + c]; a += w * su[c]; b += w * sv[c]; }
    ws[OFF_AV + j] = a; ws[OFF_BV + j] = b;
}

// A[h,n] = avec_h . K2[n,h*128:] / sqrt(DH);  B likewise
__global__ __launch_bounds__(256) void k_ab(float* ws) {
    int wave = threadIdx.x >> 6, lane = threadIdx.x & 63;
    int row = blockIdx.x * 4 + wave;   // = h*NT + n, < NH*NT
    int h = row / NT, n = row % NT;
    const float* k2 = ws + OFF_K2 + (size_t)n * DD + h * DHD;
    const float* av = ws + OFF_AV + h * DHD;
    const float* bv = ws + OFF_BV + h * DHD;
    int d = lane * 2;
    float a = av[d] * k2[d] + av[d + 1] * k2[d + 1];
    float b = bv[d] * k2[d] + bv[d + 1] * k2[d + 1];
    for (int off = 32; off; off >>= 1) { a += __shfl_xor(a, off); b += __shfl_xor(b, off); }
    if (lane == 0) { ws[OFF_AARR + row] = a * RSQRT_DH; ws[OFF_BARR + row] = b * RSQRT_DH; }
}

// E0 = exp(S0 - rowmax), in-place bf16, 8 elems/thread
__global__ __launch_bounds__(256) void k_e0(float* ws) {
    bf16* S = (bf16*)(ws + OFF_S);
    size_t idx = (size_t)blockIdx.x * 256 + threadIdx.x;   // < NH*NT*NT/8
    int row = (int)(idx / (NT / 8));
    float m = ws[OFF_RST + 2 * row];
    union { uint4 u4; unsigned short us[8]; } b;
    b.u4 = ((const uint4*)S)[idx];
#pragma unroll
    for (int t = 0; t < 8; t++) {
        bf16 hv; *(unsigned short*)&hv = b.us[t];
        bf16 ov = __float2bfloat16(__expf(__bfloat162float(hv) - m));
        b.us[t] = *(unsigned short*)&ov;
    }
    ((uint4*)S)[idx] = b.u4;
}

// Hrelu[i,n,j] = relu(H0[n, l*128+j] + s_i*w1[l,j,512] + e_i*w1[l,j,513])
__global__ void k_hrelu(const float* __restrict__ rw1, int l, float* ws) {
    int idx = blockIdx.x * 256 + threadIdx.x;  // < MAXI*NT*128
    int i = idx / (NT * 128);
    int rem = idx % (NT * 128);
    int n = rem >> 7, j = rem & 127;
    float s = ws[OFF_SCAL + SC_START + i], e = ws[OFF_SCAL + SC_END + i];
    const float* wr = rw1 + (size_t)(l * 128 + j) * 514;
    float v = ws[OFF_H0 + (size_t)n * 384 + l * 128 + j] + s * wr[512] + e * wr[513];
    ws[OFF_HR + idx] = fmaxf(v, 0.f);
}

// per (interval,row): softmax over 100 bins dotted with weight_params, both halves
__global__ __launch_bounds__(256) void k_softdot(const float* __restrict__ wp, float* ws) {
    int wave = threadIdx.x >> 6, lane = threadIdx.x & 63;
    int r = blockIdx.x * 4 + wave;   // < MAXI*NT
    if (blockIdx.x == 0 && threadIdx.x < 10) ws[OFF_SCAL + SC_DSDE + threadIdx.x] = 0.f;
    const float* L = ws + OFF_LG + (size_t)r * 200;
#pragma unroll
    for (int half = 0; half < 2; half++) {
        const float* Lh = L + half * NBINS;
        float x1 = (lane < NBINS) ? Lh[lane] : -1e30f;
        float x2 = (lane + 64 < NBINS) ? Lh[lane + 64] : -1e30f;
        float m = fmaxf(x1, x2);
        for (int off = 32; off; off >>= 1) m = fmaxf(m, __shfl_xor(m, off));
        float p1 = (lane < NBINS) ? __expf(x1 - m) : 0.f;
        float p2 = (lane + 64 < NBINS) ? __expf(x2 - m) : 0.f;
        float den = p1 + p2;
        float num = p1 * ((lane < NBINS) ? wp[lane] : 0.f) + p2 * ((lane + 64 < NBINS) ? wp[lane + 64] : 0.f);
        for (int off = 32; off; off >>= 1) { den += __shfl_xor(den, off); num += __shfl_xor(num, off); }
        if (lane == 0) ws[(half ? OFF_EOFF : OFF_SOFF) + r] = num / den;
    }
}

// build U[h][c][k], c = i*3 + {0:g, 1:g*so, 2:g*eo}; g = exp(s_i*A + e_i*B - mg)
// one block per (i,h)
__global__ __launch_bounds__(256) void k_gu(float* ws) {
    int i = blockIdx.x / NH, h = blockIdx.x % NH;
    __shared__ float red[256];
    int tid = threadIdx.x;
    float s_i = ws[OFF_SCAL + SC_START + i], e_i = ws[OFF_SCAL + SC_END + i];
    const float* Ar = ws + OFF_AARR + h * NT;
    const float* Br = ws + OFF_BARR + h * NT;
    float vals[6], mx = -1e30f;
#pragma unroll
    for (int t = 0; t < 6; t++) {
        int k = t * 256 + tid;
        vals[t] = s_i * Ar[k] + e_i * Br[k];
        mx = fmaxf(mx, vals[t]);
    }
    red[tid] = mx; __syncthreads();
    for (int s = 128; s; s >>= 1) {
        if (tid < s) red[tid] = fmaxf(red[tid], red[tid + s]);
        __syncthreads();
    }
    float mg = red[0];
    float* Uh = ws + OFF_HR + (size_t)h * 15 * NT;
    const float* so = ws + OFF_SOFF + i * NT;
    const float* eo = ws + OFF_EOFF + i * NT;
#pragma unroll
    for (int t = 0; t < 6; t++) {
        int k = t * 256 + tid;
        float g = __expf(vals[t] - mg);
        Uh[(i * 3 + 0) * NT + k] = g;
        Uh[(i * 3 + 1) * NT + k] = g * so[k];
        Uh[(i * 3 + 2) * NT + k] = g * eo[k];
    }
}

// per row r of E0: 15 dots with U[h][c][:]; ds[i] += ns/den, de[i] += ne/den
__global__ __launch_bounds__(256) void k_egemm(const bf16* __restrict__ E0, float* ws) {
    __shared__ float part[4][10];
    int wave = threadIdx.x >> 6, lane = threadIdx.x & 63;
    int row = blockIdx.x * 4 + wave;   // < NH*NT
    int h = row / NT;
    const bf16* p = E0 + (size_t)row * NT;
    const float* Uh = ws + OFF_HR + (size_t)h * 15 * NT;
    float acc[15] = {};
#pragma unroll 2
    for (int t = 0; t < 24; t++) {
        int k = t * 64 + lane;
        float e = __bfloat162float(p[k]);
#pragma unroll
        for (int c = 0; c < 15; c++) acc[c] += e * Uh[c * NT + k];
    }
#pragma unroll
    for (int c = 0; c < 15; c++)
        for (int off = 32; off; off >>= 1) acc[c] += __shfl_xor(acc[c], off);
    if (lane == 0) {
#pragma unroll
        for (int i = 0; i < MAXI; i++) {
            float den = acc[i * 3];
            part[wave][i]        = acc[i * 3 + 1] / den;
            part[wave][MAXI + i] = acc[i * 3 + 2] / den;
        }
    }
    __syncthreads();
    if (threadIdx.x < 10) {
        float s = part[0][threadIdx.x] + part[1][threadIdx.x] + part[2][threadIdx.x] + part[3][threadIdx.x];
        atomicAdd(&ws[OFF_SCAL + SC_DSDE + threadIdx.x], s);
    }
}

__global__ void k_update(float* ws) {
    int tid = threadIdx.x;
    if (tid < MAXI) {
        ws[OFF_SCAL + SC_START + tid] += ws[OFF_SCAL + SC_DSDE + tid] * 0.25f;        // 1/H
        ws[OFF_SCAL + SC_END + tid]   += ws[OFF_SCAL + SC_DSDE + MAXI + tid] * 0.25f;
    }
}

__global__ void k_final(const float* __restrict__ ws, float* out) {
    int tid = threadIdx.x;
    if (tid < MAXI) {
        out[2 * tid]     = ws[OFF_SCAL + SC_START + tid];
        out[2 * tid + 1] = ws[OFF_SCAL + SC_END + tid];
    }
}

// -------------------------------------------------------------------------
extern "C" void kernel_launch(void* const* d_in, const int* in_sizes, int n_in,
                              void* d_out, int out_size, void* d_ws, size_t ws_size,
                              hipStream_t stream) {
    const float* emb    = (const float*)d_in[0];
    const float* tpos   = (const float*)d_in[1];
    const float* W_time = (const float*)d_in[3];
    const float* b_time = (const float*)d_in[4];
    const float* in_w   = (const float*)d_in[5];
    const float* in_b   = (const float*)d_in[6];
    const float* out_w  = (const float*)d_in[7];
    const float* out_b  = (const float*)d_in[8];
    const float* ic_w1  = (const float*)d_in[9];
    const float* ic_b1  = (const float*)d_in[10];
    const float* ic_w2  = (const float*)d_in[11];
    const float* ic_b2  = (const float*)d_in[12];
    const float* ref_w1 = (const float*)d_in[13];
    const float* ref_b1 = (const float*)d_in[14];
    const float* ref_w2 = (const float*)d_in[15];
    const float* ref_b2 = (const float*)d_in[16];
    const float* wp     = (const float*)d_in[17];
    const float* qp_w   = (const float*)d_in[18];
    const float* qp_b   = (const float*)d_in[19];
    float* ws  = (float*)d_ws;
    float* out = (float*)d_out;
    bf16* S = (bf16*)(ws + OFF_S);

    k_init<<<2, 256, 0, stream>>>(ws);
    k_tgrid<<<1, 256, 0, stream>>>(tpos, ws);
    k_x<<<NT * DD / 256, 256, 0, stream>>>(emb, tpos, W_time, b_time, ws);

    // qkv = x @ in_w^T + in_b   (1536 x 1536, K=512)
    k_gemm_nt<0><<<dim3(24, 24, 1), 256, 0, stream>>>(
        ws + OFF_X, DD, 0, in_w, DD, 0, ws + OFF_QKV, 3 * DD, 0, NT, 3 * DD, DD, 1.f, in_b);
    // scores per head -> S (bf16)
    k_gemm_nt<1><<<dim3(24, 24, NH), 256, 0, stream>>>(
        ws + OFF_QKV, 3 * DD, DHD, ws + OFF_QKV + DD, 3 * DD, DHD,
        S, NT, (long long)NT * NT, NT, NT, DHD, RSQRT_DH, nullptr);
    k_rstats<<<NH * NT / 4, 256, 0, stream>>>(S, ws);
    k_av<<<dim3(1, NT / 32, NH), 256, 0, stream>>>(ws, S);
    // attn_out = ctx @ out_w^T + out_b
    k_gemm_nt<0><<<dim3(8, 24, 1), 256, 0, stream>>>(
        ws + OFF_CTX, DD, 0, out_w, DD, 0, ws + OFF_ATT, DD, 0, NT, DD, DD, 1.f, out_b);

    k_pool<<<dim3(2, 12), 256, 0, stream>>>(ws);
    k_head<<<1, 128, 0, stream>>>(ic_w1, ic_b1, ic_w2, ic_b2, ws, out);

    // K2 = attn_out @ wk^T + bk
    k_gemm_nt<0><<<dim3(8, 24, 1), 256, 0, stream>>>(
        ws + OFF_ATT, DD, 0, in_w + (size_t)DD * DD, DD, 0, ws + OFF_K2, DD, 0, NT, DD, DD, 1.f, in_b + DD);
    // QP0 = attn_out @ qp_w[:, :512]^T + qp_b   (ldb = 514)
    k_gemm_nt<0><<<dim3(8, 24, 1), 256, 0, stream>>>(
        ws + OFF_ATT, DD, 0, qp_w, 514, 0, ws + OFF_QP0, DD, 0, NT, DD, DD, 1.f, qp_b);
    // Q0 = QP0 @ wq^T + bq
    k_gemm_nt<0><<<dim3(8, 24, 1), 256, 0, stream>>>(
        ws + OFF_QP0, DD, 0, in_w, DD, 0, ws + OFF_Q0, DD, 0, NT, DD, DD, 1.f, in_b);
    // H0 = attn_out @ ref_w1[:, :, :512]^T + ref_b1   (384 rows, ldb=514)
    k_gemm_nt<0><<<dim3(6, 24, 1), 256, 0, stream>>>(
        ws + OFF_ATT, DD, 0, ref_w1, 514, 0, ws + OFF_H0, 384, 0, NT, 384, DD, 1.f, ref_b1);

    k_uv<<<2, 256, 0, stream>>>(in_w, qp_w, ws);
    k_ab<<<NH * NT / 4, 256, 0, stream>>>(ws);

    // S0 per head -> S (bf16), overwrites first-MHA scores (dead)
    k_gemm_nt<1><<<dim3(24, 24, NH), 256, 0, stream>>>(
        ws + OFF_Q0, DD, DHD, ws + OFF_K2, DD, DHD,
        S, NT, (long long)NT * NT, NT, NT, DHD, RSQRT_DH, nullptr);
    // row maxes of S0, then E0 = exp(S0 - max) in place
    k_rstats<<<NH * NT / 4, 256, 0, stream>>>(S, ws);
    k_e0<<<NH * NT * (NT / 8) / 256, 256, 0, stream>>>(ws);

    for (int l = 0; l < NL; l++) {
        k_hrelu<<<MAXI * NT * 128 / 256, 256, 0, stream>>>(ref_w1, l, ws);
        k_gemm_nt<0><<<dim3(4, 120, 1), 256, 0, stream>>>(
            ws + OFF_HR, 128, 0, ref_w2 + (size_t)l * 200 * 128, 128, 0,
            ws + OFF_LG, 200, 0, MAXI * NT, 200, 128, 1.f, ref_b2 + l * 200);
        k_softdot<<<MAXI * NT / 4, 256, 0, stream>>>(wp, ws);
        k_gu<<<MAXI * NH, 256, 0, stream>>>(ws);
        k_egemm<<<NH * NT / 4, 256, 0, stream>>>(S, ws);
        k_update<<<1, 32, 0, stream>>>(ws);
    }
    k_final<<<1, 32, 0, stream>>>(ws, out);
}

// Round 3
// 635.025 us; speedup vs baseline: 3.2487x; 1.4894x over previous
//
#include <hip/hip_runtime.h>
#include <hip/hip_bf16.h>

typedef __hip_bfloat16 bf16;
typedef __bf16 bf16x8 __attribute__((ext_vector_type(8)));
typedef float f32x4 __attribute__((ext_vector_type(4)));

#define DD   512
#define NT   1536
#define NH   4
#define DHD  128
#define NBINS 100
#define MAXI 5
#define NL   3
#define RSQRT_DH 0.08838834764831845f   // 1/sqrt(128)

// ---- workspace layout (float offsets) ----
#define OFF_X      ((size_t)0)                        // x; later reused as Vt[H][128][NT]
#define OFF_QKV    (OFF_X    + (size_t)NT*DD)        // N x 3D
#define OFF_ATT    (OFF_QKV  + (size_t)NT*3*DD)      // attn_out N x D
#define OFF_CTX    (OFF_ATT  + (size_t)NT*DD)        // pre-out-proj ctx
#define OFF_K2     (OFF_CTX  + (size_t)NT*DD)
#define OFF_QP0    (OFF_K2   + (size_t)NT*DD)
#define OFF_Q0     (OFF_QP0  + (size_t)NT*DD)
#define OFF_H0     (OFF_Q0   + (size_t)NT*DD)        // N x 384 (3 layers x 128)
#define OFF_HR     (OFF_H0   + (size_t)NT*384)       // 5 x N x 128 ; reused per-layer as U[4][15][NT]
#define OFF_LG     (OFF_HR   + (size_t)MAXI*NT*128)  // 7680 x 200
#define OFF_AARR   (OFF_LG   + (size_t)MAXI*NT*200)  // H x N
#define OFF_BARR   (OFF_AARR + (size_t)NH*NT)
#define OFF_AV     (OFF_BARR + (size_t)NH*NT)        // D
#define OFF_BV     (OFF_AV   + (size_t)DD)
#define OFF_SOFF   (OFF_BV   + (size_t)DD)           // 5 x N
#define OFF_EOFF   (OFF_SOFF + (size_t)MAXI*NT)
#define OFF_RST    (OFF_EOFF + (size_t)MAXI*NT)      // H*N x 2 (max, 1/den)
#define OFF_POOL   (OFF_RST  + (size_t)NH*NT*2)      // D
#define OFF_SCAL   (OFF_POOL + (size_t)DD)           // 64 scalars
#define OFF_S      (OFF_SCAL + (size_t)64)           // bf16 region H*N*N
#define SC_START 0
#define SC_END   5
#define SC_DSDE  10
#define SC_TMIN  20
#define SC_TMAX  21

// -------------------------------------------------------------------------
__global__ void k_init(float* ws) {
    int i = blockIdx.x * 256 + threadIdx.x;
    if (i < DD) ws[OFF_POOL + i] = 0.f;
}

__global__ void k_tgrid(const float* __restrict__ t, float* ws) {
    __shared__ float smn[256], smx[256];
    int tid = threadIdx.x;
    float mn = 1e30f, mx = -1e30f;
    for (int i = tid; i < NT; i += 256) { float v = t[i]; mn = fminf(mn, v); mx = fmaxf(mx, v); }
    smn[tid] = mn; smx[tid] = mx; __syncthreads();
    for (int s = 128; s; s >>= 1) {
        if (tid < s) { smn[tid] = fminf(smn[tid], smn[tid + s]); smx[tid] = fmaxf(smx[tid], smx[tid + s]); }
        __syncthreads();
    }
    if (tid == 0) {
        float tmin = smn[0], tmax = smx[0];
        ws[OFF_SCAL + SC_TMIN] = tmin; ws[OFF_SCAL + SC_TMAX] = tmax;
        for (int i = 0; i < MAXI; i++) {
            ws[OFF_SCAL + SC_START + i] = tmin + (tmax - tmin) * (float)i / 5.0f;
            ws[OFF_SCAL + SC_END + i]   = tmin + (tmax - tmin) * (float)(i + 1) / 5.0f;
        }
    }
}

__global__ void k_x(const float* __restrict__ emb, const float* __restrict__ t,
                    const float* __restrict__ wt, const float* __restrict__ bt, float* ws) {
    int idx = blockIdx.x * 256 + threadIdx.x;  // < NT*DD
    int n = idx >> 9, j = idx & 511;
    ws[OFF_X + idx] = emb[idx] + t[n] * wt[j] + bt[j];
}

// ---------------- MFMA bf16 GEMM: C[M,N] = alpha * A[M,K] @ B[N,K]^T (+bias) ----------------
// M multiple of 128 (grid.y), N arbitrary (col-bounds), K multiple of 32.
// fp32 A,B converted to bf16 during LDS staging; fp32 MFMA accumulate.
template <int BF16OUT>
__global__ __launch_bounds__(256) void k_mgemm(
    const float* __restrict__ A, int lda, long long aZ,
    const float* __restrict__ B, int ldb, long long bZ,
    void* __restrict__ Cv, int ldc, long long cZ,
    int N, int K, float alpha, const float* __restrict__ bias)
{
    int z = blockIdx.z;
    A += (size_t)z * aZ; B += (size_t)z * bZ;
    int m0 = blockIdx.y * 128, n0 = blockIdx.x * 128;
    __shared__ __bf16 As[128 * 40];
    __shared__ __bf16 Bs[128 * 40];
    int tid = threadIdx.x;
    int r = tid >> 1, hh = tid & 1;
    int w = tid >> 6, lane = tid & 63;
    int wm = (w & 1) * 64, wn = (w >> 1) * 64;
    int lr = lane & 15, lq = lane >> 4;
    f32x4 acc[4][4];
#pragma unroll
    for (int i = 0; i < 4; i++)
#pragma unroll
        for (int j = 0; j < 4; j++) acc[i][j] = (f32x4){0.f, 0.f, 0.f, 0.f};

    int gnr = n0 + r;
    const float* arow = A + (size_t)(m0 + r) * lda + hh * 16;
    const float* brow = B + (size_t)gnr * ldb + hh * 16;
    __bf16* awr = &As[r * 40 + hh * 16];
    __bf16* bwr = &Bs[r * 40 + hh * 16];

    for (int k0 = 0; k0 < K; k0 += 32) {
        __bf16 ta[16] __attribute__((aligned(16)));
        __bf16 tb[16] __attribute__((aligned(16)));
#pragma unroll
        for (int q = 0; q < 8; q++) {
            float2 f = *(const float2*)(arow + k0 + 2 * q);
            ta[2 * q] = (__bf16)f.x; ta[2 * q + 1] = (__bf16)f.y;
        }
        if (gnr < N) {
#pragma unroll
            for (int q = 0; q < 8; q++) {
                float2 f = *(const float2*)(brow + k0 + 2 * q);
                tb[2 * q] = (__bf16)f.x; tb[2 * q + 1] = (__bf16)f.y;
            }
        } else {
#pragma unroll
            for (int q = 0; q < 16; q++) tb[q] = (__bf16)0.f;
        }
        __syncthreads();
        *(bf16x8*)awr = *(bf16x8*)ta;
        *(bf16x8*)(awr + 8) = *(bf16x8*)(ta + 8);
        *(bf16x8*)bwr = *(bf16x8*)tb;
        *(bf16x8*)(bwr + 8) = *(bf16x8*)(tb + 8);
        __syncthreads();
        bf16x8 af[4], bfr[4];
#pragma unroll
        for (int i = 0; i < 4; i++) af[i] = *(bf16x8*)&As[(wm + i * 16 + lr) * 40 + lq * 8];
#pragma unroll
        for (int j = 0; j < 4; j++) bfr[j] = *(bf16x8*)&Bs[(wn + j * 16 + lr) * 40 + lq * 8];
#pragma unroll
        for (int i = 0; i < 4; i++)
#pragma unroll
            for (int j = 0; j < 4; j++)
                acc[i][j] = __builtin_amdgcn_mfma_f32_16x16x32_bf16(af[i], bfr[j], acc[i][j], 0, 0, 0);
    }
#pragma unroll
    for (int i = 0; i < 4; i++) {
#pragma unroll
        for (int r4 = 0; r4 < 4; r4++) {
            int gm = m0 + wm + i * 16 + lq * 4 + r4;
#pragma unroll
            for (int j = 0; j < 4; j++) {
                int gn = n0 + wn + j * 16 + lr;
                if (gn < N) {
                    float v = acc[i][j][r4] * alpha + (bias ? bias[gn] : 0.f);
                    if (BF16OUT) ((bf16*)Cv)[cZ * z + (size_t)gm * ldc + gn] = __float2bfloat16(v);
                    else         ((float*)Cv)[cZ * z + (size_t)gm * ldc + gn] = v;
                }
            }
        }
    }
}

// per-row softmax stats over bf16 score matrix (H*N rows, NT cols)
__global__ __launch_bounds__(256) void k_rstats(const bf16* __restrict__ S, float* ws) {
    int wave = threadIdx.x >> 6, lane = threadIdx.x & 63;
    int row = blockIdx.x * 4 + wave;  // < NH*NT
    const bf16* p = S + (size_t)row * NT;
    float v[24], m = -1e30f;
#pragma unroll
    for (int t = 0; t < 24; t++) { v[t] = __bfloat162float(p[t * 64 + lane]); m = fmaxf(m, v[t]); }
    for (int off = 32; off; off >>= 1) m = fmaxf(m, __shfl_xor(m, off));
    float s = 0.f;
#pragma unroll
    for (int t = 0; t < 24; t++) s += __expf(v[t] - m);
    for (int off = 32; off; off >>= 1) s += __shfl_xor(s, off);
    if (lane == 0) { ws[OFF_RST + 2 * row] = m; ws[OFF_RST + 2 * row + 1] = 1.f / s; }
}

// Vt[h][n][k] = qkv[k][2D + h*128 + n]   (transpose V for k_pv)
__global__ void k_vt(float* ws) {
    __shared__ float tb[32][33];
    int h = blockIdx.z, k0 = blockIdx.x * 32, n0 = blockIdx.y * 32;
    int tid = threadIdx.x;
    const float* qkv = ws + OFF_QKV;
    float* Vt = ws + OFF_X;
    int kk = tid >> 5, nn = tid & 31;
#pragma unroll
    for (int p = 0; p < 4; p++)
        tb[kk + p * 8][nn] = qkv[(size_t)(k0 + kk + p * 8) * (3 * DD) + 2 * DD + h * DHD + n0 + nn];
    __syncthreads();
    int nn2 = tid >> 5, kk2 = tid & 31;
#pragma unroll
    for (int p = 0; p < 4; p++)
        Vt[(size_t)(h * DHD + n0 + nn2 + p * 8) * NT + k0 + kk2] = tb[kk2][nn2 + p * 8];
}

// ctx[:, h*128:(h+1)*128] = softmax(S_h) @ V_h via MFMA.
// A-tile = exp(S - rowmax) (bf16), B = Vt; epilogue scales by 1/den.
__global__ __launch_bounds__(256) void k_pv(const bf16* __restrict__ S, float* ws) {
    int h = blockIdx.z, m0 = blockIdx.y * 128;
    __shared__ __bf16 As[128 * 40];
    __shared__ __bf16 Bs[128 * 40];
    int tid = threadIdx.x;
    int r = tid >> 1, hh = tid & 1;
    int w = tid >> 6, lane = tid & 63;
    int wm = (w & 1) * 64, wn = (w >> 1) * 64;
    int lr = lane & 15, lq = lane >> 4;
    const float* rst = ws + OFF_RST;
    const float* Vt = ws + OFF_X + (size_t)h * DHD * NT;
    const bf16* Sh = S + (size_t)h * NT * NT;
    int row = m0 + r;
    float mrow = rst[2 * (h * NT + row)];
    const unsigned short* srow = (const unsigned short*)(Sh + (size_t)row * NT) + hh * 16;
    const float* brow = Vt + (size_t)r * NT + hh * 16;
    __bf16* awr = &As[r * 40 + hh * 16];
    __bf16* bwr = &Bs[r * 40 + hh * 16];
    f32x4 acc[4][4];
#pragma unroll
    for (int i = 0; i < 4; i++)
#pragma unroll
        for (int j = 0; j < 4; j++) acc[i][j] = (f32x4){0.f, 0.f, 0.f, 0.f};

    for (int k0 = 0; k0 < NT; k0 += 32) {
        union { uint4 u; unsigned short s[8]; } b0, b1;
        b0.u = *(const uint4*)(srow + k0);
        b1.u = *(const uint4*)(srow + k0 + 8);
        __bf16 ta[16] __attribute__((aligned(16)));
        __bf16 tb[16] __attribute__((aligned(16)));
#pragma unroll
        for (int q = 0; q < 8; q++) {
            ta[q]     = (__bf16)__expf(__uint_as_float((unsigned)b0.s[q] << 16) - mrow);
            ta[8 + q] = (__bf16)__expf(__uint_as_float((unsigned)b1.s[q] << 16) - mrow);
        }
#pragma unroll
        for (int q = 0; q < 8; q++) {
            float2 f = *(const float2*)(brow + k0 + 2 * q);
            tb[2 * q] = (__bf16)f.x; tb[2 * q + 1] = (__bf16)f.y;
        }
        __syncthreads();
        *(bf16x8*)awr = *(bf16x8*)ta;
        *(bf16x8*)(awr + 8) = *(bf16x8*)(ta + 8);
        *(bf16x8*)bwr = *(bf16x8*)tb;
        *(bf16x8*)(bwr + 8) = *(bf16x8*)(tb + 8);
        __syncthreads();
        bf16x8 af[4], bfr[4];
#pragma unroll
        for (int i = 0; i < 4; i++) af[i] = *(bf16x8*)&As[(wm + i * 16 + lr) * 40 + lq * 8];
#pragma unroll
        for (int j = 0; j < 4; j++) bfr[j] = *(bf16x8*)&Bs[(wn + j * 16 + lr) * 40 + lq * 8];
#pragma unroll
        for (int i = 0; i < 4; i++)
#pragma unroll
            for (int j = 0; j < 4; j++)
                acc[i][j] = __builtin_amdgcn_mfma_f32_16x16x32_bf16(af[i], bfr[j], acc[i][j], 0, 0, 0);
    }
    float* ctx = ws + OFF_CTX;
#pragma unroll
    for (int i = 0; i < 4; i++) {
#pragma unroll
        for (int r4 = 0; r4 < 4; r4++) {
            int gm = m0 + wm + i * 16 + lq * 4 + r4;
            float ri = rst[2 * (h * NT + gm) + 1];
#pragma unroll
            for (int j = 0; j < 4; j++) {
                int gn = wn + j * 16 + lr;
                ctx[(size_t)gm * DD + h * DHD + gn] = acc[i][j][r4] * ri;
            }
        }
    }
}

__global__ void k_pool(float* ws) {
    int col = blockIdx.x * 256 + threadIdx.x;
    int r0 = blockIdx.y * 128;
    const float* att = ws + OFF_ATT;
    float s = 0.f;
    for (int r = 0; r < 128; r++) s += att[(size_t)(r0 + r) * DD + col];
    atomicAdd(&ws[OFF_POOL + col], s);
}

__global__ void k_head(const float* __restrict__ icw1, const float* __restrict__ icb1,
                       const float* __restrict__ icw2, const float* __restrict__ icb2,
                       float* ws, float* out) {
    __shared__ float h1[128];
    __shared__ float lg[MAXI];
    int tid = threadIdx.x;  // 128 threads
    float a = 0.f;
    for (int c = 0; c < DD; c++) a += icw1[(size_t)tid * DD + c] * ws[OFF_POOL + c];
    h1[tid] = fmaxf(a * (1.0f / NT) + icb1[tid], 0.f);
    __syncthreads();
    if (tid < MAXI) {
        float s = icb2[tid];
        for (int j = 0; j < 128; j++) s += icw2[tid * 128 + j] * h1[j];
        lg[tid] = s;
    }
    __syncthreads();
    if (tid == 0) {
        int best = 0; float bv = lg[0];
        for (int m = 1; m < MAXI; m++) if (lg[m] > bv) { bv = lg[m]; best = m; }
        int ni = best + 1;
        for (int i = 0; i < MAXI; i++) out[10 + i] = (i < ni) ? 1.f : 0.f;
    }
}

// avec = wq @ qp_w[:,512], bvec = wq @ qp_w[:,513]
__global__ void k_uv(const float* __restrict__ in_w, const float* __restrict__ qp_w, float* ws) {
    __shared__ float su[DD], sv[DD];
    int tid = threadIdx.x;
    for (int c = tid; c < DD; c += 256) { su[c] = qp_w[c * 514 + 512]; sv[c] = qp_w[c * 514 + 513]; }
    __syncthreads();
    int j = blockIdx.x * 256 + tid;
    float a = 0.f, b = 0.f;
    for (int c = 0; c < DD; c++) { float w = in_w[(size_t)j * DD + c]; a += w * su[c]; b += w * sv[c]; }
    ws[OFF_AV + j] = a; ws[OFF_BV + j] = b;
}

// A[h,n] = avec_h . K2[n,h*128:] / sqrt(DH);  B likewise
__global__ __launch_bounds__(256) void k_ab(float* ws) {
    int wave = threadIdx.x >> 6, lane = threadIdx.x & 63;
    int row = blockIdx.x * 4 + wave;   // = h*NT + n
    int h = row / NT, n = row % NT;
    const float* k2 = ws + OFF_K2 + (size_t)n * DD + h * DHD;
    const float* av = ws + OFF_AV + h * DHD;
    const float* bv = ws + OFF_BV + h * DHD;
    int d = lane * 2;
    float a = av[d] * k2[d] + av[d + 1] * k2[d + 1];
    float b = bv[d] * k2[d] + bv[d + 1] * k2[d + 1];
    for (int off = 32; off; off >>= 1) { a += __shfl_xor(a, off); b += __shfl_xor(b, off); }
    if (lane == 0) { ws[OFF_AARR + row] = a * RSQRT_DH; ws[OFF_BARR + row] = b * RSQRT_DH; }
}

// E0 = exp(S0 - rowmax), in-place bf16, 8 elems/thread
__global__ __launch_bounds__(256) void k_e0(float* ws) {
    bf16* S = (bf16*)(ws + OFF_S);
    size_t idx = (size_t)blockIdx.x * 256 + threadIdx.x;   // < NH*NT*NT/8
    int row = (int)(idx / (NT / 8));
    float m = ws[OFF_RST + 2 * row];
    union { uint4 u4; unsigned short us[8]; } b;
    b.u4 = ((const uint4*)S)[idx];
#pragma unroll
    for (int t = 0; t < 8; t++) {
        bf16 hv; *(unsigned short*)&hv = b.us[t];
        bf16 ov = __float2bfloat16(__expf(__bfloat162float(hv) - m));
        b.us[t] = *(unsigned short*)&ov;
    }
    ((uint4*)S)[idx] = b.u4;
}

// Hrelu[i,n,j] = relu(H0[n, l*128+j] + s_i*w1[l,j,512] + e_i*w1[l,j,513])
__global__ void k_hrelu(const float* __restrict__ rw1, int l, float* ws) {
    int idx = blockIdx.x * 256 + threadIdx.x;  // < MAXI*NT*128
    int i = idx / (NT * 128);
    int rem = idx % (NT * 128);
    int n = rem >> 7, j = rem & 127;
    float s = ws[OFF_SCAL + SC_START + i], e = ws[OFF_SCAL + SC_END + i];
    const float* wr = rw1 + (size_t)(l * 128 + j) * 514;
    float v = ws[OFF_H0 + (size_t)n * 384 + l * 128 + j] + s * wr[512] + e * wr[513];
    ws[OFF_HR + idx] = fmaxf(v, 0.f);
}

// per (interval,row): softmax over 100 bins dotted with weight_params, both halves
__global__ __launch_bounds__(256) void k_softdot(const float* __restrict__ wp, float* ws) {
    int wave = threadIdx.x >> 6, lane = threadIdx.x & 63;
    int r = blockIdx.x * 4 + wave;   // < MAXI*NT
    if (blockIdx.x == 0 && threadIdx.x < 10) ws[OFF_SCAL + SC_DSDE + threadIdx.x] = 0.f;
    const float* L = ws + OFF_LG + (size_t)r * 200;
#pragma unroll
    for (int half = 0; half < 2; half++) {
        const float* Lh = L + half * NBINS;
        float x1 = (lane < NBINS) ? Lh[lane] : -1e30f;
        float x2 = (lane + 64 < NBINS) ? Lh[lane + 64] : -1e30f;
        float m = fmaxf(x1, x2);
        for (int off = 32; off; off >>= 1) m = fmaxf(m, __shfl_xor(m, off));
        float p1 = (lane < NBINS) ? __expf(x1 - m) : 0.f;
        float p2 = (lane + 64 < NBINS) ? __expf(x2 - m) : 0.f;
        float den = p1 + p2;
        float num = p1 * ((lane < NBINS) ? wp[lane] : 0.f) + p2 * ((lane + 64 < NBINS) ? wp[lane + 64] : 0.f);
        for (int off = 32; off; off >>= 1) { den += __shfl_xor(den, off); num += __shfl_xor(num, off); }
        if (lane == 0) ws[(half ? OFF_EOFF : OFF_SOFF) + r] = num / den;
    }
}

// build U[h][c][k], c = i*3 + {0:g, 1:g*so, 2:g*eo}; g = exp(s_i*A + e_i*B - mg)
__global__ __launch_bounds__(256) void k_gu(float* ws) {
    int i = blockIdx.x / NH, h = blockIdx.x % NH;
    __shared__ float red[256];
    int tid = threadIdx.x;
    float s_i = ws[OFF_SCAL + SC_START + i], e_i = ws[OFF_SCAL + SC_END + i];
    const float* Ar = ws + OFF_AARR + h * NT;
    const float* Br = ws + OFF_BARR + h * NT;
    float vals[6], mx = -1e30f;
#pragma unroll
    for (int t = 0; t < 6; t++) {
        int k = t * 256 + tid;
        vals[t] = s_i * Ar[k] + e_i * Br[k];
        mx = fmaxf(mx, vals[t]);
    }
    red[tid] = mx; __syncthreads();
    for (int s = 128; s; s >>= 1) {
        if (tid < s) red[tid] = fmaxf(red[tid], red[tid + s]);
        __syncthreads();
    }
    float mg = red[0];
    float* Uh = ws + OFF_HR + (size_t)h * 15 * NT;
    const float* so = ws + OFF_SOFF + i * NT;
    const float* eo = ws + OFF_EOFF + i * NT;
#pragma unroll
    for (int t = 0; t < 6; t++) {
        int k = t * 256 + tid;
        float g = __expf(vals[t] - mg);
        Uh[(i * 3 + 0) * NT + k] = g;
        Uh[(i * 3 + 1) * NT + k] = g * so[k];
        Uh[(i * 3 + 2) * NT + k] = g * eo[k];
    }
}

// per row r of E0: 15 dots with U[h][c][:]; ds[i] += ns/den, de[i] += ne/den
__global__ __launch_bounds__(256) void k_egemm(const bf16* __restrict__ E0, float* ws) {
    __shared__ float part[4][10];
    int wave = threadIdx.x >> 6, lane = threadIdx.x & 63;
    int row = blockIdx.x * 4 + wave;   // < NH*NT
    int h = row / NT;
    const bf16* p = E0 + (size_t)row * NT;
    const float* Uh = ws + OFF_HR + (size_t)h * 15 * NT;
    float acc[15] = {};
#pragma unroll 2
    for (int t = 0; t < 24; t++) {
        int k = t * 64 + lane;
        float e = __bfloat162float(p[k]);
#pragma unroll
        for (int c = 0; c < 15; c++) acc[c] += e * Uh[c * NT + k];
    }
#pragma unroll
    for (int c = 0; c < 15; c++)
        for (int off = 32; off; off >>= 1) acc[c] += __shfl_xor(acc[c], off);
    if (lane == 0) {
#pragma unroll
        for (int i = 0; i < MAXI; i++) {
            float den = acc[i * 3];
            part[wave][i]        = acc[i * 3 + 1] / den;
            part[wave][MAXI + i] = acc[i * 3 + 2] / den;
        }
    }
    __syncthreads();
    if (threadIdx.x < 10) {
        float s = part[0][threadIdx.x] + part[1][threadIdx.x] + part[2][threadIdx.x] + part[3][threadIdx.x];
        atomicAdd(&ws[OFF_SCAL + SC_DSDE + threadIdx.x], s);
    }
}

__global__ void k_update(float* ws) {
    int tid = threadIdx.x;
    if (tid < MAXI) {
        ws[OFF_SCAL + SC_START + tid] += ws[OFF_SCAL + SC_DSDE + tid] * 0.25f;        // 1/H
        ws[OFF_SCAL + SC_END + tid]   += ws[OFF_SCAL + SC_DSDE + MAXI + tid] * 0.25f;
    }
}

__global__ void k_final(const float* __restrict__ ws, float* out) {
    int tid = threadIdx.x;
    if (tid < MAXI) {
        out[2 * tid]     = ws[OFF_SCAL + SC_START + tid];
        out[2 * tid + 1] = ws[OFF_SCAL + SC_END + tid];
    }
}

// -------------------------------------------------------------------------
extern "C" void kernel_launch(void* const* d_in, const int* in_sizes, int n_in,
                              void* d_out, int out_size, void* d_ws, size_t ws_size,
                              hipStream_t stream) {
    const float* emb    = (const float*)d_in[0];
    const float* tpos   = (const float*)d_in[1];
    const float* W_time = (const float*)d_in[3];
    const float* b_time = (const float*)d_in[4];
    const float* in_w   = (const float*)d_in[5];
    const float* in_b   = (const float*)d_in[6];
    const float* out_w  = (const float*)d_in[7];
    const float* out_b  = (const float*)d_in[8];
    const float* ic_w1  = (const float*)d_in[9];
    const float* ic_b1  = (const float*)d_in[10];
    const float* ic_w2  = (const float*)d_in[11];
    const float* ic_b2  = (const float*)d_in[12];
    const float* ref_w1 = (const float*)d_in[13];
    const float* ref_b1 = (const float*)d_in[14];
    const float* ref_w2 = (const float*)d_in[15];
    const float* ref_b2 = (const float*)d_in[16];
    const float* wp     = (const float*)d_in[17];
    const float* qp_w   = (const float*)d_in[18];
    const float* qp_b   = (const float*)d_in[19];
    float* ws  = (float*)d_ws;
    float* out = (float*)d_out;
    bf16* S = (bf16*)(ws + OFF_S);

    k_init<<<2, 256, 0, stream>>>(ws);
    k_tgrid<<<1, 256, 0, stream>>>(tpos, ws);
    k_x<<<NT * DD / 256, 256, 0, stream>>>(emb, tpos, W_time, b_time, ws);

    // qkv = x @ in_w^T + in_b   (1536 x 1536, K=512)
    k_mgemm<0><<<dim3(12, 12, 1), 256, 0, stream>>>(
        ws + OFF_X, DD, 0, in_w, DD, 0, ws + OFF_QKV, 3 * DD, 0, 3 * DD, DD, 1.f, in_b);
    // scores per head -> S (bf16)
    k_mgemm<1><<<dim3(12, 12, NH), 256, 0, stream>>>(
        ws + OFF_QKV, 3 * DD, DHD, ws + OFF_QKV + DD, 3 * DD, DHD,
        S, NT, (long long)NT * NT, NT, DHD, RSQRT_DH, nullptr);
    k_rstats<<<NH * NT / 4, 256, 0, stream>>>(S, ws);
    // V transpose (into dead x region), then P@V via MFMA
    k_vt<<<dim3(NT / 32, DHD / 32, NH), 256, 0, stream>>>(ws);
    k_pv<<<dim3(1, NT / 128, NH), 256, 0, stream>>>(S, ws);
    // attn_out = ctx @ out_w^T + out_b
    k_mgemm<0><<<dim3(4, 12, 1), 256, 0, stream>>>(
        ws + OFF_CTX, DD, 0, out_w, DD, 0, ws + OFF_ATT, DD, 0, DD, DD, 1.f, out_b);

    k_pool<<<dim3(2, 12), 256, 0, stream>>>(ws);
    k_head<<<1, 128, 0, stream>>>(ic_w1, ic_b1, ic_w2, ic_b2, ws, out);

    // K2 = attn_out @ wk^T + bk
    k_mgemm<0><<<dim3(4, 12, 1), 256, 0, stream>>>(
        ws + OFF_ATT, DD, 0, in_w + (size_t)DD * DD, DD, 0, ws + OFF_K2, DD, 0, DD, DD, 1.f, in_b + DD);
    // QP0 = attn_out @ qp_w[:, :512]^T + qp_b   (ldb = 514)
    k_mgemm<0><<<dim3(4, 12, 1), 256, 0, stream>>>(
        ws + OFF_ATT, DD, 0, qp_w, 514, 0, ws + OFF_QP0, DD, 0, DD, DD, 1.f, qp_b);
    // Q0 = QP0 @ wq^T + bq
    k_mgemm<0><<<dim3(4, 12, 1), 256, 0, stream>>>(
        ws + OFF_QP0, DD, 0, in_w, DD, 0, ws + OFF_Q0, DD, 0, DD, DD, 1.f, in_b);
    // H0 = attn_out @ ref_w1[:, :, :512]^T + ref_b1   (384 rows, ldb=514)
    k_mgemm<0><<<dim3(3, 12, 1), 256, 0, stream>>>(
        ws + OFF_ATT, DD, 0, ref_w1, 514, 0, ws + OFF_H0, 384, 0, 384, DD, 1.f, ref_b1);

    k_uv<<<2, 256, 0, stream>>>(in_w, qp_w, ws);
    k_ab<<<NH * NT / 4, 256, 0, stream>>>(ws);

    // S0 per head -> S (bf16)
    k_mgemm<1><<<dim3(12, 12, NH), 256, 0, stream>>>(
        ws + OFF_Q0, DD, DHD, ws + OFF_K2, DD, DHD,
        S, NT, (long long)NT * NT, NT, DHD, RSQRT_DH, nullptr);
    k_rstats<<<NH * NT / 4, 256, 0, stream>>>(S, ws);
    k_e0<<<NH * NT * (NT / 8) / 256, 256, 0, stream>>>(ws);

    for (int l = 0; l < NL; l++) {
        k_hrelu<<<MAXI * NT * 128 / 256, 256, 0, stream>>>(ref_w1, l, ws);
        k_mgemm<0><<<dim3(2, 60, 1), 256, 0, stream>>>(
            ws + OFF_HR, 128, 0, ref_w2 + (size_t)l * 200 * 128, 128, 0,
            ws + OFF_LG, 200, 0, 200, 128, 1.f, ref_b2 + l * 200);
        k_softdot<<<MAXI * NT / 4, 256, 0, stream>>>(wp, ws);
        k_gu<<<MAXI * NH, 256, 0, stream>>>(ws);
        k_egemm<<<NH * NT / 4, 256, 0, stream>>>(S, ws);
        k_update<<<1, 32, 0, stream>>>(ws);
    }
    k_final<<<1, 32, 0, stream>>>(ws, out);
}

// Round 4
// 430.864 us; speedup vs baseline: 4.7881x; 1.4738x over previous
//
#include <hip/hip_runtime.h>
#include <hip/hip_bf16.h>

typedef __hip_bfloat16 bf16;
typedef __bf16 bf16x8 __attribute__((ext_vector_type(8)));
typedef float f32x4 __attribute__((ext_vector_type(4)));

#define DD   512
#define NT   1536
#define NH   4
#define DHD  128
#define NBINS 100
#define MAXI 5
#define NL   3
#define RSQRT_DH 0.08838834764831845f   // 1/sqrt(128)

// ---- workspace layout (float offsets) ----
#define OFF_X      ((size_t)0)                        // x; later reused as Vt[H][128][NT]
#define OFF_QKV    (OFF_X    + (size_t)NT*DD)        // N x 3D
#define OFF_ATT    (OFF_QKV  + (size_t)NT*3*DD)      // attn_out N x D
#define OFF_CTX    (OFF_ATT  + (size_t)NT*DD)        // pre-out-proj ctx (atomic accum)
#define OFF_K2     (OFF_CTX  + (size_t)NT*DD)
#define OFF_QP0    (OFF_K2   + (size_t)NT*DD)
#define OFF_Q0     (OFF_QP0  + (size_t)NT*DD)
#define OFF_H0     (OFF_Q0   + (size_t)NT*DD)        // N x 384 (3 layers x 128)
#define OFF_HR     (OFF_H0   + (size_t)NT*384)       // 5 x N x 128 ; reused per-layer as U[4][15][NT]
#define OFF_LG     (OFF_HR   + (size_t)MAXI*NT*128)  // 7680 x 200 ; reused per-layer as P[6144][16]
#define OFF_AARR   (OFF_LG   + (size_t)MAXI*NT*200)  // H x N
#define OFF_BARR   (OFF_AARR + (size_t)NH*NT)
#define OFF_AV     (OFF_BARR + (size_t)NH*NT)        // D
#define OFF_BV     (OFF_AV   + (size_t)DD)
#define OFF_SOFF   (OFF_BV   + (size_t)DD)           // 5 x N
#define OFF_EOFF   (OFF_SOFF + (size_t)MAXI*NT)
#define OFF_RST    (OFF_EOFF + (size_t)MAXI*NT)      // H*N x 2 (max, 1/den)
#define OFF_POOL   (OFF_RST  + (size_t)NH*NT*2)      // D
#define OFF_SCAL   (OFF_POOL + (size_t)DD)           // 64 scalars
#define OFF_S      (OFF_SCAL + (size_t)64)           // bf16 region H*N*N
#define SC_START 0
#define SC_END   5
#define SC_DSDE  10
#define SC_TMIN  20
#define SC_TMAX  21

// -------------------------------------------------------------------------
__global__ void k_init(float* ws) {
    int i = blockIdx.x * 256 + threadIdx.x;
    if (i < DD) ws[OFF_POOL + i] = 0.f;
}

__global__ void k_tgrid(const float* __restrict__ t, float* ws) {
    __shared__ float smn[256], smx[256];
    int tid = threadIdx.x;
    float mn = 1e30f, mx = -1e30f;
    for (int i = tid; i < NT; i += 256) { float v = t[i]; mn = fminf(mn, v); mx = fmaxf(mx, v); }
    smn[tid] = mn; smx[tid] = mx; __syncthreads();
    for (int s = 128; s; s >>= 1) {
        if (tid < s) { smn[tid] = fminf(smn[tid], smn[tid + s]); smx[tid] = fmaxf(smx[tid], smx[tid + s]); }
        __syncthreads();
    }
    if (tid == 0) {
        float tmin = smn[0], tmax = smx[0];
        ws[OFF_SCAL + SC_TMIN] = tmin; ws[OFF_SCAL + SC_TMAX] = tmax;
        for (int i = 0; i < MAXI; i++) {
            ws[OFF_SCAL + SC_START + i] = tmin + (tmax - tmin) * (float)i / 5.0f;
            ws[OFF_SCAL + SC_END + i]   = tmin + (tmax - tmin) * (float)(i + 1) / 5.0f;
        }
    }
}

__global__ void k_x(const float* __restrict__ emb, const float* __restrict__ t,
                    const float* __restrict__ wt, const float* __restrict__ bt, float* ws) {
    int idx = blockIdx.x * 256 + threadIdx.x;  // < NT*DD
    int n = idx >> 9, j = idx & 511;
    ws[OFF_X + idx] = emb[idx] + t[n] * wt[j] + bt[j];
}

// ---------------- 128x128-tile MFMA GEMM (for big square GEMMs) ----------------
template <int BF16OUT>
__global__ __launch_bounds__(256) void k_mgemm(
    const float* __restrict__ A, int lda, long long aZ,
    const float* __restrict__ B, int ldb, long long bZ,
    void* __restrict__ Cv, int ldc, long long cZ,
    int N, int K, float alpha, const float* __restrict__ bias)
{
    int z = blockIdx.z;
    A += (size_t)z * aZ; B += (size_t)z * bZ;
    int m0 = blockIdx.y * 128, n0 = blockIdx.x * 128;
    __shared__ __bf16 As[128 * 40];
    __shared__ __bf16 Bs[128 * 40];
    int tid = threadIdx.x;
    int r = tid >> 1, hh = tid & 1;
    int w = tid >> 6, lane = tid & 63;
    int wm = (w & 1) * 64, wn = (w >> 1) * 64;
    int lr = lane & 15, lq = lane >> 4;
    f32x4 acc[4][4];
#pragma unroll
    for (int i = 0; i < 4; i++)
#pragma unroll
        for (int j = 0; j < 4; j++) acc[i][j] = (f32x4){0.f, 0.f, 0.f, 0.f};

    int gnr = n0 + r;
    const float* arow = A + (size_t)(m0 + r) * lda + hh * 16;
    const float* brow = B + (size_t)gnr * ldb + hh * 16;
    __bf16* awr = &As[r * 40 + hh * 16];
    __bf16* bwr = &Bs[r * 40 + hh * 16];

    for (int k0 = 0; k0 < K; k0 += 32) {
        __bf16 ta[16] __attribute__((aligned(16)));
        __bf16 tb[16] __attribute__((aligned(16)));
#pragma unroll
        for (int q = 0; q < 8; q++) {
            float2 f = *(const float2*)(arow + k0 + 2 * q);
            ta[2 * q] = (__bf16)f.x; ta[2 * q + 1] = (__bf16)f.y;
        }
        if (gnr < N) {
#pragma unroll
            for (int q = 0; q < 8; q++) {
                float2 f = *(const float2*)(brow + k0 + 2 * q);
                tb[2 * q] = (__bf16)f.x; tb[2 * q + 1] = (__bf16)f.y;
            }
        } else {
#pragma unroll
            for (int q = 0; q < 16; q++) tb[q] = (__bf16)0.f;
        }
        __syncthreads();
        *(bf16x8*)awr = *(bf16x8*)ta;
        *(bf16x8*)(awr + 8) = *(bf16x8*)(ta + 8);
        *(bf16x8*)bwr = *(bf16x8*)tb;
        *(bf16x8*)(bwr + 8) = *(bf16x8*)(tb + 8);
        __syncthreads();
        bf16x8 af[4], bfr[4];
#pragma unroll
        for (int i = 0; i < 4; i++) af[i] = *(bf16x8*)&As[(wm + i * 16 + lr) * 40 + lq * 8];
#pragma unroll
        for (int j = 0; j < 4; j++) bfr[j] = *(bf16x8*)&Bs[(wn + j * 16 + lr) * 40 + lq * 8];
#pragma unroll
        for (int i = 0; i < 4; i++)
#pragma unroll
            for (int j = 0; j < 4; j++)
                acc[i][j] = __builtin_amdgcn_mfma_f32_16x16x32_bf16(af[i], bfr[j], acc[i][j], 0, 0, 0);
    }
#pragma unroll
    for (int i = 0; i < 4; i++) {
#pragma unroll
        for (int r4 = 0; r4 < 4; r4++) {
            int gm = m0 + wm + i * 16 + lq * 4 + r4;
#pragma unroll
            for (int j = 0; j < 4; j++) {
                int gn = n0 + wn + j * 16 + lr;
                if (gn < N) {
                    float v = acc[i][j][r4] * alpha + (bias ? bias[gn] : 0.f);
                    if (BF16OUT) ((bf16*)Cv)[cZ * z + (size_t)gm * ldc + gn] = __float2bfloat16(v);
                    else         ((float*)Cv)[cZ * z + (size_t)gm * ldc + gn] = v;
                }
            }
        }
    }
}

// ---------------- 64x64-tile MFMA GEMM (occupancy for skinny/medium GEMMs) ----------------
template <int BF16OUT>
__global__ __launch_bounds__(256) void k_g64(
    const float* __restrict__ A, int lda, long long aZ,
    const float* __restrict__ B, int ldb, long long bZ,
    void* __restrict__ Cv, int ldc, long long cZ,
    int N, int K, float alpha, const float* __restrict__ bias)
{
    int z = blockIdx.z;
    A += (size_t)z * aZ; B += (size_t)z * bZ;
    int m0 = blockIdx.y * 64, n0 = blockIdx.x * 64;
    __shared__ __bf16 As[64 * 40];
    __shared__ __bf16 Bs[64 * 40];
    int tid = threadIdx.x;
    int r = tid >> 2, quad = tid & 3;
    int w = tid >> 6, lane = tid & 63;
    int wm = (w & 1) * 32, wn = (w >> 1) * 32;
    int lr = lane & 15, lq = lane >> 4;
    f32x4 acc[2][2];
#pragma unroll
    for (int i = 0; i < 2; i++)
#pragma unroll
        for (int j = 0; j < 2; j++) acc[i][j] = (f32x4){0.f, 0.f, 0.f, 0.f};

    int gnr = n0 + r;
    const float* arow = A + (size_t)(m0 + r) * lda + quad * 8;
    const float* brow = B + (size_t)gnr * ldb + quad * 8;
    __bf16* awr = &As[r * 40 + quad * 8];
    __bf16* bwr = &Bs[r * 40 + quad * 8];

    for (int k0 = 0; k0 < K; k0 += 32) {
        __bf16 ta[8] __attribute__((aligned(16)));
        __bf16 tb[8] __attribute__((aligned(16)));
#pragma unroll
        for (int q = 0; q < 4; q++) {
            float2 f = *(const float2*)(arow + k0 + 2 * q);
            ta[2 * q] = (__bf16)f.x; ta[2 * q + 1] = (__bf16)f.y;
        }
        if (gnr < N) {
#pragma unroll
            for (int q = 0; q < 4; q++) {
                float2 f = *(const float2*)(brow + k0 + 2 * q);
                tb[2 * q] = (__bf16)f.x; tb[2 * q + 1] = (__bf16)f.y;
            }
        } else {
#pragma unroll
            for (int q = 0; q < 8; q++) tb[q] = (__bf16)0.f;
        }
        __syncthreads();
        *(bf16x8*)awr = *(bf16x8*)ta;
        *(bf16x8*)bwr = *(bf16x8*)tb;
        __syncthreads();
        bf16x8 af[2], bfr[2];
#pragma unroll
        for (int i = 0; i < 2; i++) af[i] = *(bf16x8*)&As[(wm + i * 16 + lr) * 40 + lq * 8];
#pragma unroll
        for (int j = 0; j < 2; j++) bfr[j] = *(bf16x8*)&Bs[(wn + j * 16 + lr) * 40 + lq * 8];
#pragma unroll
        for (int i = 0; i < 2; i++)
#pragma unroll
            for (int j = 0; j < 2; j++)
                acc[i][j] = __builtin_amdgcn_mfma_f32_16x16x32_bf16(af[i], bfr[j], acc[i][j], 0, 0, 0);
    }
#pragma unroll
    for (int i = 0; i < 2; i++) {
#pragma unroll
        for (int r4 = 0; r4 < 4; r4++) {
            int gm = m0 + wm + i * 16 + lq * 4 + r4;
#pragma unroll
            for (int j = 0; j < 2; j++) {
                int gn = n0 + wn + j * 16 + lr;
                if (gn < N) {
                    float v = acc[i][j][r4] * alpha + (bias ? bias[gn] : 0.f);
                    if (BF16OUT) ((bf16*)Cv)[cZ * z + (size_t)gm * ldc + gn] = __float2bfloat16(v);
                    else         ((float*)Cv)[cZ * z + (size_t)gm * ldc + gn] = v;
                }
            }
        }
    }
}

// per-row softmax stats over bf16 score matrix (H*N rows, NT cols)
__global__ __launch_bounds__(256) void k_rstats(const bf16* __restrict__ S, float* ws) {
    int wave = threadIdx.x >> 6, lane = threadIdx.x & 63;
    int row = blockIdx.x * 4 + wave;  // < NH*NT
    const bf16* p = S + (size_t)row * NT;
    float v[24], m = -1e30f;
#pragma unroll
    for (int t = 0; t < 24; t++) { v[t] = __bfloat162float(p[t * 64 + lane]); m = fmaxf(m, v[t]); }
    for (int off = 32; off; off >>= 1) m = fmaxf(m, __shfl_xor(m, off));
    float s = 0.f;
#pragma unroll
    for (int t = 0; t < 24; t++) s += __expf(v[t] - m);
    for (int off = 32; off; off >>= 1) s += __shfl_xor(s, off);
    if (lane == 0) { ws[OFF_RST + 2 * row] = m; ws[OFF_RST + 2 * row + 1] = 1.f / s; }
}

// Vt[h][n][k] = qkv[k][2D + h*128 + n]   (transpose V for k_pv)
__global__ void k_vt(float* ws) {
    __shared__ float tb[32][33];
    int h = blockIdx.z, k0 = blockIdx.x * 32, n0 = blockIdx.y * 32;
    int tid = threadIdx.x;
    const float* qkv = ws + OFF_QKV;
    float* Vt = ws + OFF_X;
    int kk = tid >> 5, nn = tid & 31;
#pragma unroll
    for (int p = 0; p < 4; p++)
        tb[kk + p * 8][nn] = qkv[(size_t)(k0 + kk + p * 8) * (3 * DD) + 2 * DD + h * DHD + n0 + nn];
    __syncthreads();
    int nn2 = tid >> 5, kk2 = tid & 31;
#pragma unroll
    for (int p = 0; p < 4; p++)
        Vt[(size_t)(h * DHD + n0 + nn2 + p * 8) * NT + k0 + kk2] = tb[kk2][nn2 + p * 8];
}

// ctx[:, h*128:(h+1)*128] += partial softmax(S_h) @ V_h ; 64x64 tiles, split-K=4, atomic epilogue.
// grid: (8 = 2 n-tiles x 4 k-splits, 24 m-tiles, 4 heads)
__global__ __launch_bounds__(256) void k_pv(const bf16* __restrict__ S, float* ws) {
    int h = blockIdx.z;
    int m0 = blockIdx.y * 64;
    int n0 = (blockIdx.x & 1) * 64;
    int ks = blockIdx.x >> 1;
    const int KCH = NT / 4;   // 384 -> 12 iters
    int kbeg = ks * KCH;
    __shared__ __bf16 As[64 * 40];
    __shared__ __bf16 Bs[64 * 40];
    int tid = threadIdx.x;
    int r = tid >> 2, quad = tid & 3;
    int w = tid >> 6, lane = tid & 63;
    int wm = (w & 1) * 32, wn = (w >> 1) * 32;
    int lr = lane & 15, lq = lane >> 4;
    const float* rst = ws + OFF_RST;
    const float* Vt = ws + OFF_X + (size_t)h * DHD * NT;
    const bf16* Sh = S + (size_t)h * NT * NT;
    int row = m0 + r;
    float mrow = rst[2 * (h * NT + row)];
    const unsigned short* srow = (const unsigned short*)(Sh + (size_t)row * NT) + quad * 8;
    const float* brow = Vt + (size_t)(n0 + r) * NT + quad * 8;
    __bf16* awr = &As[r * 40 + quad * 8];
    __bf16* bwr = &Bs[r * 40 + quad * 8];
    f32x4 acc[2][2];
#pragma unroll
    for (int i = 0; i < 2; i++)
#pragma unroll
        for (int j = 0; j < 2; j++) acc[i][j] = (f32x4){0.f, 0.f, 0.f, 0.f};

    for (int k0 = kbeg; k0 < kbeg + KCH; k0 += 32) {
        union { uint4 u; unsigned short s[8]; } bb;
        bb.u = *(const uint4*)(srow + k0);
        __bf16 ta[8] __attribute__((aligned(16)));
        __bf16 tb[8] __attribute__((aligned(16)));
#pragma unroll
        for (int q = 0; q < 8; q++)
            ta[q] = (__bf16)__expf(__uint_as_float((unsigned)bb.s[q] << 16) - mrow);
#pragma unroll
        for (int q = 0; q < 4; q++) {
            float2 f = *(const float2*)(brow + k0 + 2 * q);
            tb[2 * q] = (__bf16)f.x; tb[2 * q + 1] = (__bf16)f.y;
        }
        __syncthreads();
        *(bf16x8*)awr = *(bf16x8*)ta;
        *(bf16x8*)bwr = *(bf16x8*)tb;
        __syncthreads();
        bf16x8 af[2], bfr[2];
#pragma unroll
        for (int i = 0; i < 2; i++) af[i] = *(bf16x8*)&As[(wm + i * 16 + lr) * 40 + lq * 8];
#pragma unroll
        for (int j = 0; j < 2; j++) bfr[j] = *(bf16x8*)&Bs[(wn + j * 16 + lr) * 40 + lq * 8];
#pragma unroll
        for (int i = 0; i < 2; i++)
#pragma unroll
            for (int j = 0; j < 2; j++)
                acc[i][j] = __builtin_amdgcn_mfma_f32_16x16x32_bf16(af[i], bfr[j], acc[i][j], 0, 0, 0);
    }
    float* ctx = ws + OFF_CTX;
#pragma unroll
    for (int i = 0; i < 2; i++) {
#pragma unroll
        for (int r4 = 0; r4 < 4; r4++) {
            int gm = m0 + wm + i * 16 + lq * 4 + r4;
            float ri = rst[2 * (h * NT + gm) + 1];
#pragma unroll
            for (int j = 0; j < 2; j++) {
                int gn = n0 + wn + j * 16 + lr;
                atomicAdd(&ctx[(size_t)gm * DD + h * DHD + gn], acc[i][j][r4] * ri);
            }
        }
    }
}

__global__ void k_pool(float* ws) {
    int col = blockIdx.x * 256 + threadIdx.x;
    int r0 = blockIdx.y * 128;
    const float* att = ws + OFF_ATT;
    float s = 0.f;
    for (int r = 0; r < 128; r++) s += att[(size_t)(r0 + r) * DD + col];
    atomicAdd(&ws[OFF_POOL + col], s);
}

__global__ void k_head(const float* __restrict__ icw1, const float* __restrict__ icb1,
                       const float* __restrict__ icw2, const float* __restrict__ icb2,
                       float* ws, float* out) {
    __shared__ float h1[128];
    __shared__ float lg[MAXI];
    int tid = threadIdx.x;  // 128 threads
    float a = 0.f;
    for (int c = 0; c < DD; c++) a += icw1[(size_t)tid * DD + c] * ws[OFF_POOL + c];
    h1[tid] = fmaxf(a * (1.0f / NT) + icb1[tid], 0.f);
    __syncthreads();
    if (tid < MAXI) {
        float s = icb2[tid];
        for (int j = 0; j < 128; j++) s += icw2[tid * 128 + j] * h1[j];
        lg[tid] = s;
    }
    __syncthreads();
    if (tid == 0) {
        int best = 0; float bv = lg[0];
        for (int m = 1; m < MAXI; m++) if (lg[m] > bv) { bv = lg[m]; best = m; }
        int ni = best + 1;
        for (int i = 0; i < MAXI; i++) out[10 + i] = (i < ni) ? 1.f : 0.f;
    }
}

// avec = wq @ qp_w[:,512], bvec = wq @ qp_w[:,513]
__global__ void k_uv(const float* __restrict__ in_w, const float* __restrict__ qp_w, float* ws) {
    __shared__ float su[DD], sv[DD];
    int tid = threadIdx.x;
    for (int c = tid; c < DD; c += 256) { su[c] = qp_w[c * 514 + 512]; sv[c] = qp_w[c * 514 + 513]; }
    __syncthreads();
    int j = blockIdx.x * 256 + tid;
    float a = 0.f, b = 0.f;
    for (int c = 0; c < DD; c++) { float w = in_w[(size_t)j * DD + c]; a += w * su[c]; b += w * sv[c]; }
    ws[OFF_AV + j] = a; ws[OFF_BV + j] = b;
}

// A[h,n] = avec_h . K2[n,h*128:] / sqrt(DH);  B likewise
__global__ __launch_bounds__(256) void k_ab(float* ws) {
    int wave = threadIdx.x >> 6, lane = threadIdx.x & 63;
    int row = blockIdx.x * 4 + wave;   // = h*NT + n
    int h = row / NT, n = row % NT;
    const float* k2 = ws + OFF_K2 + (size_t)n * DD + h * DHD;
    const float* av = ws + OFF_AV + h * DHD;
    const float* bv = ws + OFF_BV + h * DHD;
    int d = lane * 2;
    float a = av[d] * k2[d] + av[d + 1] * k2[d + 1];
    float b = bv[d] * k2[d] + bv[d + 1] * k2[d + 1];
    for (int off = 32; off; off >>= 1) { a += __shfl_xor(a, off); b += __shfl_xor(b, off); }
    if (lane == 0) { ws[OFF_AARR + row] = a * RSQRT_DH; ws[OFF_BARR + row] = b * RSQRT_DH; }
}

// E0 = exp(S0 - rowmax), in-place bf16, 8 elems/thread
__global__ __launch_bounds__(256) void k_e0(float* ws) {
    bf16* S = (bf16*)(ws + OFF_S);
    size_t idx = (size_t)blockIdx.x * 256 + threadIdx.x;   // < NH*NT*NT/8
    int row = (int)(idx / (NT / 8));
    float m = ws[OFF_RST + 2 * row];
    union { uint4 u4; unsigned short us[8]; } b;
    b.u4 = ((const uint4*)S)[idx];
#pragma unroll
    for (int t = 0; t < 8; t++) {
        bf16 hv; *(unsigned short*)&hv = b.us[t];
        bf16 ov = __float2bfloat16(__expf(__bfloat162float(hv) - m));
        b.us[t] = *(unsigned short*)&ov;
    }
    ((uint4*)S)[idx] = b.u4;
}

// Hrelu[i,n,j] = relu(H0[n, l*128+j] + s_i*w1[l,j,512] + e_i*w1[l,j,513])
__global__ void k_hrelu(const float* __restrict__ rw1, int l, float* ws) {
    int idx = blockIdx.x * 256 + threadIdx.x;  // < MAXI*NT*128
    int i = idx / (NT * 128);
    int rem = idx % (NT * 128);
    int n = rem >> 7, j = rem & 127;
    float s = ws[OFF_SCAL + SC_START + i], e = ws[OFF_SCAL + SC_END + i];
    const float* wr = rw1 + (size_t)(l * 128 + j) * 514;
    float v = ws[OFF_H0 + (size_t)n * 384 + l * 128 + j] + s * wr[512] + e * wr[513];
    ws[OFF_HR + idx] = fmaxf(v, 0.f);
}

// per (interval,row): softmax over 100 bins dotted with weight_params, both halves
__global__ __launch_bounds__(256) void k_softdot(const float* __restrict__ wp, float* ws) {
    int wave = threadIdx.x >> 6, lane = threadIdx.x & 63;
    int r = blockIdx.x * 4 + wave;   // < MAXI*NT
    if (blockIdx.x == 0 && threadIdx.x < 10) ws[OFF_SCAL + SC_DSDE + threadIdx.x] = 0.f;
    const float* L = ws + OFF_LG + (size_t)r * 200;
#pragma unroll
    for (int half = 0; half < 2; half++) {
        const float* Lh = L + half * NBINS;
        float x1 = (lane < NBINS) ? Lh[lane] : -1e30f;
        float x2 = (lane + 64 < NBINS) ? Lh[lane + 64] : -1e30f;
        float m = fmaxf(x1, x2);
        for (int off = 32; off; off >>= 1) m = fmaxf(m, __shfl_xor(m, off));
        float p1 = (lane < NBINS) ? __expf(x1 - m) : 0.f;
        float p2 = (lane + 64 < NBINS) ? __expf(x2 - m) : 0.f;
        float den = p1 + p2;
        float num = p1 * ((lane < NBINS) ? wp[lane] : 0.f) + p2 * ((lane + 64 < NBINS) ? wp[lane + 64] : 0.f);
        for (int off = 32; off; off >>= 1) { den += __shfl_xor(den, off); num += __shfl_xor(num, off); }
        if (lane == 0) ws[(half ? OFF_EOFF : OFF_SOFF) + r] = num / den;
    }
}

// build U[h][c][k], c = i*3 + {0:g, 1:g*so, 2:g*eo}; g = exp(s_i*A + e_i*B - mg)
__global__ __launch_bounds__(256) void k_gu(float* ws) {
    int i = blockIdx.x / NH, h = blockIdx.x % NH;
    __shared__ float red[256];
    int tid = threadIdx.x;
    float s_i = ws[OFF_SCAL + SC_START + i], e_i = ws[OFF_SCAL + SC_END + i];
    const float* Ar = ws + OFF_AARR + h * NT;
    const float* Br = ws + OFF_BARR + h * NT;
    float vals[6], mx = -1e30f;
#pragma unroll
    for (int t = 0; t < 6; t++) {
        int k = t * 256 + tid;
        vals[t] = s_i * Ar[k] + e_i * Br[k];
        mx = fmaxf(mx, vals[t]);
    }
    red[tid] = mx; __syncthreads();
    for (int s = 128; s; s >>= 1) {
        if (tid < s) red[tid] = fmaxf(red[tid], red[tid + s]);
        __syncthreads();
    }
    float mg = red[0];
    float* Uh = ws + OFF_HR + (size_t)h * 15 * NT;
    const float* so = ws + OFF_SOFF + i * NT;
    const float* eo = ws + OFF_EOFF + i * NT;
#pragma unroll
    for (int t = 0; t < 6; t++) {
        int k = t * 256 + tid;
        float g = __expf(vals[t] - mg);
        Uh[(i * 3 + 0) * NT + k] = g;
        Uh[(i * 3 + 1) * NT + k] = g * so[k];
        Uh[(i * 3 + 2) * NT + k] = g * eo[k];
    }
}

// P[h*NT + m][c] += sum_k E0[h][m][k] * U[h][c][k]  via MFMA, split-K=8.
// grid: (8 k-splits, 12 m-tiles, 4 heads). P in OFF_LG (zeroed by memset).
__global__ __launch_bounds__(256) void k_eg(const bf16* __restrict__ E0, float* ws) {
    int h = blockIdx.z;
    int m0 = blockIdx.y * 128;
    int ks = blockIdx.x;
    const int KCH = NT / 8;   // 192 -> 6 iters
    __shared__ __bf16 As[128 * 40];
    __shared__ __bf16 Bs[16 * 40];
    int tid = threadIdx.x;
    int w = tid >> 6, lane = tid & 63;
    int lr = lane & 15, lq = lane >> 4;
    int r = tid >> 1, half = tid & 1;
    const bf16* Sh = E0 + (size_t)h * NT * NT;
    const unsigned short* arow = (const unsigned short*)(Sh + (size_t)(m0 + r) * NT) + half * 16;
    const float* Uh = ws + OFF_HR + (size_t)h * 15 * NT;
    int wm = w * 32;
    f32x4 acc[2];
    acc[0] = (f32x4){0.f, 0.f, 0.f, 0.f};
    acc[1] = (f32x4){0.f, 0.f, 0.f, 0.f};
    int bc = tid >> 3, bk = tid & 7;   // tid<128: c in [0,16), 4 k each

    for (int k0 = ks * KCH; k0 < ks * KCH + KCH; k0 += 32) {
        uint4 a0 = *(const uint4*)(arow + k0);
        uint4 a1 = *(const uint4*)(arow + k0 + 8);
        float4 uf = {0.f, 0.f, 0.f, 0.f};
        if (tid < 128 && bc < 15) uf = *(const float4*)(Uh + (size_t)bc * NT + k0 + bk * 4);
        __syncthreads();
        *(uint4*)&As[r * 40 + half * 16] = a0;
        *(uint4*)&As[r * 40 + half * 16 + 8] = a1;
        if (tid < 128) {
            __bf16* bw = &Bs[bc * 40 + bk * 4];
            bw[0] = (__bf16)uf.x; bw[1] = (__bf16)uf.y; bw[2] = (__bf16)uf.z; bw[3] = (__bf16)uf.w;
        }
        __syncthreads();
        bf16x8 bf0 = *(bf16x8*)&Bs[lr * 40 + lq * 8];
        bf16x8 af0 = *(bf16x8*)&As[(wm + lr) * 40 + lq * 8];
        bf16x8 af1 = *(bf16x8*)&As[(wm + 16 + lr) * 40 + lq * 8];
        acc[0] = __builtin_amdgcn_mfma_f32_16x16x32_bf16(af0, bf0, acc[0], 0, 0, 0);
        acc[1] = __builtin_amdgcn_mfma_f32_16x16x32_bf16(af1, bf0, acc[1], 0, 0, 0);
    }
    float* P = ws + OFF_LG;
    if (lr < 15) {
#pragma unroll
        for (int i = 0; i < 2; i++)
#pragma unroll
            for (int r4 = 0; r4 < 4; r4++) {
                int gm = m0 + wm + i * 16 + lq * 4 + r4;
                atomicAdd(&P[(size_t)(h * NT + gm) * 16 + lr], acc[i][r4]);
            }
    }
}

// reduce P -> ds/de atomics. 24 blocks x 256 threads, one row each.
__global__ __launch_bounds__(256) void k_fin(float* ws) {
    __shared__ float part[4][10];
    int tid = threadIdx.x;
    int w = tid >> 6, lane = tid & 63;
    int row = blockIdx.x * 256 + tid;   // < NH*NT
    const float* P = ws + OFF_LG + (size_t)row * 16;
    float loc[10];
#pragma unroll
    for (int i = 0; i < MAXI; i++) {
        float den = P[i * 3];
        loc[i]        = P[i * 3 + 1] / den;
        loc[MAXI + i] = P[i * 3 + 2] / den;
    }
#pragma unroll
    for (int c = 0; c < 10; c++)
        for (int off = 32; off; off >>= 1) loc[c] += __shfl_xor(loc[c], off);
    if (lane == 0) {
#pragma unroll
        for (int c = 0; c < 10; c++) part[w][c] = loc[c];
    }
    __syncthreads();
    if (tid < 10) {
        float s = part[0][tid] + part[1][tid] + part[2][tid] + part[3][tid];
        atomicAdd(&ws[OFF_SCAL + SC_DSDE + tid], s);
    }
}

__global__ void k_update(float* ws) {
    int tid = threadIdx.x;
    if (tid < MAXI) {
        ws[OFF_SCAL + SC_START + tid] += ws[OFF_SCAL + SC_DSDE + tid] * 0.25f;        // 1/H
        ws[OFF_SCAL + SC_END + tid]   += ws[OFF_SCAL + SC_DSDE + MAXI + tid] * 0.25f;
    }
}

__global__ void k_final(const float* __restrict__ ws, float* out) {
    int tid = threadIdx.x;
    if (tid < MAXI) {
        out[2 * tid]     = ws[OFF_SCAL + SC_START + tid];
        out[2 * tid + 1] = ws[OFF_SCAL + SC_END + tid];
    }
}

// -------------------------------------------------------------------------
extern "C" void kernel_launch(void* const* d_in, const int* in_sizes, int n_in,
                              void* d_out, int out_size, void* d_ws, size_t ws_size,
                              hipStream_t stream) {
    const float* emb    = (const float*)d_in[0];
    const float* tpos   = (const float*)d_in[1];
    const float* W_time = (const float*)d_in[3];
    const float* b_time = (const float*)d_in[4];
    const float* in_w   = (const float*)d_in[5];
    const float* in_b   = (const float*)d_in[6];
    const float* out_w  = (const float*)d_in[7];
    const float* out_b  = (const float*)d_in[8];
    const float* ic_w1  = (const float*)d_in[9];
    const float* ic_b1  = (const float*)d_in[10];
    const float* ic_w2  = (const float*)d_in[11];
    const float* ic_b2  = (const float*)d_in[12];
    const float* ref_w1 = (const float*)d_in[13];
    const float* ref_b1 = (const float*)d_in[14];
    const float* ref_w2 = (const float*)d_in[15];
    const float* ref_b2 = (const float*)d_in[16];
    const float* wp     = (const float*)d_in[17];
    const float* qp_w   = (const float*)d_in[18];
    const float* qp_b   = (const float*)d_in[19];
    float* ws  = (float*)d_ws;
    float* out = (float*)d_out;
    bf16* S = (bf16*)(ws + OFF_S);

    k_init<<<2, 256, 0, stream>>>(ws);
    k_tgrid<<<1, 256, 0, stream>>>(tpos, ws);
    k_x<<<NT * DD / 256, 256, 0, stream>>>(emb, tpos, W_time, b_time, ws);
    hipMemsetAsync(ws + OFF_CTX, 0, (size_t)NT * DD * sizeof(float), stream);

    // qkv = x @ in_w^T + in_b   (1536 x 1536, K=512)
    k_g64<0><<<dim3(24, 24, 1), 256, 0, stream>>>(
        ws + OFF_X, DD, 0, in_w, DD, 0, ws + OFF_QKV, 3 * DD, 0, 3 * DD, DD, 1.f, in_b);
    // scores per head -> S (bf16)
    k_mgemm<1><<<dim3(12, 12, NH), 256, 0, stream>>>(
        ws + OFF_QKV, 3 * DD, DHD, ws + OFF_QKV + DD, 3 * DD, DHD,
        S, NT, (long long)NT * NT, NT, DHD, RSQRT_DH, nullptr);
    k_rstats<<<NH * NT / 4, 256, 0, stream>>>(S, ws);
    // V transpose (into dead x region), then P@V via MFMA (split-K, atomic into zeroed ctx)
    k_vt<<<dim3(NT / 32, DHD / 32, NH), 256, 0, stream>>>(ws);
    k_pv<<<dim3(8, NT / 64, NH), 256, 0, stream>>>(S, ws);
    // attn_out = ctx @ out_w^T + out_b
    k_g64<0><<<dim3(8, 24, 1), 256, 0, stream>>>(
        ws + OFF_CTX, DD, 0, out_w, DD, 0, ws + OFF_ATT, DD, 0, DD, DD, 1.f, out_b);

    k_pool<<<dim3(2, 12), 256, 0, stream>>>(ws);
    k_head<<<1, 128, 0, stream>>>(ic_w1, ic_b1, ic_w2, ic_b2, ws, out);

    // K2 = attn_out @ wk^T + bk
    k_g64<0><<<dim3(8, 24, 1), 256, 0, stream>>>(
        ws + OFF_ATT, DD, 0, in_w + (size_t)DD * DD, DD, 0, ws + OFF_K2, DD, 0, DD, DD, 1.f, in_b + DD);
    // QP0 = attn_out @ qp_w[:, :512]^T + qp_b   (ldb = 514)
    k_g64<0><<<dim3(8, 24, 1), 256, 0, stream>>>(
        ws + OFF_ATT, DD, 0, qp_w, 514, 0, ws + OFF_QP0, DD, 0, DD, DD, 1.f, qp_b);
    // Q0 = QP0 @ wq^T + bq
    k_g64<0><<<dim3(8, 24, 1), 256, 0, stream>>>(
        ws + OFF_QP0, DD, 0, in_w, DD, 0, ws + OFF_Q0, DD, 0, DD, DD, 1.f, in_b);
    // H0 = attn_out @ ref_w1[:, :, :512]^T + ref_b1   (384 rows, ldb=514)
    k_g64<0><<<dim3(6, 24, 1), 256, 0, stream>>>(
        ws + OFF_ATT, DD, 0, ref_w1, 514, 0, ws + OFF_H0, 384, 0, 384, DD, 1.f, ref_b1);

    k_uv<<<2, 256, 0, stream>>>(in_w, qp_w, ws);
    k_ab<<<NH * NT / 4, 256, 0, stream>>>(ws);

    // S0 per head -> S (bf16)
    k_mgemm<1><<<dim3(12, 12, NH), 256, 0, stream>>>(
        ws + OFF_Q0, DD, DHD, ws + OFF_K2, DD, DHD,
        S, NT, (long long)NT * NT, NT, DHD, RSQRT_DH, nullptr);
    k_rstats<<<NH * NT / 4, 256, 0, stream>>>(S, ws);
    k_e0<<<NH * NT * (NT / 8) / 256, 256, 0, stream>>>(ws);

    for (int l = 0; l < NL; l++) {
        k_hrelu<<<MAXI * NT * 128 / 256, 256, 0, stream>>>(ref_w1, l, ws);
        k_g64<0><<<dim3(4, 120, 1), 256, 0, stream>>>(
            ws + OFF_HR, 128, 0, ref_w2 + (size_t)l * 200 * 128, 128, 0,
            ws + OFF_LG, 200, 0, 200, 128, 1.f, ref_b2 + l * 200);
        k_softdot<<<MAXI * NT / 4, 256, 0, stream>>>(wp, ws);
        k_gu<<<MAXI * NH, 256, 0, stream>>>(ws);
        hipMemsetAsync(ws + OFF_LG, 0, (size_t)NH * NT * 16 * sizeof(float), stream);
        k_eg<<<dim3(8, NT / 128, NH), 256, 0, stream>>>(S, ws);
        k_fin<<<NH * NT / 256, 256, 0, stream>>>(ws);
        k_update<<<1, 32, 0, stream>>>(ws);
    }
    k_final<<<1, 32, 0, stream>>>(ws, out);
}

// Round 5
// 410.267 us; speedup vs baseline: 5.0284x; 1.0502x over previous
//
#include <hip/hip_runtime.h>
#include <hip/hip_bf16.h>

typedef __hip_bfloat16 bf16;
typedef __bf16 bf16x8 __attribute__((ext_vector_type(8)));
typedef float f32x4 __attribute__((ext_vector_type(4)));

#define DD   512
#define NT   1536
#define NH   4
#define DHD  128
#define NBINS 100
#define MAXI 5
#define NL   3
#define RSQRT_DH 0.08838834764831845f   // 1/sqrt(128)

// ---- workspace layout (float offsets) ----
#define OFF_X      ((size_t)0)                        // Vt[H][128][NT] (x is never materialized)
#define OFF_QKV    (OFF_X    + (size_t)NT*DD)        // N x 3D
#define OFF_ATT    (OFF_QKV  + (size_t)NT*3*DD)      // attn_out N x D
#define OFF_CTX    (OFF_ATT  + (size_t)NT*DD)        // pv partial ks=0
#define OFF_K2     (OFF_CTX  + (size_t)NT*DD)
#define OFF_QP0    (OFF_K2   + (size_t)NT*DD)        // reused: qpT | M2 | b2
#define OFF_Q0     (OFF_QP0  + (size_t)NT*DD)
#define OFF_H0     (OFF_Q0   + (size_t)NT*DD)        // N x 384 (3 layers x 128)
#define OFF_HR     (OFF_H0   + (size_t)NT*384)       // pv partial ks=1 ; later U[4][15][NT]
#define OFF_LG     (OFF_HR   + (size_t)MAXI*NT*128)  // logits 7680x200 ; later P slices [8][NH*NT][16]
#define OFF_AARR   (OFF_LG   + (size_t)MAXI*NT*200)  // H x N
#define OFF_BARR   (OFF_AARR + (size_t)NH*NT)
#define OFF_AV     (OFF_BARR + (size_t)NH*NT)        // D
#define OFF_BV     (OFF_AV   + (size_t)DD)
#define OFF_SOFF   (OFF_BV   + (size_t)DD)           // 5 x N
#define OFF_EOFF   (OFF_SOFF + (size_t)MAXI*NT)
#define OFF_RST    (OFF_EOFF + (size_t)MAXI*NT)      // H*N x 2 (max, 1/den) for first MHA
#define OFF_POOL   (OFF_RST  + (size_t)NH*NT*2)      // D
#define OFF_SCAL   (OFF_POOL + (size_t)DD)           // 64 scalars
#define OFF_S      (OFF_SCAL + (size_t)64)           // bf16 region H*N*N
#define SC_START 0
#define SC_END   5
#define SC_DSDE  10
#define SC_TMIN  20
#define SC_TMAX  21
// sub-offsets in the dead QP0 region
#define OFF_QPT  (OFF_QP0)
#define OFF_M2   (OFF_QP0 + (size_t)512*512)
#define OFF_B2   (OFF_QP0 + (size_t)2*512*512)
#define PSLICE   ((size_t)NH*NT*16)

// -------------------------------------------------------------------------
__global__ void k_init(float* ws) {
    int i = blockIdx.x * 256 + threadIdx.x;
    if (i < DD) ws[OFF_POOL + i] = 0.f;
}

__global__ void k_tgrid(const float* __restrict__ t, float* ws) {
    __shared__ float smn[256], smx[256];
    int tid = threadIdx.x;
    float mn = 1e30f, mx = -1e30f;
    for (int i = tid; i < NT; i += 256) { float v = t[i]; mn = fminf(mn, v); mx = fmaxf(mx, v); }
    smn[tid] = mn; smx[tid] = mx; __syncthreads();
    for (int s = 128; s; s >>= 1) {
        if (tid < s) { smn[tid] = fminf(smn[tid], smn[tid + s]); smx[tid] = fmaxf(smx[tid], smx[tid + s]); }
        __syncthreads();
    }
    if (tid == 0) {
        float tmin = smn[0], tmax = smx[0];
        ws[OFF_SCAL + SC_TMIN] = tmin; ws[OFF_SCAL + SC_TMAX] = tmax;
        for (int i = 0; i < MAXI; i++) {
            ws[OFF_SCAL + SC_START + i] = tmin + (tmax - tmin) * (float)i / 5.0f;
            ws[OFF_SCAL + SC_END + i]   = tmin + (tmax - tmin) * (float)(i + 1) / 5.0f;
        }
    }
}

// transpose qp_w[:, :512] (ld 514) -> qpT (512x512)
__global__ void k_qpt(const float* __restrict__ qp_w, float* ws) {
    __shared__ float tb[32][33];
    int c0 = blockIdx.x * 32, d0 = blockIdx.y * 32;
    int tid = threadIdx.x;
    int dd = tid >> 5, cc = tid & 31;
#pragma unroll
    for (int p = 0; p < 4; p++)
        tb[dd + p * 8][cc] = qp_w[(size_t)(d0 + dd + p * 8) * 514 + c0 + cc];
    __syncthreads();
    int cc2 = tid >> 5, dd2 = tid & 31;
    float* qpT = ws + OFF_QPT;
#pragma unroll
    for (int p = 0; p < 4; p++)
        qpT[(size_t)(c0 + cc2 + p * 8) * 512 + d0 + dd2] = tb[dd2][cc2 + p * 8];
}

// ---------------- 128x128-tile MFMA GEMM ----------------
template <int BF16OUT>
__global__ __launch_bounds__(256) void k_mgemm(
    const float* __restrict__ A, int lda, long long aZ,
    const float* __restrict__ B, int ldb, long long bZ,
    void* __restrict__ Cv, int ldc, long long cZ,
    int N, int K, float alpha, const float* __restrict__ bias)
{
    int z = blockIdx.z;
    A += (size_t)z * aZ; B += (size_t)z * bZ;
    int m0 = blockIdx.y * 128, n0 = blockIdx.x * 128;
    __shared__ __bf16 As[128 * 40];
    __shared__ __bf16 Bs[128 * 40];
    int tid = threadIdx.x;
    int r = tid >> 1, hh = tid & 1;
    int w = tid >> 6, lane = tid & 63;
    int wm = (w & 1) * 64, wn = (w >> 1) * 64;
    int lr = lane & 15, lq = lane >> 4;
    f32x4 acc[4][4];
#pragma unroll
    for (int i = 0; i < 4; i++)
#pragma unroll
        for (int j = 0; j < 4; j++) acc[i][j] = (f32x4){0.f, 0.f, 0.f, 0.f};

    int gnr = n0 + r;
    const float* arow = A + (size_t)(m0 + r) * lda + hh * 16;
    const float* brow = B + (size_t)gnr * ldb + hh * 16;
    __bf16* awr = &As[r * 40 + hh * 16];
    __bf16* bwr = &Bs[r * 40 + hh * 16];

    for (int k0 = 0; k0 < K; k0 += 32) {
        __bf16 ta[16] __attribute__((aligned(16)));
        __bf16 tb[16] __attribute__((aligned(16)));
#pragma unroll
        for (int q = 0; q < 8; q++) {
            float2 f = *(const float2*)(arow + k0 + 2 * q);
            ta[2 * q] = (__bf16)f.x; ta[2 * q + 1] = (__bf16)f.y;
        }
        if (gnr < N) {
#pragma unroll
            for (int q = 0; q < 8; q++) {
                float2 f = *(const float2*)(brow + k0 + 2 * q);
                tb[2 * q] = (__bf16)f.x; tb[2 * q + 1] = (__bf16)f.y;
            }
        } else {
#pragma unroll
            for (int q = 0; q < 16; q++) tb[q] = (__bf16)0.f;
        }
        __syncthreads();
        *(bf16x8*)awr = *(bf16x8*)ta;
        *(bf16x8*)(awr + 8) = *(bf16x8*)(ta + 8);
        *(bf16x8*)bwr = *(bf16x8*)tb;
        *(bf16x8*)(bwr + 8) = *(bf16x8*)(tb + 8);
        __syncthreads();
        bf16x8 af[4], bfr[4];
#pragma unroll
        for (int i = 0; i < 4; i++) af[i] = *(bf16x8*)&As[(wm + i * 16 + lr) * 40 + lq * 8];
#pragma unroll
        for (int j = 0; j < 4; j++) bfr[j] = *(bf16x8*)&Bs[(wn + j * 16 + lr) * 40 + lq * 8];
#pragma unroll
        for (int i = 0; i < 4; i++)
#pragma unroll
            for (int j = 0; j < 4; j++)
                acc[i][j] = __builtin_amdgcn_mfma_f32_16x16x32_bf16(af[i], bfr[j], acc[i][j], 0, 0, 0);
    }
#pragma unroll
    for (int i = 0; i < 4; i++) {
#pragma unroll
        for (int r4 = 0; r4 < 4; r4++) {
            int gm = m0 + wm + i * 16 + lq * 4 + r4;
#pragma unroll
            for (int j = 0; j < 4; j++) {
                int gn = n0 + wn + j * 16 + lr;
                if (gn < N) {
                    float v = acc[i][j][r4] * alpha + (bias ? bias[gn] : 0.f);
                    if (BF16OUT) ((bf16*)Cv)[cZ * z + (size_t)gm * ldc + gn] = __float2bfloat16(v);
                    else         ((float*)Cv)[cZ * z + (size_t)gm * ldc + gn] = v;
                }
            }
        }
    }
}

// ---------------- 64x64-tile MFMA GEMM ----------------
template <int BF16OUT>
__global__ __launch_bounds__(256) void k_g64(
    const float* __restrict__ A, int lda, long long aZ,
    const float* __restrict__ B, int ldb, long long bZ,
    void* __restrict__ Cv, int ldc, long long cZ,
    int N, int K, float alpha, const float* __restrict__ bias)
{
    int z = blockIdx.z;
    A += (size_t)z * aZ; B += (size_t)z * bZ;
    int m0 = blockIdx.y * 64, n0 = blockIdx.x * 64;
    __shared__ __bf16 As[64 * 40];
    __shared__ __bf16 Bs[64 * 40];
    int tid = threadIdx.x;
    int r = tid >> 2, quad = tid & 3;
    int w = tid >> 6, lane = tid & 63;
    int wm = (w & 1) * 32, wn = (w >> 1) * 32;
    int lr = lane & 15, lq = lane >> 4;
    f32x4 acc[2][2];
#pragma unroll
    for (int i = 0; i < 2; i++)
#pragma unroll
        for (int j = 0; j < 2; j++) acc[i][j] = (f32x4){0.f, 0.f, 0.f, 0.f};

    int gnr = n0 + r;
    const float* arow = A + (size_t)(m0 + r) * lda + quad * 8;
    const float* brow = B + (size_t)gnr * ldb + quad * 8;
    __bf16* awr = &As[r * 40 + quad * 8];
    __bf16* bwr = &Bs[r * 40 + quad * 8];

    for (int k0 = 0; k0 < K; k0 += 32) {
        __bf16 ta[8] __attribute__((aligned(16)));
        __bf16 tb[8] __attribute__((aligned(16)));
#pragma unroll
        for (int q = 0; q < 4; q++) {
            float2 f = *(const float2*)(arow + k0 + 2 * q);
            ta[2 * q] = (__bf16)f.x; ta[2 * q + 1] = (__bf16)f.y;
        }
        if (gnr < N) {
#pragma unroll
            for (int q = 0; q < 4; q++) {
                float2 f = *(const float2*)(brow + k0 + 2 * q);
                tb[2 * q] = (__bf16)f.x; tb[2 * q + 1] = (__bf16)f.y;
            }
        } else {
#pragma unroll
            for (int q = 0; q < 8; q++) tb[q] = (__bf16)0.f;
        }
        __syncthreads();
        *(bf16x8*)awr = *(bf16x8*)ta;
        *(bf16x8*)bwr = *(bf16x8*)tb;
        __syncthreads();
        bf16x8 af[2], bfr[2];
#pragma unroll
        for (int i = 0; i < 2; i++) af[i] = *(bf16x8*)&As[(wm + i * 16 + lr) * 40 + lq * 8];
#pragma unroll
        for (int j = 0; j < 2; j++) bfr[j] = *(bf16x8*)&Bs[(wn + j * 16 + lr) * 40 + lq * 8];
#pragma unroll
        for (int i = 0; i < 2; i++)
#pragma unroll
            for (int j = 0; j < 2; j++)
                acc[i][j] = __builtin_amdgcn_mfma_f32_16x16x32_bf16(af[i], bfr[j], acc[i][j], 0, 0, 0);
    }
#pragma unroll
    for (int i = 0; i < 2; i++) {
#pragma unroll
        for (int r4 = 0; r4 < 4; r4++) {
            int gm = m0 + wm + i * 16 + lq * 4 + r4;
#pragma unroll
            for (int j = 0; j < 2; j++) {
                int gn = n0 + wn + j * 16 + lr;
                if (gn < N) {
                    float v = acc[i][j][r4] * alpha + (bias ? bias[gn] : 0.f);
                    if (BF16OUT) ((bf16*)Cv)[cZ * z + (size_t)gm * ldc + gn] = __float2bfloat16(v);
                    else         ((float*)Cv)[cZ * z + (size_t)gm * ldc + gn] = v;
                }
            }
        }
    }
}

// qkv = (emb + t*wt + bt) @ in_w^T + in_b, fused time-embedding in A-staging
__global__ __launch_bounds__(256) void k_qkv(
    const float* __restrict__ emb, const float* __restrict__ t,
    const float* __restrict__ wt, const float* __restrict__ bt,
    const float* __restrict__ in_w, const float* __restrict__ in_b, float* ws)
{
    int m0 = blockIdx.y * 64, n0 = blockIdx.x * 64;
    __shared__ __bf16 As[64 * 40];
    __shared__ __bf16 Bs[64 * 40];
    int tid = threadIdx.x;
    int r = tid >> 2, quad = tid & 3;
    int w = tid >> 6, lane = tid & 63;
    int wm = (w & 1) * 32, wn = (w >> 1) * 32;
    int lr = lane & 15, lq = lane >> 4;
    f32x4 acc[2][2];
#pragma unroll
    for (int i = 0; i < 2; i++)
#pragma unroll
        for (int j = 0; j < 2; j++) acc[i][j] = (f32x4){0.f, 0.f, 0.f, 0.f};

    float trow = t[m0 + r];
    const float* arow = emb + (size_t)(m0 + r) * DD + quad * 8;
    const float* brow = in_w + (size_t)(n0 + r) * DD + quad * 8;
    __bf16* awr = &As[r * 40 + quad * 8];
    __bf16* bwr = &Bs[r * 40 + quad * 8];

    for (int k0 = 0; k0 < DD; k0 += 32) {
        __bf16 ta[8] __attribute__((aligned(16)));
        __bf16 tb[8] __attribute__((aligned(16)));
#pragma unroll
        for (int q = 0; q < 4; q++) {
            float2 e = *(const float2*)(arow + k0 + 2 * q);
            float2 wv = *(const float2*)(wt + k0 + quad * 8 + 2 * q);
            float2 bv = *(const float2*)(bt + k0 + quad * 8 + 2 * q);
            ta[2 * q]     = (__bf16)(e.x + trow * wv.x + bv.x);
            ta[2 * q + 1] = (__bf16)(e.y + trow * wv.y + bv.y);
            float2 f = *(const float2*)(brow + k0 + 2 * q);
            tb[2 * q] = (__bf16)f.x; tb[2 * q + 1] = (__bf16)f.y;
        }
        __syncthreads();
        *(bf16x8*)awr = *(bf16x8*)ta;
        *(bf16x8*)bwr = *(bf16x8*)tb;
        __syncthreads();
        bf16x8 af[2], bfr[2];
#pragma unroll
        for (int i = 0; i < 2; i++) af[i] = *(bf16x8*)&As[(wm + i * 16 + lr) * 40 + lq * 8];
#pragma unroll
        for (int j = 0; j < 2; j++) bfr[j] = *(bf16x8*)&Bs[(wn + j * 16 + lr) * 40 + lq * 8];
#pragma unroll
        for (int i = 0; i < 2; i++)
#pragma unroll
            for (int j = 0; j < 2; j++)
                acc[i][j] = __builtin_amdgcn_mfma_f32_16x16x32_bf16(af[i], bfr[j], acc[i][j], 0, 0, 0);
    }
    float* qkv = ws + OFF_QKV;
#pragma unroll
    for (int i = 0; i < 2; i++)
#pragma unroll
        for (int r4 = 0; r4 < 4; r4++) {
            int gm = m0 + wm + i * 16 + lq * 4 + r4;
#pragma unroll
            for (int j = 0; j < 2; j++) {
                int gn = n0 + wn + j * 16 + lr;
                qkv[(size_t)gm * (3 * DD) + gn] = acc[i][j][r4] + in_b[gn];
            }
        }
}

// attn_out = (ctx_part0 + ctx_part1) @ out_w^T + out_b, partial-sum fused in A-staging
__global__ __launch_bounds__(256) void k_oproj(
    const float* __restrict__ out_w, const float* __restrict__ out_b, float* ws)
{
    int m0 = blockIdx.y * 64, n0 = blockIdx.x * 64;
    __shared__ __bf16 As[64 * 40];
    __shared__ __bf16 Bs[64 * 40];
    int tid = threadIdx.x;
    int r = tid >> 2, quad = tid & 3;
    int w = tid >> 6, lane = tid & 63;
    int wm = (w & 1) * 32, wn = (w >> 1) * 32;
    int lr = lane & 15, lq = lane >> 4;
    f32x4 acc[2][2];
#pragma unroll
    for (int i = 0; i < 2; i++)
#pragma unroll
        for (int j = 0; j < 2; j++) acc[i][j] = (f32x4){0.f, 0.f, 0.f, 0.f};

    const float* a0 = ws + OFF_CTX + (size_t)(m0 + r) * DD + quad * 8;
    const float* a1 = ws + OFF_HR  + (size_t)(m0 + r) * DD + quad * 8;
    const float* brow = out_w + (size_t)(n0 + r) * DD + quad * 8;
    __bf16* awr = &As[r * 40 + quad * 8];
    __bf16* bwr = &Bs[r * 40 + quad * 8];

    for (int k0 = 0; k0 < DD; k0 += 32) {
        __bf16 ta[8] __attribute__((aligned(16)));
        __bf16 tb[8] __attribute__((aligned(16)));
#pragma unroll
        for (int q = 0; q < 4; q++) {
            float2 x = *(const float2*)(a0 + k0 + 2 * q);
            float2 y = *(const float2*)(a1 + k0 + 2 * q);
            ta[2 * q]     = (__bf16)(x.x + y.x);
            ta[2 * q + 1] = (__bf16)(x.y + y.y);
            float2 f = *(const float2*)(brow + k0 + 2 * q);
            tb[2 * q] = (__bf16)f.x; tb[2 * q + 1] = (__bf16)f.y;
        }
        __syncthreads();
        *(bf16x8*)awr = *(bf16x8*)ta;
        *(bf16x8*)bwr = *(bf16x8*)tb;
        __syncthreads();
        bf16x8 af[2], bfr[2];
#pragma unroll
        for (int i = 0; i < 2; i++) af[i] = *(bf16x8*)&As[(wm + i * 16 + lr) * 40 + lq * 8];
#pragma unroll
        for (int j = 0; j < 2; j++) bfr[j] = *(bf16x8*)&Bs[(wn + j * 16 + lr) * 40 + lq * 8];
#pragma unroll
        for (int i = 0; i < 2; i++)
#pragma unroll
            for (int j = 0; j < 2; j++)
                acc[i][j] = __builtin_amdgcn_mfma_f32_16x16x32_bf16(af[i], bfr[j], acc[i][j], 0, 0, 0);
    }
    float* att = ws + OFF_ATT;
#pragma unroll
    for (int i = 0; i < 2; i++)
#pragma unroll
        for (int r4 = 0; r4 < 4; r4++) {
            int gm = m0 + wm + i * 16 + lq * 4 + r4;
#pragma unroll
            for (int j = 0; j < 2; j++) {
                int gn = n0 + wn + j * 16 + lr;
                att[(size_t)gm * DD + gn] = acc[i][j][r4] + out_b[gn];
            }
        }
}

// logits = relu(H0[:,l*128:]+delta) @ ref_w2[l]^T + ref_b2[l], hrelu fused in A-staging
__global__ __launch_bounds__(256) void k_lgemm(
    const float* __restrict__ rw1, const float* __restrict__ rw2,
    const float* __restrict__ rb2, int l, float* ws)
{
    int m0 = blockIdx.y * 64, n0 = blockIdx.x * 64;
    int i_int = m0 / NT;
    int nbase = m0 % NT;
    __shared__ __bf16 As[64 * 40];
    __shared__ __bf16 Bs[64 * 40];
    __shared__ float dsh[128];
    int tid = threadIdx.x;
    if (tid < 128) {
        float s_i = ws[OFF_SCAL + SC_START + i_int], e_i = ws[OFF_SCAL + SC_END + i_int];
        const float* wr = rw1 + (size_t)(l * 128 + tid) * 514;
        dsh[tid] = s_i * wr[512] + e_i * wr[513];
    }
    __syncthreads();
    int r = tid >> 2, quad = tid & 3;
    int w = tid >> 6, lane = tid & 63;
    int wm = (w & 1) * 32, wn = (w >> 1) * 32;
    int lr = lane & 15, lq = lane >> 4;
    f32x4 acc[2][2];
#pragma unroll
    for (int i = 0; i < 2; i++)
#pragma unroll
        for (int j = 0; j < 2; j++) acc[i][j] = (f32x4){0.f, 0.f, 0.f, 0.f};

    int gnr = n0 + r;
    const float* arow = ws + OFF_H0 + (size_t)(nbase + r) * 384 + l * 128 + quad * 8;
    const float* brow = rw2 + (size_t)gnr * 128 + quad * 8;
    __bf16* awr = &As[r * 40 + quad * 8];
    __bf16* bwr = &Bs[r * 40 + quad * 8];

    for (int k0 = 0; k0 < 128; k0 += 32) {
        __bf16 ta[8] __attribute__((aligned(16)));
        __bf16 tb[8] __attribute__((aligned(16)));
#pragma unroll
        for (int q = 0; q < 4; q++) {
            float2 f = *(const float2*)(arow + k0 + 2 * q);
            int jj = k0 + quad * 8 + 2 * q;
            ta[2 * q]     = (__bf16)fmaxf(f.x + dsh[jj], 0.f);
            ta[2 * q + 1] = (__bf16)fmaxf(f.y + dsh[jj + 1], 0.f);
        }
        if (gnr < 200) {
#pragma unroll
            for (int q = 0; q < 4; q++) {
                float2 f = *(const float2*)(brow + k0 + 2 * q);
                tb[2 * q] = (__bf16)f.x; tb[2 * q + 1] = (__bf16)f.y;
            }
        } else {
#pragma unroll
            for (int q = 0; q < 8; q++) tb[q] = (__bf16)0.f;
        }
        __syncthreads();
        *(bf16x8*)awr = *(bf16x8*)ta;
        *(bf16x8*)bwr = *(bf16x8*)tb;
        __syncthreads();
        bf16x8 af[2], bfr[2];
#pragma unroll
        for (int i = 0; i < 2; i++) af[i] = *(bf16x8*)&As[(wm + i * 16 + lr) * 40 + lq * 8];
#pragma unroll
        for (int j = 0; j < 2; j++) bfr[j] = *(bf16x8*)&Bs[(wn + j * 16 + lr) * 40 + lq * 8];
#pragma unroll
        for (int i = 0; i < 2; i++)
#pragma unroll
            for (int j = 0; j < 2; j++)
                acc[i][j] = __builtin_amdgcn_mfma_f32_16x16x32_bf16(af[i], bfr[j], acc[i][j], 0, 0, 0);
    }
    float* LG = ws + OFF_LG;
#pragma unroll
    for (int i = 0; i < 2; i++)
#pragma unroll
        for (int r4 = 0; r4 < 4; r4++) {
            int gm = m0 + wm + i * 16 + lq * 4 + r4;
#pragma unroll
            for (int j = 0; j < 2; j++) {
                int gn = n0 + wn + j * 16 + lr;
                if (gn < 200) LG[(size_t)gm * 200 + gn] = acc[i][j][r4] + rb2[gn];
            }
        }
}

// per-row softmax stats over bf16 score matrix (first MHA)
__global__ __launch_bounds__(256) void k_rstats(const bf16* __restrict__ S, float* ws) {
    int wave = threadIdx.x >> 6, lane = threadIdx.x & 63;
    int row = blockIdx.x * 4 + wave;  // < NH*NT
    const bf16* p = S + (size_t)row * NT;
    float v[24], m = -1e30f;
#pragma unroll
    for (int t = 0; t < 24; t++) { v[t] = __bfloat162float(p[t * 64 + lane]); m = fmaxf(m, v[t]); }
    for (int off = 32; off; off >>= 1) m = fmaxf(m, __shfl_xor(m, off));
    float s = 0.f;
#pragma unroll
    for (int t = 0; t < 24; t++) s += __expf(v[t] - m);
    for (int off = 32; off; off >>= 1) s += __shfl_xor(s, off);
    if (lane == 0) { ws[OFF_RST + 2 * row] = m; ws[OFF_RST + 2 * row + 1] = 1.f / s; }
}

// fused rowmax + E0 = exp(S0 - rowmax) in place (no stats needed downstream)
__global__ __launch_bounds__(256) void k_rse(float* ws) {
    bf16* S = (bf16*)(ws + OFF_S);
    int wave = threadIdx.x >> 6, lane = threadIdx.x & 63;
    int row = blockIdx.x * 4 + wave;  // < NH*NT
    unsigned short* p = (unsigned short*)(S + (size_t)row * NT);
    union { uint4 u; unsigned short s[8]; } b[3];
    float v[24], m = -1e30f;
#pragma unroll
    for (int c = 0; c < 3; c++) {
        b[c].u = *(const uint4*)(p + c * 512 + lane * 8);
#pragma unroll
        for (int q = 0; q < 8; q++) {
            v[c * 8 + q] = __uint_as_float((unsigned)b[c].s[q] << 16);
            m = fmaxf(m, v[c * 8 + q]);
        }
    }
    for (int off = 32; off; off >>= 1) m = fmaxf(m, __shfl_xor(m, off));
#pragma unroll
    for (int c = 0; c < 3; c++) {
#pragma unroll
        for (int q = 0; q < 8; q++) {
            bf16 ov = __float2bfloat16(__expf(v[c * 8 + q] - m));
            b[c].s[q] = *(unsigned short*)&ov;
        }
        *(uint4*)(p + c * 512 + lane * 8) = b[c].u;
    }
}

// Vt[h][n][k] = qkv[k][2D + h*128 + n]
__global__ void k_vt(float* ws) {
    __shared__ float tb[32][33];
    int h = blockIdx.z, k0 = blockIdx.x * 32, n0 = blockIdx.y * 32;
    int tid = threadIdx.x;
    const float* qkv = ws + OFF_QKV;
    float* Vt = ws + OFF_X;
    int kk = tid >> 5, nn = tid & 31;
#pragma unroll
    for (int p = 0; p < 4; p++)
        tb[kk + p * 8][nn] = qkv[(size_t)(k0 + kk + p * 8) * (3 * DD) + 2 * DD + h * DHD + n0 + nn];
    __syncthreads();
    int nn2 = tid >> 5, kk2 = tid & 31;
#pragma unroll
    for (int p = 0; p < 4; p++)
        Vt[(size_t)(h * DHD + n0 + nn2 + p * 8) * NT + k0 + kk2] = tb[kk2][nn2 + p * 8];
}

// softmax(S_h) @ V_h, 64x64 tiles, split-K=2 into disjoint partial buffers (no atomics)
// grid: (4 = 2 n-tiles x 2 ks, 24 m-tiles, 4 heads)
__global__ __launch_bounds__(256) void k_pv(const bf16* __restrict__ S, float* ws) {
    int h = blockIdx.z;
    int m0 = blockIdx.y * 64;
    int n0 = (blockIdx.x & 1) * 64;
    int ks = blockIdx.x >> 1;
    const int KCH = NT / 2;   // 768
    int kbeg = ks * KCH;
    __shared__ __bf16 As[64 * 40];
    __shared__ __bf16 Bs[64 * 40];
    int tid = threadIdx.x;
    int r = tid >> 2, quad = tid & 3;
    int w = tid >> 6, lane = tid & 63;
    int wm = (w & 1) * 32, wn = (w >> 1) * 32;
    int lr = lane & 15, lq = lane >> 4;
    const float* rst = ws + OFF_RST;
    const float* Vt = ws + OFF_X + (size_t)h * DHD * NT;
    const bf16* Sh = S + (size_t)h * NT * NT;
    int row = m0 + r;
    float mrow = rst[2 * (h * NT + row)];
    const unsigned short* srow = (const unsigned short*)(Sh + (size_t)row * NT) + quad * 8;
    const float* brow = Vt + (size_t)(n0 + r) * NT + quad * 8;
    __bf16* awr = &As[r * 40 + quad * 8];
    __bf16* bwr = &Bs[r * 40 + quad * 8];
    f32x4 acc[2][2];
#pragma unroll
    for (int i = 0; i < 2; i++)
#pragma unroll
        for (int j = 0; j < 2; j++) acc[i][j] = (f32x4){0.f, 0.f, 0.f, 0.f};

    for (int k0 = kbeg; k0 < kbeg + KCH; k0 += 32) {
        union { uint4 u; unsigned short s[8]; } bb;
        bb.u = *(const uint4*)(srow + k0);
        __bf16 ta[8] __attribute__((aligned(16)));
        __bf16 tb[8] __attribute__((aligned(16)));
#pragma unroll
        for (int q = 0; q < 8; q++)
            ta[q] = (__bf16)__expf(__uint_as_float((unsigned)bb.s[q] << 16) - mrow);
#pragma unroll
        for (int q = 0; q < 4; q++) {
            float2 f = *(const float2*)(brow + k0 + 2 * q);
            tb[2 * q] = (__bf16)f.x; tb[2 * q + 1] = (__bf16)f.y;
        }
        __syncthreads();
        *(bf16x8*)awr = *(bf16x8*)ta;
        *(bf16x8*)bwr = *(bf16x8*)tb;
        __syncthreads();
        bf16x8 af[2], bfr[2];
#pragma unroll
        for (int i = 0; i < 2; i++) af[i] = *(bf16x8*)&As[(wm + i * 16 + lr) * 40 + lq * 8];
#pragma unroll
        for (int j = 0; j < 2; j++) bfr[j] = *(bf16x8*)&Bs[(wn + j * 16 + lr) * 40 + lq * 8];
#pragma unroll
        for (int i = 0; i < 2; i++)
#pragma unroll
            for (int j = 0; j < 2; j++)
                acc[i][j] = __builtin_amdgcn_mfma_f32_16x16x32_bf16(af[i], bfr[j], acc[i][j], 0, 0, 0);
    }
    float* dst = ws + (ks == 0 ? OFF_CTX : OFF_HR);
#pragma unroll
    for (int i = 0; i < 2; i++)
#pragma unroll
        for (int r4 = 0; r4 < 4; r4++) {
            int gm = m0 + wm + i * 16 + lq * 4 + r4;
            float ri = rst[2 * (h * NT + gm) + 1];
#pragma unroll
            for (int j = 0; j < 2; j++) {
                int gn = n0 + wn + j * 16 + lr;
                dst[(size_t)gm * DD + h * DHD + gn] = acc[i][j][r4] * ri;
            }
        }
}

__global__ void k_pool(float* ws) {
    int col = blockIdx.x * 256 + threadIdx.x;
    int r0 = blockIdx.y * 128;
    const float* att = ws + OFF_ATT;
    float s = 0.f;
    for (int r = 0; r < 128; r++) s += att[(size_t)(r0 + r) * DD + col];
    atomicAdd(&ws[OFF_POOL + col], s);
}

__global__ void k_head(const float* __restrict__ icw1, const float* __restrict__ icb1,
                       const float* __restrict__ icw2, const float* __restrict__ icb2,
                       float* ws, float* out) {
    __shared__ float h1[128];
    __shared__ float lg[MAXI];
    int tid = threadIdx.x;  // 128 threads
    float a = 0.f;
    for (int c = 0; c < DD; c++) a += icw1[(size_t)tid * DD + c] * ws[OFF_POOL + c];
    h1[tid] = fmaxf(a * (1.0f / NT) + icb1[tid], 0.f);
    __syncthreads();
    if (tid < MAXI) {
        float s = icb2[tid];
        for (int j = 0; j < 128; j++) s += icw2[tid * 128 + j] * h1[j];
        lg[tid] = s;
    }
    __syncthreads();
    if (tid == 0) {
        int best = 0; float bv = lg[0];
        for (int m = 1; m < MAXI; m++) if (lg[m] > bv) { bv = lg[m]; best = m; }
        int ni = best + 1;
        for (int i = 0; i < MAXI; i++) out[10 + i] = (i < ni) ? 1.f : 0.f;
    }
}

// avec/bvec = wq @ qp_w[:,512/513]; b2 = wq @ qp_b + bq
__global__ void k_uv(const float* __restrict__ in_w, const float* __restrict__ qp_w,
                     const float* __restrict__ qp_b, const float* __restrict__ in_b, float* ws) {
    __shared__ float su[DD], sv[DD], sb[DD];
    int tid = threadIdx.x;
    for (int c = tid; c < DD; c += 256) {
        su[c] = qp_w[c * 514 + 512]; sv[c] = qp_w[c * 514 + 513]; sb[c] = qp_b[c];
    }
    __syncthreads();
    int j = blockIdx.x * 256 + tid;
    float a = 0.f, b = 0.f, c2 = 0.f;
    for (int c = 0; c < DD; c++) {
        float w = in_w[(size_t)j * DD + c];
        a += w * su[c]; b += w * sv[c]; c2 += w * sb[c];
    }
    ws[OFF_AV + j] = a; ws[OFF_BV + j] = b; ws[OFF_B2 + j] = c2 + in_b[j];
}

// A[h,n] = avec_h . K2[n,h*128:] / sqrt(DH);  B likewise
__global__ __launch_bounds__(256) void k_ab(float* ws) {
    int wave = threadIdx.x >> 6, lane = threadIdx.x & 63;
    int row = blockIdx.x * 4 + wave;   // = h*NT + n
    int h = row / NT, n = row % NT;
    const float* k2 = ws + OFF_K2 + (size_t)n * DD + h * DHD;
    const float* av = ws + OFF_AV + h * DHD;
    const float* bv = ws + OFF_BV + h * DHD;
    int d = lane * 2;
    float a = av[d] * k2[d] + av[d + 1] * k2[d + 1];
    float b = bv[d] * k2[d] + bv[d + 1] * k2[d + 1];
    for (int off = 32; off; off >>= 1) { a += __shfl_xor(a, off); b += __shfl_xor(b, off); }
    if (lane == 0) { ws[OFF_AARR + row] = a * RSQRT_DH; ws[OFF_BARR + row] = b * RSQRT_DH; }
}

// per (interval,row): softmax over 100 bins dotted with weight_params, both halves
__global__ __launch_bounds__(256) void k_softdot(const float* __restrict__ wp, float* ws) {
    int wave = threadIdx.x >> 6, lane = threadIdx.x & 63;
    int r = blockIdx.x * 4 + wave;   // < MAXI*NT
    if (blockIdx.x == 0 && threadIdx.x < 10) ws[OFF_SCAL + SC_DSDE + threadIdx.x] = 0.f;
    const float* L = ws + OFF_LG + (size_t)r * 200;
#pragma unroll
    for (int half = 0; half < 2; half++) {
        const float* Lh = L + half * NBINS;
        float x1 = (lane < NBINS) ? Lh[lane] : -1e30f;
        float x2 = (lane + 64 < NBINS) ? Lh[lane + 64] : -1e30f;
        float m = fmaxf(x1, x2);
        for (int off = 32; off; off >>= 1) m = fmaxf(m, __shfl_xor(m, off));
        float p1 = (lane < NBINS) ? __expf(x1 - m) : 0.f;
        float p2 = (lane + 64 < NBINS) ? __expf(x2 - m) : 0.f;
        float den = p1 + p2;
        float num = p1 * ((lane < NBINS) ? wp[lane] : 0.f) + p2 * ((lane + 64 < NBINS) ? wp[lane + 64] : 0.f);
        for (int off = 32; off; off >>= 1) { den += __shfl_xor(den, off); num += __shfl_xor(num, off); }
        if (lane == 0) ws[(half ? OFF_EOFF : OFF_SOFF) + r] = num / den;
    }
}

// build U[h][c][k], c = i*3 + {0:g, 1:g*so, 2:g*eo}; g = exp(s_i*A + e_i*B - mg)
__global__ __launch_bounds__(256) void k_gu(float* ws) {
    int i = blockIdx.x / NH, h = blockIdx.x % NH;
    __shared__ float red[256];
    int tid = threadIdx.x;
    float s_i = ws[OFF_SCAL + SC_START + i], e_i = ws[OFF_SCAL + SC_END + i];
    const float* Ar = ws + OFF_AARR + h * NT;
    const float* Br = ws + OFF_BARR + h * NT;
    float vals[6], mx = -1e30f;
#pragma unroll
    for (int t = 0; t < 6; t++) {
        int k = t * 256 + tid;
        vals[t] = s_i * Ar[k] + e_i * Br[k];
        mx = fmaxf(mx, vals[t]);
    }
    red[tid] = mx; __syncthreads();
    for (int s = 128; s; s >>= 1) {
        if (tid < s) red[tid] = fmaxf(red[tid], red[tid + s]);
        __syncthreads();
    }
    float mg = red[0];
    float* Uh = ws + OFF_HR + (size_t)h * 15 * NT;
    const float* so = ws + OFF_SOFF + i * NT;
    const float* eo = ws + OFF_EOFF + i * NT;
#pragma unroll
    for (int t = 0; t < 6; t++) {
        int k = t * 256 + tid;
        float g = __expf(vals[t] - mg);
        Uh[(i * 3 + 0) * NT + k] = g;
        Uh[(i * 3 + 1) * NT + k] = g * so[k];
        Uh[(i * 3 + 2) * NT + k] = g * eo[k];
    }
}

// P_ks[h*NT+m][c] = sum_{k in chunk ks} E0[h][m][k]*U[h][c][k]; MFMA, disjoint slices
// grid: (8 k-splits, 12 m-tiles, 4 heads)
__global__ __launch_bounds__(256) void k_eg(const bf16* __restrict__ E0, float* ws) {
    int h = blockIdx.z;
    int m0 = blockIdx.y * 128;
    int ks = blockIdx.x;
    const int KCH = NT / 8;   // 192
    __shared__ __bf16 As[128 * 40];
    __shared__ __bf16 Bs[16 * 40];
    int tid = threadIdx.x;
    int w = tid >> 6, lane = tid & 63;
    int lr = lane & 15, lq = lane >> 4;
    int r = tid >> 1, half = tid & 1;
    const bf16* Sh = E0 + (size_t)h * NT * NT;
    const unsigned short* arow = (const unsigned short*)(Sh + (size_t)(m0 + r) * NT) + half * 16;
    const float* Uh = ws + OFF_HR + (size_t)h * 15 * NT;
    int wm = w * 32;
    f32x4 acc[2];
    acc[0] = (f32x4){0.f, 0.f, 0.f, 0.f};
    acc[1] = (f32x4){0.f, 0.f, 0.f, 0.f};
    int bc = tid >> 3, bk = tid & 7;

    for (int k0 = ks * KCH; k0 < ks * KCH + KCH; k0 += 32) {
        uint4 a0 = *(const uint4*)(arow + k0);
        uint4 a1 = *(const uint4*)(arow + k0 + 8);
        float4 uf = {0.f, 0.f, 0.f, 0.f};
        if (tid < 128 && bc < 15) uf = *(const float4*)(Uh + (size_t)bc * NT + k0 + bk * 4);
        __syncthreads();
        *(uint4*)&As[r * 40 + half * 16] = a0;
        *(uint4*)&As[r * 40 + half * 16 + 8] = a1;
        if (tid < 128) {
            __bf16* bw = &Bs[bc * 40 + bk * 4];
            bw[0] = (__bf16)uf.x; bw[1] = (__bf16)uf.y; bw[2] = (__bf16)uf.z; bw[3] = (__bf16)uf.w;
        }
        __syncthreads();
        bf16x8 bf0 = *(bf16x8*)&Bs[lr * 40 + lq * 8];
        bf16x8 af0 = *(bf16x8*)&As[(wm + lr) * 40 + lq * 8];
        bf16x8 af1 = *(bf16x8*)&As[(wm + 16 + lr) * 40 + lq * 8];
        acc[0] = __builtin_amdgcn_mfma_f32_16x16x32_bf16(af0, bf0, acc[0], 0, 0, 0);
        acc[1] = __builtin_amdgcn_mfma_f32_16x16x32_bf16(af1, bf0, acc[1], 0, 0, 0);
    }
    float* P = ws + OFF_LG + (size_t)ks * PSLICE;
    if (lr < 15) {
#pragma unroll
        for (int i = 0; i < 2; i++)
#pragma unroll
            for (int r4 = 0; r4 < 4; r4++) {
                int gm = m0 + wm + i * 16 + lq * 4 + r4;
                P[(size_t)(h * NT + gm) * 16 + lr] = acc[i][r4];
            }
    }
}

// sum 8 slices, form ratios, reduce to ds/de. 24 blocks x 256 threads, one row each.
__global__ __launch_bounds__(256) void k_fin(float* ws) {
    __shared__ float part[4][10];
    int tid = threadIdx.x;
    int w = tid >> 6, lane = tid & 63;
    int row = blockIdx.x * 256 + tid;   // < NH*NT
    float acc[15];
#pragma unroll
    for (int c = 0; c < 15; c++) acc[c] = 0.f;
    for (int ks = 0; ks < 8; ks++) {
        const float* Pr = ws + OFF_LG + (size_t)ks * PSLICE + (size_t)row * 16;
#pragma unroll
        for (int c = 0; c < 15; c++) acc[c] += Pr[c];
    }
    float loc[10];
#pragma unroll
    for (int i = 0; i < MAXI; i++) {
        float den = acc[i * 3];
        loc[i]        = acc[i * 3 + 1] / den;
        loc[MAXI + i] = acc[i * 3 + 2] / den;
    }
#pragma unroll
    for (int c = 0; c < 10; c++)
        for (int off = 32; off; off >>= 1) loc[c] += __shfl_xor(loc[c], off);
    if (lane == 0) {
#pragma unroll
        for (int c = 0; c < 10; c++) part[w][c] = loc[c];
    }
    __syncthreads();
    if (tid < 10) {
        float s = part[0][tid] + part[1][tid] + part[2][tid] + part[3][tid];
        atomicAdd(&ws[OFF_SCAL + SC_DSDE + tid], s);
    }
}

__global__ void k_update(float* ws) {
    int tid = threadIdx.x;
    if (tid < MAXI) {
        ws[OFF_SCAL + SC_START + tid] += ws[OFF_SCAL + SC_DSDE + tid] * 0.25f;        // 1/H
        ws[OFF_SCAL + SC_END + tid]   += ws[OFF_SCAL + SC_DSDE + MAXI + tid] * 0.25f;
    }
}

__global__ void k_final(const float* __restrict__ ws, float* out) {
    int tid = threadIdx.x;
    if (tid < MAXI) {
        out[2 * tid]     = ws[OFF_SCAL + SC_START + tid];
        out[2 * tid + 1] = ws[OFF_SCAL + SC_END + tid];
    }
}

// -------------------------------------------------------------------------
extern "C" void kernel_launch(void* const* d_in, const int* in_sizes, int n_in,
                              void* d_out, int out_size, void* d_ws, size_t ws_size,
                              hipStream_t stream) {
    const float* emb    = (const float*)d_in[0];
    const float* tpos   = (const float*)d_in[1];
    const float* W_time = (const float*)d_in[3];
    const float* b_time = (const float*)d_in[4];
    const float* in_w   = (const float*)d_in[5];
    const float* in_b   = (const float*)d_in[6];
    const float* out_w  = (const float*)d_in[7];
    const float* out_b  = (const float*)d_in[8];
    const float* ic_w1  = (const float*)d_in[9];
    const float* ic_b1  = (const float*)d_in[10];
    const float* ic_w2  = (const float*)d_in[11];
    const float* ic_b2  = (const float*)d_in[12];
    const float* ref_w1 = (const float*)d_in[13];
    const float* ref_b1 = (const float*)d_in[14];
    const float* ref_w2 = (const float*)d_in[15];
    const float* ref_b2 = (const float*)d_in[16];
    const float* wp     = (const float*)d_in[17];
    const float* qp_w   = (const float*)d_in[18];
    const float* qp_b   = (const float*)d_in[19];
    float* ws  = (float*)d_ws;
    float* out = (float*)d_out;
    bf16* S = (bf16*)(ws + OFF_S);

    k_init<<<2, 256, 0, stream>>>(ws);
    k_tgrid<<<1, 256, 0, stream>>>(tpos, ws);
    // weight-only precompute: qpT, M2 = wq @ qp_w[:,:512], avec/bvec/b2
    k_qpt<<<dim3(16, 16), 256, 0, stream>>>(qp_w, ws);
    k_g64<0><<<dim3(8, 8, 1), 256, 0, stream>>>(
        in_w, DD, 0, ws + OFF_QPT, 512, 0, ws + OFF_M2, 512, 0, 512, DD, 1.f, nullptr);
    k_uv<<<2, 256, 0, stream>>>(in_w, qp_w, qp_b, in_b, ws);

    // qkv = (emb + t*wt + bt) @ in_w^T + in_b  (x fused into staging)
    k_qkv<<<dim3(24, 24), 256, 0, stream>>>(emb, tpos, W_time, b_time, in_w, in_b, ws);
    // scores per head -> S (bf16)
    k_mgemm<1><<<dim3(12, 12, NH), 256, 0, stream>>>(
        ws + OFF_QKV, 3 * DD, DHD, ws + OFF_QKV + DD, 3 * DD, DHD,
        S, NT, (long long)NT * NT, NT, DHD, RSQRT_DH, nullptr);
    k_rstats<<<NH * NT / 4, 256, 0, stream>>>(S, ws);
    k_vt<<<dim3(NT / 32, DHD / 32, NH), 256, 0, stream>>>(ws);
    k_pv<<<dim3(4, NT / 64, NH), 256, 0, stream>>>(S, ws);
    // attn_out = (ctx0 + ctx1) @ out_w^T + out_b
    k_oproj<<<dim3(8, 24), 256, 0, stream>>>(out_w, out_b, ws);

    k_pool<<<dim3(2, 12), 256, 0, stream>>>(ws);
    k_head<<<1, 128, 0, stream>>>(ic_w1, ic_b1, ic_w2, ic_b2, ws, out);

    // K2 = attn_out @ wk^T + bk
    k_g64<0><<<dim3(8, 24, 1), 256, 0, stream>>>(
        ws + OFF_ATT, DD, 0, in_w + (size_t)DD * DD, DD, 0, ws + OFF_K2, DD, 0, DD, DD, 1.f, in_b + DD);
    // Q0 = attn_out @ M2^T + b2   (QP0 eliminated)
    k_g64<0><<<dim3(8, 24, 1), 256, 0, stream>>>(
        ws + OFF_ATT, DD, 0, ws + OFF_M2, 512, 0, ws + OFF_Q0, DD, 0, DD, DD, 1.f, ws + OFF_B2);
    // H0 = attn_out @ ref_w1[:, :, :512]^T + ref_b1
    k_g64<0><<<dim3(6, 24, 1), 256, 0, stream>>>(
        ws + OFF_ATT, DD, 0, ref_w1, 514, 0, ws + OFF_H0, 384, 0, 384, DD, 1.f, ref_b1);
    k_ab<<<NH * NT / 4, 256, 0, stream>>>(ws);

    // S0 per head -> S (bf16), then fused rowmax+exp in place
    k_mgemm<1><<<dim3(12, 12, NH), 256, 0, stream>>>(
        ws + OFF_Q0, DD, DHD, ws + OFF_K2, DD, DHD,
        S, NT, (long long)NT * NT, NT, DHD, RSQRT_DH, nullptr);
    k_rse<<<NH * NT / 4, 256, 0, stream>>>(ws);

    for (int l = 0; l < NL; l++) {
        k_lgemm<<<dim3(4, 120), 256, 0, stream>>>(ref_w1, ref_w2 + (size_t)l * 200 * 128,
                                                  ref_b2 + l * 200, l, ws);
        k_softdot<<<MAXI * NT / 4, 256, 0, stream>>>(wp, ws);
        k_gu<<<MAXI * NH, 256, 0, stream>>>(ws);
        k_eg<<<dim3(8, NT / 128, NH), 256, 0, stream>>>(S, ws);
        k_fin<<<NH * NT / 256, 256, 0, stream>>>(ws);
        k_update<<<1, 32, 0, stream>>>(ws);
    }
    k_final<<<1, 32, 0, stream>>>(ws, out);
}

// Round 6
// 367.290 us; speedup vs baseline: 5.6168x; 1.1170x over previous
//
#include <hip/hip_runtime.h>
#include <hip/hip_bf16.h>

typedef __hip_bfloat16 bf16;
typedef __bf16 bf16x8 __attribute__((ext_vector_type(8)));
typedef float f32x4 __attribute__((ext_vector_type(4)));

#define DD   512
#define NT   1536
#define NH   4
#define DHD  128
#define NBINS 100
#define MAXI 5
#define NL   3
#define RSQRT_DH 0.08838834764831845f   // 1/sqrt(128)

// ---- workspace layout (float offsets) ----
#define OFF_X      ((size_t)0)                        // Vt[H][128][NT]
#define OFF_QKV    (OFF_X    + (size_t)NT*DD)        // N x 3D (V part unused)
#define OFF_ATT    (OFF_QKV  + (size_t)NT*3*DD)      // attn_out N x D
#define OFF_CTX    (OFF_ATT  + (size_t)NT*DD)        // pv partial ks=0
#define OFF_K2     (OFF_CTX  + (size_t)NT*DD)
#define OFF_QP0    (OFF_K2   + (size_t)NT*DD)        // reused: qpT | M2 | b2
#define OFF_Q0     (OFF_QP0  + (size_t)NT*DD)
#define OFF_H0     (OFF_Q0   + (size_t)NT*DD)        // N x 384 (3 layers x 128)
#define OFF_HR     (OFF_H0   + (size_t)NT*384)       // pv partial ks=1
#define OFF_LG     (OFF_HR   + (size_t)MAXI*NT*128)  // P slices [8][NH*NT][16]
#define OFF_AARR   (OFF_LG   + (size_t)MAXI*NT*200)  // H x N
#define OFF_BARR   (OFF_AARR + (size_t)NH*NT)
#define OFF_AV     (OFF_BARR + (size_t)NH*NT)        // D
#define OFF_BV     (OFF_AV   + (size_t)DD)
#define OFF_SOFF   (OFF_BV   + (size_t)DD)           // 5 x N
#define OFF_EOFF   (OFF_SOFF + (size_t)MAXI*NT)
#define OFF_RST    (OFF_EOFF + (size_t)MAXI*NT)      // H*N x 2 (max, 1/den)
#define OFF_POOL   (OFF_RST  + (size_t)NH*NT*2)      // D
#define OFF_SCAL   (OFF_POOL + (size_t)DD)           // 64 scalars
#define OFF_S      (OFF_SCAL + (size_t)64)           // bf16 region H*N*N
#define SC_START 0
#define SC_END   5
#define SC_DSDE  10
#define SC_CNT   20     // ticket counter (overwrites unused tmin slot)
#define OFF_QPT  (OFF_QP0)
#define OFF_M2   (OFF_QP0 + (size_t)512*512)
#define OFF_B2   (OFF_QP0 + (size_t)2*512*512)
#define PSLICE   ((size_t)NH*NT*16)

// -------------------------------------------------------------------------
// init pool + time grid (1 block)
__global__ void k_pre(const float* __restrict__ t, float* ws) {
    __shared__ float smn[256], smx[256];
    int tid = threadIdx.x;
    ws[OFF_POOL + tid] = 0.f; ws[OFF_POOL + 256 + tid] = 0.f;
    float mn = 1e30f, mx = -1e30f;
    for (int i = tid; i < NT; i += 256) { float v = t[i]; mn = fminf(mn, v); mx = fmaxf(mx, v); }
    smn[tid] = mn; smx[tid] = mx; __syncthreads();
    for (int s = 128; s; s >>= 1) {
        if (tid < s) { smn[tid] = fminf(smn[tid], smn[tid + s]); smx[tid] = fmaxf(smx[tid], smx[tid + s]); }
        __syncthreads();
    }
    if (tid == 0) {
        float tmin = smn[0], tmax = smx[0];
        for (int i = 0; i < MAXI; i++) {
            ws[OFF_SCAL + SC_START + i] = tmin + (tmax - tmin) * (float)i / 5.0f;
            ws[OFF_SCAL + SC_END + i]   = tmin + (tmax - tmin) * (float)(i + 1) / 5.0f;
        }
    }
}

// transpose qp_w[:, :512] (ld 514) -> qpT (512x512)
__global__ void k_qpt(const float* __restrict__ qp_w, float* ws) {
    __shared__ float tb[32][33];
    int c0 = blockIdx.x * 32, d0 = blockIdx.y * 32;
    int tid = threadIdx.x;
    int dd = tid >> 5, cc = tid & 31;
#pragma unroll
    for (int p = 0; p < 4; p++)
        tb[dd + p * 8][cc] = qp_w[(size_t)(d0 + dd + p * 8) * 514 + c0 + cc];
    __syncthreads();
    int cc2 = tid >> 5, dd2 = tid & 31;
    float* qpT = ws + OFF_QPT;
#pragma unroll
    for (int p = 0; p < 4; p++)
        qpT[(size_t)(c0 + cc2 + p * 8) * 512 + d0 + dd2] = tb[dd2][cc2 + p * 8];
}

// ---------------- 128x128-tile MFMA GEMM (scores) ----------------
template <int BF16OUT>
__global__ __launch_bounds__(256) void k_mgemm(
    const float* __restrict__ A, int lda, long long aZ,
    const float* __restrict__ B, int ldb, long long bZ,
    void* __restrict__ Cv, int ldc, long long cZ,
    int N, int K, float alpha, const float* __restrict__ bias)
{
    int z = blockIdx.z;
    A += (size_t)z * aZ; B += (size_t)z * bZ;
    int m0 = blockIdx.y * 128, n0 = blockIdx.x * 128;
    __shared__ __bf16 As[128 * 40];
    __shared__ __bf16 Bs[128 * 40];
    int tid = threadIdx.x;
    int r = tid >> 1, hh = tid & 1;
    int w = tid >> 6, lane = tid & 63;
    int wm = (w & 1) * 64, wn = (w >> 1) * 64;
    int lr = lane & 15, lq = lane >> 4;
    f32x4 acc[4][4];
#pragma unroll
    for (int i = 0; i < 4; i++)
#pragma unroll
        for (int j = 0; j < 4; j++) acc[i][j] = (f32x4){0.f, 0.f, 0.f, 0.f};

    int gnr = n0 + r;
    const float* arow = A + (size_t)(m0 + r) * lda + hh * 16;
    const float* brow = B + (size_t)gnr * ldb + hh * 16;
    __bf16* awr = &As[r * 40 + hh * 16];
    __bf16* bwr = &Bs[r * 40 + hh * 16];

    for (int k0 = 0; k0 < K; k0 += 32) {
        __bf16 ta[16] __attribute__((aligned(16)));
        __bf16 tb[16] __attribute__((aligned(16)));
#pragma unroll
        for (int q = 0; q < 8; q++) {
            float2 f = *(const float2*)(arow + k0 + 2 * q);
            ta[2 * q] = (__bf16)f.x; ta[2 * q + 1] = (__bf16)f.y;
        }
        if (gnr < N) {
#pragma unroll
            for (int q = 0; q < 8; q++) {
                float2 f = *(const float2*)(brow + k0 + 2 * q);
                tb[2 * q] = (__bf16)f.x; tb[2 * q + 1] = (__bf16)f.y;
            }
        } else {
#pragma unroll
            for (int q = 0; q < 16; q++) tb[q] = (__bf16)0.f;
        }
        __syncthreads();
        *(bf16x8*)awr = *(bf16x8*)ta;
        *(bf16x8*)(awr + 8) = *(bf16x8*)(ta + 8);
        *(bf16x8*)bwr = *(bf16x8*)tb;
        *(bf16x8*)(bwr + 8) = *(bf16x8*)(tb + 8);
        __syncthreads();
        bf16x8 af[4], bfr[4];
#pragma unroll
        for (int i = 0; i < 4; i++) af[i] = *(bf16x8*)&As[(wm + i * 16 + lr) * 40 + lq * 8];
#pragma unroll
        for (int j = 0; j < 4; j++) bfr[j] = *(bf16x8*)&Bs[(wn + j * 16 + lr) * 40 + lq * 8];
#pragma unroll
        for (int i = 0; i < 4; i++)
#pragma unroll
            for (int j = 0; j < 4; j++)
                acc[i][j] = __builtin_amdgcn_mfma_f32_16x16x32_bf16(af[i], bfr[j], acc[i][j], 0, 0, 0);
    }
#pragma unroll
    for (int i = 0; i < 4; i++) {
#pragma unroll
        for (int r4 = 0; r4 < 4; r4++) {
            int gm = m0 + wm + i * 16 + lq * 4 + r4;
#pragma unroll
            for (int j = 0; j < 4; j++) {
                int gn = n0 + wn + j * 16 + lr;
                if (gn < N) {
                    float v = acc[i][j][r4] * alpha + (bias ? bias[gn] : 0.f);
                    if (BF16OUT) ((bf16*)Cv)[cZ * z + (size_t)gm * ldc + gn] = __float2bfloat16(v);
                    else         ((float*)Cv)[cZ * z + (size_t)gm * ldc + gn] = v;
                }
            }
        }
    }
}

// ---------------- 64x64-tile MFMA GEMM (M2 precompute) ----------------
template <int BF16OUT>
__global__ __launch_bounds__(256) void k_g64(
    const float* __restrict__ A, int lda, long long aZ,
    const float* __restrict__ B, int ldb, long long bZ,
    void* __restrict__ Cv, int ldc, long long cZ,
    int N, int K, float alpha, const float* __restrict__ bias)
{
    int z = blockIdx.z;
    A += (size_t)z * aZ; B += (size_t)z * bZ;
    int m0 = blockIdx.y * 64, n0 = blockIdx.x * 64;
    __shared__ __bf16 As[64 * 40];
    __shared__ __bf16 Bs[64 * 40];
    int tid = threadIdx.x;
    int r = tid >> 2, quad = tid & 3;
    int w = tid >> 6, lane = tid & 63;
    int wm = (w & 1) * 32, wn = (w >> 1) * 32;
    int lr = lane & 15, lq = lane >> 4;
    f32x4 acc[2][2];
#pragma unroll
    for (int i = 0; i < 2; i++)
#pragma unroll
        for (int j = 0; j < 2; j++) acc[i][j] = (f32x4){0.f, 0.f, 0.f, 0.f};

    int gnr = n0 + r;
    const float* arow = A + (size_t)(m0 + r) * lda + quad * 8;
    const float* brow = B + (size_t)gnr * ldb + quad * 8;
    __bf16* awr = &As[r * 40 + quad * 8];
    __bf16* bwr = &Bs[r * 40 + quad * 8];

    for (int k0 = 0; k0 < K; k0 += 32) {
        __bf16 ta[8] __attribute__((aligned(16)));
        __bf16 tb[8] __attribute__((aligned(16)));
#pragma unroll
        for (int q = 0; q < 4; q++) {
            float2 f = *(const float2*)(arow + k0 + 2 * q);
            ta[2 * q] = (__bf16)f.x; ta[2 * q + 1] = (__bf16)f.y;
        }
        if (gnr < N) {
#pragma unroll
            for (int q = 0; q < 4; q++) {
                float2 f = *(const float2*)(brow + k0 + 2 * q);
                tb[2 * q] = (__bf16)f.x; tb[2 * q + 1] = (__bf16)f.y;
            }
        } else {
#pragma unroll
            for (int q = 0; q < 8; q++) tb[q] = (__bf16)0.f;
        }
        __syncthreads();
        *(bf16x8*)awr = *(bf16x8*)ta;
        *(bf16x8*)bwr = *(bf16x8*)tb;
        __syncthreads();
        bf16x8 af[2], bfr[2];
#pragma unroll
        for (int i = 0; i < 2; i++) af[i] = *(bf16x8*)&As[(wm + i * 16 + lr) * 40 + lq * 8];
#pragma unroll
        for (int j = 0; j < 2; j++) bfr[j] = *(bf16x8*)&Bs[(wn + j * 16 + lr) * 40 + lq * 8];
#pragma unroll
        for (int i = 0; i < 2; i++)
#pragma unroll
            for (int j = 0; j < 2; j++)
                acc[i][j] = __builtin_amdgcn_mfma_f32_16x16x32_bf16(af[i], bfr[j], acc[i][j], 0, 0, 0);
    }
#pragma unroll
    for (int i = 0; i < 2; i++) {
#pragma unroll
        for (int r4 = 0; r4 < 4; r4++) {
            int gm = m0 + wm + i * 16 + lq * 4 + r4;
#pragma unroll
            for (int j = 0; j < 2; j++) {
                int gn = n0 + wn + j * 16 + lr;
                if (gn < N) {
                    float v = acc[i][j][r4] * alpha + (bias ? bias[gn] : 0.f);
                    if (BF16OUT) ((bf16*)Cv)[cZ * z + (size_t)gm * ldc + gn] = __float2bfloat16(v);
                    else         ((float*)Cv)[cZ * z + (size_t)gm * ldc + gn] = v;
                }
            }
        }
    }
}

// qkv = (emb + t*wt + bt) @ in_w^T + in_b; V-tiles written directly transposed to Vt
__global__ __launch_bounds__(256) void k_qkv(
    const float* __restrict__ emb, const float* __restrict__ t,
    const float* __restrict__ wt, const float* __restrict__ bt,
    const float* __restrict__ in_w, const float* __restrict__ in_b, float* ws)
{
    int m0 = blockIdx.y * 64, n0 = blockIdx.x * 64;
    __shared__ __bf16 As[64 * 40];
    __shared__ __bf16 Bs[64 * 40];
    int tid = threadIdx.x;
    int r = tid >> 2, quad = tid & 3;
    int w = tid >> 6, lane = tid & 63;
    int wm = (w & 1) * 32, wn = (w >> 1) * 32;
    int lr = lane & 15, lq = lane >> 4;
    f32x4 acc[2][2];
#pragma unroll
    for (int i = 0; i < 2; i++)
#pragma unroll
        for (int j = 0; j < 2; j++) acc[i][j] = (f32x4){0.f, 0.f, 0.f, 0.f};

    float trow = t[m0 + r];
    const float* arow = emb + (size_t)(m0 + r) * DD + quad * 8;
    const float* brow = in_w + (size_t)(n0 + r) * DD + quad * 8;
    __bf16* awr = &As[r * 40 + quad * 8];
    __bf16* bwr = &Bs[r * 40 + quad * 8];

    for (int k0 = 0; k0 < DD; k0 += 32) {
        __bf16 ta[8] __attribute__((aligned(16)));
        __bf16 tb[8] __attribute__((aligned(16)));
#pragma unroll
        for (int q = 0; q < 4; q++) {
            float2 e = *(const float2*)(arow + k0 + 2 * q);
            float2 wv = *(const float2*)(wt + k0 + quad * 8 + 2 * q);
            float2 bv = *(const float2*)(bt + k0 + quad * 8 + 2 * q);
            ta[2 * q]     = (__bf16)(e.x + trow * wv.x + bv.x);
            ta[2 * q + 1] = (__bf16)(e.y + trow * wv.y + bv.y);
            float2 f = *(const float2*)(brow + k0 + 2 * q);
            tb[2 * q] = (__bf16)f.x; tb[2 * q + 1] = (__bf16)f.y;
        }
        __syncthreads();
        *(bf16x8*)awr = *(bf16x8*)ta;
        *(bf16x8*)bwr = *(bf16x8*)tb;
        __syncthreads();
        bf16x8 af[2], bfr[2];
#pragma unroll
        for (int i = 0; i < 2; i++) af[i] = *(bf16x8*)&As[(wm + i * 16 + lr) * 40 + lq * 8];
#pragma unroll
        for (int j = 0; j < 2; j++) bfr[j] = *(bf16x8*)&Bs[(wn + j * 16 + lr) * 40 + lq * 8];
#pragma unroll
        for (int i = 0; i < 2; i++)
#pragma unroll
            for (int j = 0; j < 2; j++)
                acc[i][j] = __builtin_amdgcn_mfma_f32_16x16x32_bf16(af[i], bfr[j], acc[i][j], 0, 0, 0);
    }
    float* qkv = ws + OFF_QKV;
    float* Vt  = ws + OFF_X;
#pragma unroll
    for (int i = 0; i < 2; i++)
#pragma unroll
        for (int j = 0; j < 2; j++) {
            int gn = n0 + wn + j * 16 + lr;
            int gmb = m0 + wm + i * 16 + lq * 4;
            float b = in_b[gn];
            f32x4 vv = acc[i][j];
            vv[0] += b; vv[1] += b; vv[2] += b; vv[3] += b;
            if (gn < 2 * DD) {
#pragma unroll
                for (int r4 = 0; r4 < 4; r4++)
                    qkv[(size_t)(gmb + r4) * (3 * DD) + gn] = vv[r4];
            } else {
                *(float4*)&Vt[(size_t)(gn - 2 * DD) * NT + gmb] = *(float4*)&vv;
            }
        }
}

// attn_out = (ctx0+ctx1) @ out_w^T + out_b, + fused column pooling
__global__ __launch_bounds__(256) void k_oproj(
    const float* __restrict__ out_w, const float* __restrict__ out_b, float* ws)
{
    int m0 = blockIdx.y * 64, n0 = blockIdx.x * 64;
    __shared__ __bf16 As[64 * 40];
    __shared__ __bf16 Bs[64 * 40];
    __shared__ float ps[64];
    int tid = threadIdx.x;
    int r = tid >> 2, quad = tid & 3;
    int w = tid >> 6, lane = tid & 63;
    int wm = (w & 1) * 32, wn = (w >> 1) * 32;
    int lr = lane & 15, lq = lane >> 4;
    f32x4 acc[2][2];
#pragma unroll
    for (int i = 0; i < 2; i++)
#pragma unroll
        for (int j = 0; j < 2; j++) acc[i][j] = (f32x4){0.f, 0.f, 0.f, 0.f};
    if (tid < 64) ps[tid] = 0.f;

    const float* a0 = ws + OFF_CTX + (size_t)(m0 + r) * DD + quad * 8;
    const float* a1 = ws + OFF_HR  + (size_t)(m0 + r) * DD + quad * 8;
    const float* brow = out_w + (size_t)(n0 + r) * DD + quad * 8;
    __bf16* awr = &As[r * 40 + quad * 8];
    __bf16* bwr = &Bs[r * 40 + quad * 8];

    for (int k0 = 0; k0 < DD; k0 += 32) {
        __bf16 ta[8] __attribute__((aligned(16)));
        __bf16 tb[8] __attribute__((aligned(16)));
#pragma unroll
        for (int q = 0; q < 4; q++) {
            float2 x = *(const float2*)(a0 + k0 + 2 * q);
            float2 y = *(const float2*)(a1 + k0 + 2 * q);
            ta[2 * q]     = (__bf16)(x.x + y.x);
            ta[2 * q + 1] = (__bf16)(x.y + y.y);
            float2 f = *(const float2*)(brow + k0 + 2 * q);
            tb[2 * q] = (__bf16)f.x; tb[2 * q + 1] = (__bf16)f.y;
        }
        __syncthreads();
        *(bf16x8*)awr = *(bf16x8*)ta;
        *(bf16x8*)bwr = *(bf16x8*)tb;
        __syncthreads();
        bf16x8 af[2], bfr[2];
#pragma unroll
        for (int i = 0; i < 2; i++) af[i] = *(bf16x8*)&As[(wm + i * 16 + lr) * 40 + lq * 8];
#pragma unroll
        for (int j = 0; j < 2; j++) bfr[j] = *(bf16x8*)&Bs[(wn + j * 16 + lr) * 40 + lq * 8];
#pragma unroll
        for (int i = 0; i < 2; i++)
#pragma unroll
            for (int j = 0; j < 2; j++)
                acc[i][j] = __builtin_amdgcn_mfma_f32_16x16x32_bf16(af[i], bfr[j], acc[i][j], 0, 0, 0);
    }
    float* att = ws + OFF_ATT;
#pragma unroll
    for (int j = 0; j < 2; j++) {
        int gn = n0 + wn + j * 16 + lr;
        float b = out_b[gn];
        float colsum = 0.f;
#pragma unroll
        for (int i = 0; i < 2; i++)
#pragma unroll
            for (int r4 = 0; r4 < 4; r4++) {
                int gm = m0 + wm + i * 16 + lq * 4 + r4;
                float v = acc[i][j][r4] + b;
                att[(size_t)gm * DD + gn] = v;
                colsum += v;
            }
        atomicAdd(&ps[wn + j * 16 + lr], colsum);
    }
    __syncthreads();
    if (tid < 64) atomicAdd(&ws[OFF_POOL + n0 + tid], ps[tid]);
}

// triple GEMM sharing A = attn_out: K2 (n-tiles 0-7), Q0 (8-15), H0 (16-21)
__global__ __launch_bounds__(256) void k_trip(
    const float* __restrict__ in_w, const float* __restrict__ in_b,
    const float* __restrict__ ref_w1, const float* __restrict__ ref_b1, float* ws)
{
    int bx = blockIdx.x;
    const float* B; const float* bias; float* C; int ldb, ldc, n0;
    if (bx < 8)       { B = in_w + (size_t)DD * DD; ldb = DD;  bias = in_b + DD;   C = ws + OFF_K2; ldc = DD;  n0 = bx * 64; }
    else if (bx < 16) { B = ws + OFF_M2;            ldb = 512; bias = ws + OFF_B2; C = ws + OFF_Q0; ldc = DD;  n0 = (bx - 8) * 64; }
    else              { B = ref_w1;                 ldb = 514; bias = ref_b1;      C = ws + OFF_H0; ldc = 384; n0 = (bx - 16) * 64; }
    const float* A = ws + OFF_ATT;
    int m0 = blockIdx.y * 64;
    __shared__ __bf16 As[64 * 40];
    __shared__ __bf16 Bs[64 * 40];
    int tid = threadIdx.x;
    int r = tid >> 2, quad = tid & 3;
    int w = tid >> 6, lane = tid & 63;
    int wm = (w & 1) * 32, wn = (w >> 1) * 32;
    int lr = lane & 15, lq = lane >> 4;
    f32x4 acc[2][2];
#pragma unroll
    for (int i = 0; i < 2; i++)
#pragma unroll
        for (int j = 0; j < 2; j++) acc[i][j] = (f32x4){0.f, 0.f, 0.f, 0.f};

    const float* arow = A + (size_t)(m0 + r) * DD + quad * 8;
    const float* brow = B + (size_t)(n0 + r) * ldb + quad * 8;
    __bf16* awr = &As[r * 40 + quad * 8];
    __bf16* bwr = &Bs[r * 40 + quad * 8];

    for (int k0 = 0; k0 < DD; k0 += 32) {
        __bf16 ta[8] __attribute__((aligned(16)));
        __bf16 tb[8] __attribute__((aligned(16)));
#pragma unroll
        for (int q = 0; q < 4; q++) {
            float2 f = *(const float2*)(arow + k0 + 2 * q);
            ta[2 * q] = (__bf16)f.x; ta[2 * q + 1] = (__bf16)f.y;
            float2 g = *(const float2*)(brow + k0 + 2 * q);
            tb[2 * q] = (__bf16)g.x; tb[2 * q + 1] = (__bf16)g.y;
        }
        __syncthreads();
        *(bf16x8*)awr = *(bf16x8*)ta;
        *(bf16x8*)bwr = *(bf16x8*)tb;
        __syncthreads();
        bf16x8 af[2], bfr[2];
#pragma unroll
        for (int i = 0; i < 2; i++) af[i] = *(bf16x8*)&As[(wm + i * 16 + lr) * 40 + lq * 8];
#pragma unroll
        for (int j = 0; j < 2; j++) bfr[j] = *(bf16x8*)&Bs[(wn + j * 16 + lr) * 40 + lq * 8];
#pragma unroll
        for (int i = 0; i < 2; i++)
#pragma unroll
            for (int j = 0; j < 2; j++)
                acc[i][j] = __builtin_amdgcn_mfma_f32_16x16x32_bf16(af[i], bfr[j], acc[i][j], 0, 0, 0);
    }
#pragma unroll
    for (int i = 0; i < 2; i++)
#pragma unroll
        for (int r4 = 0; r4 < 4; r4++) {
            int gm = m0 + wm + i * 16 + lq * 4 + r4;
#pragma unroll
            for (int j = 0; j < 2; j++) {
                int gn = n0 + wn + j * 16 + lr;
                C[(size_t)gm * ldc + gn] = acc[i][j][r4] + bias[gn];
            }
        }
}

// per-row softmax stats over bf16 score matrix (first MHA)
__global__ __launch_bounds__(256) void k_rstats(const bf16* __restrict__ S, float* ws) {
    int wave = threadIdx.x >> 6, lane = threadIdx.x & 63;
    int row = blockIdx.x * 4 + wave;
    const bf16* p = S + (size_t)row * NT;
    float v[24], m = -1e30f;
#pragma unroll
    for (int t = 0; t < 24; t++) { v[t] = __bfloat162float(p[t * 64 + lane]); m = fmaxf(m, v[t]); }
    for (int off = 32; off; off >>= 1) m = fmaxf(m, __shfl_xor(m, off));
    float s = 0.f;
#pragma unroll
    for (int t = 0; t < 24; t++) s += __expf(v[t] - m);
    for (int off = 32; off; off >>= 1) s += __shfl_xor(s, off);
    if (lane == 0) { ws[OFF_RST + 2 * row] = m; ws[OFF_RST + 2 * row + 1] = 1.f / s; }
}

// fused rowmax + E0 = exp(S0 - rowmax) in place
__global__ __launch_bounds__(256) void k_rse(float* ws) {
    bf16* S = (bf16*)(ws + OFF_S);
    int wave = threadIdx.x >> 6, lane = threadIdx.x & 63;
    int row = blockIdx.x * 4 + wave;
    unsigned short* p = (unsigned short*)(S + (size_t)row * NT);
    union { uint4 u; unsigned short s[8]; } b[3];
    float v[24], m = -1e30f;
#pragma unroll
    for (int c = 0; c < 3; c++) {
        b[c].u = *(const uint4*)(p + c * 512 + lane * 8);
#pragma unroll
        for (int q = 0; q < 8; q++) {
            v[c * 8 + q] = __uint_as_float((unsigned)b[c].s[q] << 16);
            m = fmaxf(m, v[c * 8 + q]);
        }
    }
    for (int off = 32; off; off >>= 1) m = fmaxf(m, __shfl_xor(m, off));
#pragma unroll
    for (int c = 0; c < 3; c++) {
#pragma unroll
        for (int q = 0; q < 8; q++) {
            bf16 ov = __float2bfloat16(__expf(v[c * 8 + q] - m));
            b[c].s[q] = *(unsigned short*)&ov;
        }
        *(uint4*)(p + c * 512 + lane * 8) = b[c].u;
    }
}

// softmax(S_h) @ V_h, 64x64 tiles, split-K=2 into disjoint partial buffers
__global__ __launch_bounds__(256) void k_pv(const bf16* __restrict__ S, float* ws) {
    int h = blockIdx.z;
    int m0 = blockIdx.y * 64;
    int n0 = (blockIdx.x & 1) * 64;
    int ks = blockIdx.x >> 1;
    const int KCH = NT / 2;
    int kbeg = ks * KCH;
    __shared__ __bf16 As[64 * 40];
    __shared__ __bf16 Bs[64 * 40];
    int tid = threadIdx.x;
    int r = tid >> 2, quad = tid & 3;
    int w = tid >> 6, lane = tid & 63;
    int wm = (w & 1) * 32, wn = (w >> 1) * 32;
    int lr = lane & 15, lq = lane >> 4;
    const float* rst = ws + OFF_RST;
    const float* Vt = ws + OFF_X + (size_t)h * DHD * NT;
    const bf16* Sh = S + (size_t)h * NT * NT;
    int row = m0 + r;
    float mrow = rst[2 * (h * NT + row)];
    const unsigned short* srow = (const unsigned short*)(Sh + (size_t)row * NT) + quad * 8;
    const float* brow = Vt + (size_t)(n0 + r) * NT + quad * 8;
    __bf16* awr = &As[r * 40 + quad * 8];
    __bf16* bwr = &Bs[r * 40 + quad * 8];
    f32x4 acc[2][2];
#pragma unroll
    for (int i = 0; i < 2; i++)
#pragma unroll
        for (int j = 0; j < 2; j++) acc[i][j] = (f32x4){0.f, 0.f, 0.f, 0.f};

    for (int k0 = kbeg; k0 < kbeg + KCH; k0 += 32) {
        union { uint4 u; unsigned short s[8]; } bb;
        bb.u = *(const uint4*)(srow + k0);
        __bf16 ta[8] __attribute__((aligned(16)));
        __bf16 tb[8] __attribute__((aligned(16)));
#pragma unroll
        for (int q = 0; q < 8; q++)
            ta[q] = (__bf16)__expf(__uint_as_float((unsigned)bb.s[q] << 16) - mrow);
#pragma unroll
        for (int q = 0; q < 4; q++) {
            float2 f = *(const float2*)(brow + k0 + 2 * q);
            tb[2 * q] = (__bf16)f.x; tb[2 * q + 1] = (__bf16)f.y;
        }
        __syncthreads();
        *(bf16x8*)awr = *(bf16x8*)ta;
        *(bf16x8*)bwr = *(bf16x8*)tb;
        __syncthreads();
        bf16x8 af[2], bfr[2];
#pragma unroll
        for (int i = 0; i < 2; i++) af[i] = *(bf16x8*)&As[(wm + i * 16 + lr) * 40 + lq * 8];
#pragma unroll
        for (int j = 0; j < 2; j++) bfr[j] = *(bf16x8*)&Bs[(wn + j * 16 + lr) * 40 + lq * 8];
#pragma unroll
        for (int i = 0; i < 2; i++)
#pragma unroll
            for (int j = 0; j < 2; j++)
                acc[i][j] = __builtin_amdgcn_mfma_f32_16x16x32_bf16(af[i], bfr[j], acc[i][j], 0, 0, 0);
    }
    float* dst = ws + (ks == 0 ? OFF_CTX : OFF_HR);
#pragma unroll
    for (int i = 0; i < 2; i++)
#pragma unroll
        for (int r4 = 0; r4 < 4; r4++) {
            int gm = m0 + wm + i * 16 + lq * 4 + r4;
            float ri = rst[2 * (h * NT + gm) + 1];
#pragma unroll
            for (int j = 0; j < 2; j++) {
                int gn = n0 + wn + j * 16 + lr;
                dst[(size_t)gm * DD + h * DHD + gn] = acc[i][j][r4] * ri;
            }
        }
}

__global__ void k_head(const float* __restrict__ icw1, const float* __restrict__ icb1,
                       const float* __restrict__ icw2, const float* __restrict__ icb2,
                       float* ws, float* out) {
    __shared__ float h1[128];
    __shared__ float lg[MAXI];
    int tid = threadIdx.x;  // 128 threads
    float a = 0.f;
    for (int c = 0; c < DD; c++) a += icw1[(size_t)tid * DD + c] * ws[OFF_POOL + c];
    h1[tid] = fmaxf(a * (1.0f / NT) + icb1[tid], 0.f);
    __syncthreads();
    if (tid < MAXI) {
        float s = icb2[tid];
        for (int j = 0; j < 128; j++) s += icw2[tid * 128 + j] * h1[j];
        lg[tid] = s;
    }
    __syncthreads();
    if (tid == 0) {
        int best = 0; float bv = lg[0];
        for (int m = 1; m < MAXI; m++) if (lg[m] > bv) { bv = lg[m]; best = m; }
        int ni = best + 1;
        for (int i = 0; i < MAXI; i++) out[10 + i] = (i < ni) ? 1.f : 0.f;
    }
}

// avec/bvec = wq @ qp_w[:,512/513]; b2 = wq @ qp_b + bq
__global__ void k_uv(const float* __restrict__ in_w, const float* __restrict__ qp_w,
                     const float* __restrict__ qp_b, const float* __restrict__ in_b, float* ws) {
    __shared__ float su[DD], sv[DD], sb[DD];
    int tid = threadIdx.x;
    for (int c = tid; c < DD; c += 256) {
        su[c] = qp_w[c * 514 + 512]; sv[c] = qp_w[c * 514 + 513]; sb[c] = qp_b[c];
    }
    __syncthreads();
    int j = blockIdx.x * 256 + tid;
    float a = 0.f, b = 0.f, c2 = 0.f;
    for (int c = 0; c < DD; c++) {
        float w = in_w[(size_t)j * DD + c];
        a += w * su[c]; b += w * sv[c]; c2 += w * sb[c];
    }
    ws[OFF_AV + j] = a; ws[OFF_BV + j] = b; ws[OFF_B2 + j] = c2 + in_b[j];
}

// A[h,n] = avec_h . K2[n,h*128:] / sqrt(DH);  B likewise
__global__ __launch_bounds__(256) void k_ab(float* ws) {
    int wave = threadIdx.x >> 6, lane = threadIdx.x & 63;
    int row = blockIdx.x * 4 + wave;
    int h = row / NT, n = row % NT;
    const float* k2 = ws + OFF_K2 + (size_t)n * DD + h * DHD;
    const float* av = ws + OFF_AV + h * DHD;
    const float* bv = ws + OFF_BV + h * DHD;
    int d = lane * 2;
    float a = av[d] * k2[d] + av[d + 1] * k2[d + 1];
    float b = bv[d] * k2[d] + bv[d + 1] * k2[d + 1];
    for (int off = 32; off; off >>= 1) { a += __shfl_xor(a, off); b += __shfl_xor(b, off); }
    if (lane == 0) { ws[OFF_AARR + row] = a * RSQRT_DH; ws[OFF_BARR + row] = b * RSQRT_DH; }
}

// fused: logits = relu(H0+delta)@w2^T + b2 kept in LDS, then softdot -> so/eo
__global__ __launch_bounds__(256) void k_lgs(
    const float* __restrict__ rw1, const float* __restrict__ rw2,
    const float* __restrict__ rb2, const float* __restrict__ wp, int l, float* ws)
{
    __shared__ float dsh[128];
    __shared__ __bf16 As[64 * 136];
    __shared__ __bf16 Bs[64 * 136];
    __shared__ __bf16 Ls[64 * 208];
    int tid = threadIdx.x;
    int m0 = blockIdx.x * 64;           // [0, 7680)
    int i_int = m0 / NT;
    int nbase = m0 % NT;
    if (blockIdx.x == 0 && tid < 11) ws[OFF_SCAL + SC_DSDE + tid] = 0.f;   // dsde[10] + ticket
    if (tid < 128) {
        float s_i = ws[OFF_SCAL + SC_START + i_int], e_i = ws[OFF_SCAL + SC_END + i_int];
        const float* wr = rw1 + (size_t)(l * 128 + tid) * 514;
        dsh[tid] = s_i * wr[512] + e_i * wr[513];
    }
    __syncthreads();
    int r = tid >> 2, quad = tid & 3;
    {
        const float* arow = ws + OFF_H0 + (size_t)(nbase + r) * 384 + l * 128 + quad * 32;
        __bf16 tmp[32] __attribute__((aligned(16)));
#pragma unroll
        for (int q = 0; q < 16; q++) {
            float2 f = *(const float2*)(arow + 2 * q);
            int jj = quad * 32 + 2 * q;
            tmp[2 * q]     = (__bf16)fmaxf(f.x + dsh[jj], 0.f);
            tmp[2 * q + 1] = (__bf16)fmaxf(f.y + dsh[jj + 1], 0.f);
        }
        __bf16* aw = &As[r * 136 + quad * 32];
#pragma unroll
        for (int q = 0; q < 4; q++) *(bf16x8*)(aw + q * 8) = *(bf16x8*)(tmp + q * 8);
    }
    int w = tid >> 6, lane = tid & 63;
    int wm = (w & 1) * 32, wn = (w >> 1) * 32;
    int lr = lane & 15, lq = lane >> 4;
    for (int nt = 0; nt < 4; nt++) {
        int n0 = nt * 64;
        int gnr = n0 + r;
        __bf16 tmp[32] __attribute__((aligned(16)));
        if (gnr < 200) {
            const float* brow = rw2 + (size_t)gnr * 128 + quad * 32;
#pragma unroll
            for (int q = 0; q < 16; q++) {
                float2 f = *(const float2*)(brow + 2 * q);
                tmp[2 * q] = (__bf16)f.x; tmp[2 * q + 1] = (__bf16)f.y;
            }
        } else {
#pragma unroll
            for (int q = 0; q < 32; q++) tmp[q] = (__bf16)0.f;
        }
        __syncthreads();
        {
            __bf16* bw = &Bs[r * 136 + quad * 32];
#pragma unroll
            for (int q = 0; q < 4; q++) *(bf16x8*)(bw + q * 8) = *(bf16x8*)(tmp + q * 8);
        }
        __syncthreads();
        f32x4 acc[2][2];
#pragma unroll
        for (int i = 0; i < 2; i++)
#pragma unroll
            for (int j = 0; j < 2; j++) acc[i][j] = (f32x4){0.f, 0.f, 0.f, 0.f};
#pragma unroll
        for (int kk = 0; kk < 4; kk++) {
            bf16x8 af[2], bfr[2];
#pragma unroll
            for (int i = 0; i < 2; i++) af[i] = *(bf16x8*)&As[(wm + i * 16 + lr) * 136 + kk * 32 + lq * 8];
#pragma unroll
            for (int j = 0; j < 2; j++) bfr[j] = *(bf16x8*)&Bs[(wn + j * 16 + lr) * 136 + kk * 32 + lq * 8];
#pragma unroll
            for (int i = 0; i < 2; i++)
#pragma unroll
                for (int j = 0; j < 2; j++)
                    acc[i][j] = __builtin_amdgcn_mfma_f32_16x16x32_bf16(af[i], bfr[j], acc[i][j], 0, 0, 0);
        }
#pragma unroll
        for (int i = 0; i < 2; i++)
#pragma unroll
            for (int r4 = 0; r4 < 4; r4++) {
                int rl = wm + i * 16 + lq * 4 + r4;
#pragma unroll
                for (int j = 0; j < 2; j++) {
                    int gn = n0 + wn + j * 16 + lr;
                    if (gn < 200) Ls[rl * 208 + gn] = (__bf16)(acc[i][j][r4] + rb2[gn]);
                }
            }
    }
    __syncthreads();
    {
        int rloc = tid >> 2, q = tid & 3;      // q: quarter of 50 cols
        int c0 = q * 50;
        const unsigned short* lrow = (const unsigned short*)&Ls[rloc * 208];
        float m = -1e30f;
#pragma unroll
        for (int c = 0; c < 50; c++)
            m = fmaxf(m, __uint_as_float((unsigned)lrow[c0 + c] << 16));
        m = fmaxf(m, __shfl_xor(m, 1));
        float den = 0.f, num = 0.f;
#pragma unroll
        for (int c = 0; c < 50; c++) {
            float p = __expf(__uint_as_float((unsigned)lrow[c0 + c] << 16) - m);
            den += p;
            int wc = c0 + c; if (wc >= NBINS) wc -= NBINS;
            num += p * wp[wc];
        }
        den += __shfl_xor(den, 1);
        num += __shfl_xor(num, 1);
        int n = nbase + rloc;
        if (q == 0)      ws[OFF_SOFF + (size_t)i_int * NT + n] = num / den;
        else if (q == 2) ws[OFF_EOFF + (size_t)i_int * NT + n] = num / den;
    }
}

// P_ks[h*NT+m][c] = sum_{k in chunk} E0*U, U computed on the fly from A,B,so,eo
__global__ __launch_bounds__(256) void k_eg(const bf16* __restrict__ E0, float* ws) {
    int h = blockIdx.z;
    int m0 = blockIdx.y * 128;
    int ks = blockIdx.x;
    const int KCH = NT / 8;   // 192
    __shared__ __bf16 As[128 * 40];
    __shared__ __bf16 Bs[16 * 40];
    int tid = threadIdx.x;
    int w = tid >> 6, lane = tid & 63;
    int lr = lane & 15, lq = lane >> 4;
    int r = tid >> 1, half = tid & 1;
    const bf16* Sh = E0 + (size_t)h * NT * NT;
    const unsigned short* arow = (const unsigned short*)(Sh + (size_t)(m0 + r) * NT) + half * 16;
    int wm = w * 32;
    f32x4 acc[2];
    acc[0] = (f32x4){0.f, 0.f, 0.f, 0.f};
    acc[1] = (f32x4){0.f, 0.f, 0.f, 0.f};
    int bc = tid >> 3, bk = tid & 7;
    int valid = (tid < 128) && (bc < 15);
    int ii = bc / 3, tt = bc - ii * 3;
    if (ii > 4) ii = 4;
    float s_i = 0.f, e_i = 0.f;
    if (valid) { s_i = ws[OFF_SCAL + SC_START + ii]; e_i = ws[OFF_SCAL + SC_END + ii]; }
    const float* Ar = ws + OFF_AARR + h * NT;
    const float* Br = ws + OFF_BARR + h * NT;
    const float* fo = ws + (tt == 2 ? OFF_EOFF : OFF_SOFF) + (size_t)ii * NT;

    for (int k0 = ks * KCH; k0 < ks * KCH + KCH; k0 += 32) {
        uint4 a0 = *(const uint4*)(arow + k0);
        uint4 a1 = *(const uint4*)(arow + k0 + 8);
        float bv[4] = {0.f, 0.f, 0.f, 0.f};
        if (valid) {
            float4 a4 = *(const float4*)(Ar + k0 + bk * 4);
            float4 b4 = *(const float4*)(Br + k0 + bk * 4);
            bv[0] = __expf(s_i * a4.x + e_i * b4.x);
            bv[1] = __expf(s_i * a4.y + e_i * b4.y);
            bv[2] = __expf(s_i * a4.z + e_i * b4.z);
            bv[3] = __expf(s_i * a4.w + e_i * b4.w);
            if (tt) {
                float4 f4 = *(const float4*)(fo + k0 + bk * 4);
                bv[0] *= f4.x; bv[1] *= f4.y; bv[2] *= f4.z; bv[3] *= f4.w;
            }
        }
        __syncthreads();
        *(uint4*)&As[r * 40 + half * 16] = a0;
        *(uint4*)&As[r * 40 + half * 16 + 8] = a1;
        if (tid < 128) {
            __bf16* bw = &Bs[bc * 40 + bk * 4];
            bw[0] = (__bf16)bv[0]; bw[1] = (__bf16)bv[1]; bw[2] = (__bf16)bv[2]; bw[3] = (__bf16)bv[3];
        }
        __syncthreads();
        bf16x8 bf0 = *(bf16x8*)&Bs[lr * 40 + lq * 8];
        bf16x8 af0 = *(bf16x8*)&As[(wm + lr) * 40 + lq * 8];
        bf16x8 af1 = *(bf16x8*)&As[(wm + 16 + lr) * 40 + lq * 8];
        acc[0] = __builtin_amdgcn_mfma_f32_16x16x32_bf16(af0, bf0, acc[0], 0, 0, 0);
        acc[1] = __builtin_amdgcn_mfma_f32_16x16x32_bf16(af1, bf0, acc[1], 0, 0, 0);
    }
    float* P = ws + OFF_LG + (size_t)ks * PSLICE;
    if (lr < 15) {
#pragma unroll
        for (int i = 0; i < 2; i++)
#pragma unroll
            for (int r4 = 0; r4 < 4; r4++) {
                int gm = m0 + wm + i * 16 + lq * 4 + r4;
                P[(size_t)(h * NT + gm) * 16 + lr] = acc[i][r4];
            }
    }
}

// sum 8 slices, form ratios, reduce to ds/de; last block applies the update
__global__ __launch_bounds__(256) void k_fin(float* ws) {
    __shared__ float part[4][10];
    int tid = threadIdx.x;
    int w = tid >> 6, lane = tid & 63;
    int row = blockIdx.x * 256 + tid;
    float acc[15];
#pragma unroll
    for (int c = 0; c < 15; c++) acc[c] = 0.f;
    for (int ks = 0; ks < 8; ks++) {
        const float* Pr = ws + OFF_LG + (size_t)ks * PSLICE + (size_t)row * 16;
#pragma unroll
        for (int c = 0; c < 15; c++) acc[c] += Pr[c];
    }
    float loc[10];
#pragma unroll
    for (int i = 0; i < MAXI; i++) {
        float den = acc[i * 3];
        loc[i]        = acc[i * 3 + 1] / den;
        loc[MAXI + i] = acc[i * 3 + 2] / den;
    }
#pragma unroll
    for (int c = 0; c < 10; c++)
        for (int off = 32; off; off >>= 1) loc[c] += __shfl_xor(loc[c], off);
    if (lane == 0) {
#pragma unroll
        for (int c = 0; c < 10; c++) part[w][c] = loc[c];
    }
    __syncthreads();
    if (tid < 10) {
        float s = part[0][tid] + part[1][tid] + part[2][tid] + part[3][tid];
        atomicAdd(&ws[OFF_SCAL + SC_DSDE + tid], s);
    }
    __threadfence();
    __syncthreads();
    if (tid == 0) {
        unsigned old = atomicAdd((unsigned*)&ws[OFF_SCAL + SC_CNT], 1u);
        if (old == 23) {   // last of 24 blocks: apply start/end update
            for (int i = 0; i < MAXI; i++) {
                float ds = atomicAdd(&ws[OFF_SCAL + SC_DSDE + i], 0.f);
                float de = atomicAdd(&ws[OFF_SCAL + SC_DSDE + MAXI + i], 0.f);
                ws[OFF_SCAL + SC_START + i] += ds * 0.25f;   // 1/H
                ws[OFF_SCAL + SC_END + i]   += de * 0.25f;
            }
        }
    }
}

__global__ void k_final(const float* __restrict__ ws, float* out) {
    int tid = threadIdx.x;
    if (tid < MAXI) {
        out[2 * tid]     = ws[OFF_SCAL + SC_START + tid];
        out[2 * tid + 1] = ws[OFF_SCAL + SC_END + tid];
    }
}

// -------------------------------------------------------------------------
extern "C" void kernel_launch(void* const* d_in, const int* in_sizes, int n_in,
                              void* d_out, int out_size, void* d_ws, size_t ws_size,
                              hipStream_t stream) {
    const float* emb    = (const float*)d_in[0];
    const float* tpos   = (const float*)d_in[1];
    const float* W_time = (const float*)d_in[3];
    const float* b_time = (const float*)d_in[4];
    const float* in_w   = (const float*)d_in[5];
    const float* in_b   = (const float*)d_in[6];
    const float* out_w  = (const float*)d_in[7];
    const float* out_b  = (const float*)d_in[8];
    const float* ic_w1  = (const float*)d_in[9];
    const float* ic_b1  = (const float*)d_in[10];
    const float* ic_w2  = (const float*)d_in[11];
    const float* ic_b2  = (const float*)d_in[12];
    const float* ref_w1 = (const float*)d_in[13];
    const float* ref_b1 = (const float*)d_in[14];
    const float* ref_w2 = (const float*)d_in[15];
    const float* ref_b2 = (const float*)d_in[16];
    const float* wp     = (const float*)d_in[17];
    const float* qp_w   = (const float*)d_in[18];
    const float* qp_b   = (const float*)d_in[19];
    float* ws  = (float*)d_ws;
    float* out = (float*)d_out;
    bf16* S = (bf16*)(ws + OFF_S);

    k_pre<<<1, 256, 0, stream>>>(tpos, ws);
    k_qpt<<<dim3(16, 16), 256, 0, stream>>>(qp_w, ws);
    k_g64<0><<<dim3(8, 8, 1), 256, 0, stream>>>(
        in_w, DD, 0, ws + OFF_QPT, 512, 0, ws + OFF_M2, 512, 0, 512, DD, 1.f, nullptr);
    k_uv<<<2, 256, 0, stream>>>(in_w, qp_w, qp_b, in_b, ws);

    // qkv (+x fusion, +Vt direct transpose for V tiles)
    k_qkv<<<dim3(24, 24), 256, 0, stream>>>(emb, tpos, W_time, b_time, in_w, in_b, ws);
    k_mgemm<1><<<dim3(12, 12, NH), 256, 0, stream>>>(
        ws + OFF_QKV, 3 * DD, DHD, ws + OFF_QKV + DD, 3 * DD, DHD,
        S, NT, (long long)NT * NT, NT, DHD, RSQRT_DH, nullptr);
    k_rstats<<<NH * NT / 4, 256, 0, stream>>>(S, ws);
    k_pv<<<dim3(4, NT / 64, NH), 256, 0, stream>>>(S, ws);
    k_oproj<<<dim3(8, 24), 256, 0, stream>>>(out_w, out_b, ws);
    k_head<<<1, 128, 0, stream>>>(ic_w1, ic_b1, ic_w2, ic_b2, ws, out);

    // K2 | Q0 | H0 in one dispatch
    k_trip<<<dim3(22, 24), 256, 0, stream>>>(in_w, in_b, ref_w1, ref_b1, ws);
    k_ab<<<NH * NT / 4, 256, 0, stream>>>(ws);

    // S0 -> S, fused rowmax+exp
    k_mgemm<1><<<dim3(12, 12, NH), 256, 0, stream>>>(
        ws + OFF_Q0, DD, DHD, ws + OFF_K2, DD, DHD,
        S, NT, (long long)NT * NT, NT, DHD, RSQRT_DH, nullptr);
    k_rse<<<NH * NT / 4, 256, 0, stream>>>(ws);

    for (int l = 0; l < NL; l++) {
        k_lgs<<<120, 256, 0, stream>>>(ref_w1, ref_w2 + (size_t)l * 200 * 128,
                                       ref_b2 + l * 200, wp, l, ws);
        k_eg<<<dim3(8, NT / 128, NH), 256, 0, stream>>>(S, ws);
        k_fin<<<NH * NT / 256, 256, 0, stream>>>(ws);
    }
    k_final<<<1, 32, 0, stream>>>(ws, out);
}

// Round 7
// 357.855 us; speedup vs baseline: 5.7649x; 1.0264x over previous
//
#include <hip/hip_runtime.h>
#include <hip/hip_bf16.h>

typedef __hip_bfloat16 bf16;
typedef __bf16 bf16x8 __attribute__((ext_vector_type(8)));
typedef float f32x4 __attribute__((ext_vector_type(4)));

#define DD   512
#define NT   1536
#define NH   4
#define DHD  128
#define NBINS 100
#define MAXI 5
#define NL   3
#define RSQRT_DH 0.08838834764831845f   // 1/sqrt(128)

// ---- workspace layout (float offsets) ----
#define OFF_X      ((size_t)0)                        // Vt[H][128][NT]
#define OFF_QKV    (OFF_X    + (size_t)NT*DD)        // N x 3D (V part unused)
#define OFF_ATT    (OFF_QKV  + (size_t)NT*3*DD)      // attn_out N x D
#define OFF_CTX    (OFF_ATT  + (size_t)NT*DD)        // pv partial ks=0
#define OFF_K2     (OFF_CTX  + (size_t)NT*DD)
#define OFF_QP0    (OFF_K2   + (size_t)NT*DD)        // reused: M2 | b2
#define OFF_Q0     (OFF_QP0  + (size_t)NT*DD)
#define OFF_H0     (OFF_Q0   + (size_t)NT*DD)        // N x 384
#define OFF_HR     (OFF_H0   + (size_t)NT*384)       // pv partial ks=1
#define OFF_LG     (OFF_HR   + (size_t)MAXI*NT*128)  // P slices [8][NH*NT][16] | stats
#define OFF_AARR   (OFF_LG   + (size_t)MAXI*NT*200)  // H x N
#define OFF_BARR   (OFF_AARR + (size_t)NH*NT)
#define OFF_AV     (OFF_BARR + (size_t)NH*NT)        // D
#define OFF_BV     (OFF_AV   + (size_t)DD)
#define OFF_SOFF   (OFF_BV   + (size_t)DD)           // 5 x N
#define OFF_EOFF   (OFF_SOFF + (size_t)MAXI*NT)
#define OFF_RST    (OFF_EOFF + (size_t)MAXI*NT)      // H*N rowmax (S0)
#define OFF_POOL   (OFF_RST  + (size_t)NH*NT*2)      // D
#define OFF_SCAL   (OFF_POOL + (size_t)DD)           // 64 scalars
#define OFF_S      (OFF_SCAL + (size_t)64)           // bf16 region H*N*N
#define SC_START 0
#define SC_END   5
#define SC_DSDE  10
#define SC_CNT   20
#define OFF_M2   (OFF_QP0 + (size_t)512*512)
#define OFF_B2   (OFF_QP0 + (size_t)2*512*512)
#define PSLICE   ((size_t)NH*NT*16)
#define OFF_STAT (OFF_LG + (size_t)8*PSLICE)          // [NH*NT][12][2]

// -------------------------------------------------------------------------
// merged prologue: blocks 0-63 M2 (NN GEMM), 64-71 uv, 72 pre
__global__ __launch_bounds__(256) void k_misc(
    const float* __restrict__ tpos, const float* __restrict__ in_w,
    const float* __restrict__ in_b, const float* __restrict__ qp_w,
    const float* __restrict__ qp_b, float* ws)
{
    __shared__ __bf16 As[64 * 40];
    __shared__ __bf16 Bs[64 * 40];
    __shared__ float smn[256], smx[256];
    int bx = blockIdx.x, tid = threadIdx.x;
    if (bx < 64) {
        // M2[m,n] = sum_c wq[m,c] * qp_w[c,n]   (NN, B transposed in staging)
        int m0 = (bx >> 3) * 64, n0 = (bx & 7) * 64;
        int r = tid >> 2, quad = tid & 3;
        int w = tid >> 6, lane = tid & 63;
        int wm = (w & 1) * 32, wn = (w >> 1) * 32;
        int lr = lane & 15, lq = lane >> 4;
        f32x4 acc[2][2];
#pragma unroll
        for (int i = 0; i < 2; i++)
#pragma unroll
            for (int j = 0; j < 2; j++) acc[i][j] = (f32x4){0.f, 0.f, 0.f, 0.f};
        const float* arow = in_w + (size_t)(m0 + r) * DD + quad * 8;
        int kk = tid >> 3, g = tid & 7;
        for (int k0 = 0; k0 < DD; k0 += 32) {
            __bf16 ta[8] __attribute__((aligned(16)));
#pragma unroll
            for (int q = 0; q < 4; q++) {
                float2 f = *(const float2*)(arow + k0 + 2 * q);
                ta[2 * q] = (__bf16)f.x; ta[2 * q + 1] = (__bf16)f.y;
            }
            const float* bsrc = qp_w + (size_t)(k0 + kk) * 514 + n0 + g * 8;
            float4 b0 = *(const float4*)bsrc;
            float4 b1 = *(const float4*)(bsrc + 4);
            float bb[8] = {b0.x, b0.y, b0.z, b0.w, b1.x, b1.y, b1.z, b1.w};
            __syncthreads();
            *(bf16x8*)&As[r * 40 + quad * 8] = *(bf16x8*)ta;
#pragma unroll
            for (int q = 0; q < 8; q++) Bs[(g * 8 + q) * 40 + kk] = (__bf16)bb[q];
            __syncthreads();
            bf16x8 af[2], bfr[2];
#pragma unroll
            for (int i = 0; i < 2; i++) af[i] = *(bf16x8*)&As[(wm + i * 16 + lr) * 40 + lq * 8];
#pragma unroll
            for (int j = 0; j < 2; j++) bfr[j] = *(bf16x8*)&Bs[(wn + j * 16 + lr) * 40 + lq * 8];
#pragma unroll
            for (int i = 0; i < 2; i++)
#pragma unroll
                for (int j = 0; j < 2; j++)
                    acc[i][j] = __builtin_amdgcn_mfma_f32_16x16x32_bf16(af[i], bfr[j], acc[i][j], 0, 0, 0);
        }
        float* M2 = ws + OFF_M2;
#pragma unroll
        for (int i = 0; i < 2; i++)
#pragma unroll
            for (int r4 = 0; r4 < 4; r4++) {
                int gm = m0 + wm + i * 16 + lq * 4 + r4;
#pragma unroll
                for (int j = 0; j < 2; j++)
                    M2[(size_t)gm * 512 + n0 + wn + j * 16 + lr] = acc[i][j][r4];
            }
    } else if (bx < 72) {
        // avec/bvec = wq @ qp_w[:,512/513]; b2 = wq @ qp_b + bq  (wave per row)
        int w = tid >> 6, lane = tid & 63;
        float su8[8], sv8[8], sb8[8];
#pragma unroll
        for (int q = 0; q < 8; q++) {
            int c = lane * 8 + q;
            su8[q] = qp_w[(size_t)c * 514 + 512];
            sv8[q] = qp_w[(size_t)c * 514 + 513];
            sb8[q] = qp_b[c];
        }
        int base = (bx - 64) * 64 + w * 16;
        for (int t = 0; t < 16; t++) {
            int row = base + t;
            const float* wr = in_w + (size_t)row * DD + lane * 8;
            float4 x0 = *(const float4*)wr, x1 = *(const float4*)(wr + 4);
            float xa[8] = {x0.x, x0.y, x0.z, x0.w, x1.x, x1.y, x1.z, x1.w};
            float a = 0.f, b = 0.f, c2 = 0.f;
#pragma unroll
            for (int q = 0; q < 8; q++) { a += xa[q] * su8[q]; b += xa[q] * sv8[q]; c2 += xa[q] * sb8[q]; }
            for (int off = 32; off; off >>= 1) {
                a += __shfl_xor(a, off); b += __shfl_xor(b, off); c2 += __shfl_xor(c2, off);
            }
            if (lane == 0) {
                ws[OFF_AV + row] = a; ws[OFF_BV + row] = b; ws[OFF_B2 + row] = c2 + in_b[row];
            }
        }
    } else {
        // pre: pool zero + time grid
        ws[OFF_POOL + tid] = 0.f; ws[OFF_POOL + 256 + tid] = 0.f;
        float mn = 1e30f, mx = -1e30f;
        for (int i = tid; i < NT; i += 256) { float v = tpos[i]; mn = fminf(mn, v); mx = fmaxf(mx, v); }
        smn[tid] = mn; smx[tid] = mx; __syncthreads();
        for (int s = 128; s; s >>= 1) {
            if (tid < s) { smn[tid] = fminf(smn[tid], smn[tid + s]); smx[tid] = fmaxf(smx[tid], smx[tid + s]); }
            __syncthreads();
        }
        if (tid == 0) {
            float tmin = smn[0], tmax = smx[0];
            for (int i = 0; i < MAXI; i++) {
                ws[OFF_SCAL + SC_START + i] = tmin + (tmax - tmin) * (float)i / 5.0f;
                ws[OFF_SCAL + SC_END + i]   = tmin + (tmax - tmin) * (float)(i + 1) / 5.0f;
            }
        }
    }
}

// ---------------- scores GEMM (128x128, bf16 out) + per-tile softmax stats ----------------
// C = alpha * A @ B^T (bf16); stat[(z*NT+row)*24 + bx*2 + {0,1}] = (tileMax, tileExpSum)
__global__ __launch_bounds__(256) void k_score(
    const float* __restrict__ A, int lda, long long aZ,
    const float* __restrict__ B, int ldb, long long bZ,
    bf16* __restrict__ C, float* __restrict__ stat)
{
    int z = blockIdx.z;
    A += (size_t)z * aZ; B += (size_t)z * bZ;
    int m0 = blockIdx.y * 128, n0 = blockIdx.x * 128;
    __shared__ __bf16 As[128 * 40];
    __shared__ __bf16 Bs[128 * 40];
    __shared__ float sMax[4][64];
    __shared__ float sSum[4][64];
    int tid = threadIdx.x;
    int r = tid >> 1, hh = tid & 1;
    int w = tid >> 6, lane = tid & 63;
    int wm = (w & 1) * 64, wn = (w >> 1) * 64;
    int lr = lane & 15, lq = lane >> 4;
    f32x4 acc[4][4];
#pragma unroll
    for (int i = 0; i < 4; i++)
#pragma unroll
        for (int j = 0; j < 4; j++) acc[i][j] = (f32x4){0.f, 0.f, 0.f, 0.f};

    const float* arow = A + (size_t)(m0 + r) * lda + hh * 16;
    const float* brow = B + (size_t)(n0 + r) * ldb + hh * 16;
    __bf16* awr = &As[r * 40 + hh * 16];
    __bf16* bwr = &Bs[r * 40 + hh * 16];

    for (int k0 = 0; k0 < DHD; k0 += 32) {
        __bf16 ta[16] __attribute__((aligned(16)));
        __bf16 tb[16] __attribute__((aligned(16)));
#pragma unroll
        for (int q = 0; q < 8; q++) {
            float2 f = *(const float2*)(arow + k0 + 2 * q);
            ta[2 * q] = (__bf16)f.x; ta[2 * q + 1] = (__bf16)f.y;
            float2 g = *(const float2*)(brow + k0 + 2 * q);
            tb[2 * q] = (__bf16)g.x; tb[2 * q + 1] = (__bf16)g.y;
        }
        __syncthreads();
        *(bf16x8*)awr = *(bf16x8*)ta;
        *(bf16x8*)(awr + 8) = *(bf16x8*)(ta + 8);
        *(bf16x8*)bwr = *(bf16x8*)tb;
        *(bf16x8*)(bwr + 8) = *(bf16x8*)(tb + 8);
        __syncthreads();
        bf16x8 af[4], bfr[4];
#pragma unroll
        for (int i = 0; i < 4; i++) af[i] = *(bf16x8*)&As[(wm + i * 16 + lr) * 40 + lq * 8];
#pragma unroll
        for (int j = 0; j < 4; j++) bfr[j] = *(bf16x8*)&Bs[(wn + j * 16 + lr) * 40 + lq * 8];
#pragma unroll
        for (int i = 0; i < 4; i++)
#pragma unroll
            for (int j = 0; j < 4; j++)
                acc[i][j] = __builtin_amdgcn_mfma_f32_16x16x32_bf16(af[i], bfr[j], acc[i][j], 0, 0, 0);
    }
    // C write (scaled)
#pragma unroll
    for (int i = 0; i < 4; i++)
#pragma unroll
        for (int r4 = 0; r4 < 4; r4++) {
            int gm = m0 + wm + i * 16 + lq * 4 + r4;
#pragma unroll
            for (int j = 0; j < 4; j++) {
                int gn = n0 + wn + j * 16 + lr;
                C[(size_t)z * NT * NT + (size_t)gm * NT + gn] =
                    __float2bfloat16(acc[i][j][r4] * RSQRT_DH);
            }
        }
    // per-tile row stats
#pragma unroll
    for (int i = 0; i < 4; i++)
#pragma unroll
        for (int r4 = 0; r4 < 4; r4++) {
            float m = -1e30f;
#pragma unroll
            for (int j = 0; j < 4; j++) m = fmaxf(m, acc[i][j][r4] * RSQRT_DH);
            for (int off = 1; off < 16; off <<= 1) m = fmaxf(m, __shfl_xor(m, off));
            if (lr == 0) sMax[w][i * 16 + lq * 4 + r4] = m;
        }
    __syncthreads();
#pragma unroll
    for (int i = 0; i < 4; i++)
#pragma unroll
        for (int r4 = 0; r4 < 4; r4++) {
            int lidx = i * 16 + lq * 4 + r4;
            float M = fmaxf(sMax[w][lidx], sMax[w ^ 2][lidx]);
            float s = 0.f;
#pragma unroll
            for (int j = 0; j < 4; j++) s += __expf(acc[i][j][r4] * RSQRT_DH - M);
            for (int off = 1; off < 16; off <<= 1) s += __shfl_xor(s, off);
            if (lr == 0) sSum[w][lidx] = s;
        }
    __syncthreads();
    if (tid < 128) {
        int lidx = tid & 63, wb = tid >> 6;
        float M = fmaxf(sMax[wb][lidx], sMax[wb + 2][lidx]);
        float den = sSum[wb][lidx] + sSum[wb + 2][lidx];
        size_t base = ((size_t)z * NT + m0 + tid) * 24 + (size_t)blockIdx.x * 2;
        stat[base] = M; stat[base + 1] = den;
    }
}

// qkv = (emb + t*wt + bt) @ in_w^T + in_b; V-tiles written directly transposed to Vt
__global__ __launch_bounds__(256) void k_qkv(
    const float* __restrict__ emb, const float* __restrict__ t,
    const float* __restrict__ wt, const float* __restrict__ bt,
    const float* __restrict__ in_w, const float* __restrict__ in_b, float* ws)
{
    int m0 = blockIdx.y * 64, n0 = blockIdx.x * 64;
    __shared__ __bf16 As[64 * 40];
    __shared__ __bf16 Bs[64 * 40];
    int tid = threadIdx.x;
    int r = tid >> 2, quad = tid & 3;
    int w = tid >> 6, lane = tid & 63;
    int wm = (w & 1) * 32, wn = (w >> 1) * 32;
    int lr = lane & 15, lq = lane >> 4;
    f32x4 acc[2][2];
#pragma unroll
    for (int i = 0; i < 2; i++)
#pragma unroll
        for (int j = 0; j < 2; j++) acc[i][j] = (f32x4){0.f, 0.f, 0.f, 0.f};

    float trow = t[m0 + r];
    const float* arow = emb + (size_t)(m0 + r) * DD + quad * 8;
    const float* brow = in_w + (size_t)(n0 + r) * DD + quad * 8;
    __bf16* awr = &As[r * 40 + quad * 8];
    __bf16* bwr = &Bs[r * 40 + quad * 8];

    for (int k0 = 0; k0 < DD; k0 += 32) {
        __bf16 ta[8] __attribute__((aligned(16)));
        __bf16 tb[8] __attribute__((aligned(16)));
#pragma unroll
        for (int q = 0; q < 4; q++) {
            float2 e = *(const float2*)(arow + k0 + 2 * q);
            float2 wv = *(const float2*)(wt + k0 + quad * 8 + 2 * q);
            float2 bv = *(const float2*)(bt + k0 + quad * 8 + 2 * q);
            ta[2 * q]     = (__bf16)(e.x + trow * wv.x + bv.x);
            ta[2 * q + 1] = (__bf16)(e.y + trow * wv.y + bv.y);
            float2 f = *(const float2*)(brow + k0 + 2 * q);
            tb[2 * q] = (__bf16)f.x; tb[2 * q + 1] = (__bf16)f.y;
        }
        __syncthreads();
        *(bf16x8*)awr = *(bf16x8*)ta;
        *(bf16x8*)bwr = *(bf16x8*)tb;
        __syncthreads();
        bf16x8 af[2], bfr[2];
#pragma unroll
        for (int i = 0; i < 2; i++) af[i] = *(bf16x8*)&As[(wm + i * 16 + lr) * 40 + lq * 8];
#pragma unroll
        for (int j = 0; j < 2; j++) bfr[j] = *(bf16x8*)&Bs[(wn + j * 16 + lr) * 40 + lq * 8];
#pragma unroll
        for (int i = 0; i < 2; i++)
#pragma unroll
            for (int j = 0; j < 2; j++)
                acc[i][j] = __builtin_amdgcn_mfma_f32_16x16x32_bf16(af[i], bfr[j], acc[i][j], 0, 0, 0);
    }
    float* qkv = ws + OFF_QKV;
    float* Vt  = ws + OFF_X;
#pragma unroll
    for (int i = 0; i < 2; i++)
#pragma unroll
        for (int j = 0; j < 2; j++) {
            int gn = n0 + wn + j * 16 + lr;
            int gmb = m0 + wm + i * 16 + lq * 4;
            float b = in_b[gn];
            f32x4 vv = acc[i][j];
            vv[0] += b; vv[1] += b; vv[2] += b; vv[3] += b;
            if (gn < 2 * DD) {
#pragma unroll
                for (int r4 = 0; r4 < 4; r4++)
                    qkv[(size_t)(gmb + r4) * (3 * DD) + gn] = vv[r4];
            } else {
                *(float4*)&Vt[(size_t)(gn - 2 * DD) * NT + gmb] = *(float4*)&vv;
            }
        }
}

// softmax(S_h)@V_h; in-block tile-stat combine; split-K=2 disjoint partials
__global__ __launch_bounds__(256) void k_pv(const bf16* __restrict__ S, float* ws) {
    int h = blockIdx.z;
    int m0 = blockIdx.y * 64;
    int n0 = (blockIdx.x & 1) * 64;
    int ks = blockIdx.x >> 1;
    const int KCH = NT / 2;
    int kbeg = ks * KCH;
    __shared__ __bf16 As[64 * 40];
    __shared__ __bf16 Bs[64 * 40];
    __shared__ float sM[64], sI[64];
    int tid = threadIdx.x;
    // combine 12 tile-stats for this block's 64 rows
    if (tid < 64) {
        const float* st = ws + OFF_STAT + ((size_t)(h * NT + m0 + tid)) * 24;
        float M = -1e30f;
#pragma unroll
        for (int t2 = 0; t2 < 12; t2++) M = fmaxf(M, st[2 * t2]);
        float den = 0.f;
#pragma unroll
        for (int t2 = 0; t2 < 12; t2++) den += st[2 * t2 + 1] * __expf(st[2 * t2] - M);
        sM[tid] = M; sI[tid] = 1.f / den;
    }
    __syncthreads();
    int r = tid >> 2, quad = tid & 3;
    int w = tid >> 6, lane = tid & 63;
    int wm = (w & 1) * 32, wn = (w >> 1) * 32;
    int lr = lane & 15, lq = lane >> 4;
    const float* Vt = ws + OFF_X + (size_t)h * DHD * NT;
    const bf16* Sh = S + (size_t)h * NT * NT;
    float mrow = sM[r];
    const unsigned short* srow = (const unsigned short*)(Sh + (size_t)(m0 + r) * NT) + quad * 8;
    const float* brow = Vt + (size_t)(n0 + r) * NT + quad * 8;
    __bf16* awr = &As[r * 40 + quad * 8];
    __bf16* bwr = &Bs[r * 40 + quad * 8];
    f32x4 acc[2][2];
#pragma unroll
    for (int i = 0; i < 2; i++)
#pragma unroll
        for (int j = 0; j < 2; j++) acc[i][j] = (f32x4){0.f, 0.f, 0.f, 0.f};

    for (int k0 = kbeg; k0 < kbeg + KCH; k0 += 32) {
        union { uint4 u; unsigned short s[8]; } bb;
        bb.u = *(const uint4*)(srow + k0);
        __bf16 ta[8] __attribute__((aligned(16)));
        __bf16 tb[8] __attribute__((aligned(16)));
#pragma unroll
        for (int q = 0; q < 8; q++)
            ta[q] = (__bf16)__expf(__uint_as_float((unsigned)bb.s[q] << 16) - mrow);
#pragma unroll
        for (int q = 0; q < 4; q++) {
            float2 f = *(const float2*)(brow + k0 + 2 * q);
            tb[2 * q] = (__bf16)f.x; tb[2 * q + 1] = (__bf16)f.y;
        }
        __syncthreads();
        *(bf16x8*)awr = *(bf16x8*)ta;
        *(bf16x8*)bwr = *(bf16x8*)tb;
        __syncthreads();
        bf16x8 af[2], bfr[2];
#pragma unroll
        for (int i = 0; i < 2; i++) af[i] = *(bf16x8*)&As[(wm + i * 16 + lr) * 40 + lq * 8];
#pragma unroll
        for (int j = 0; j < 2; j++) bfr[j] = *(bf16x8*)&Bs[(wn + j * 16 + lr) * 40 + lq * 8];
#pragma unroll
        for (int i = 0; i < 2; i++)
#pragma unroll
            for (int j = 0; j < 2; j++)
                acc[i][j] = __builtin_amdgcn_mfma_f32_16x16x32_bf16(af[i], bfr[j], acc[i][j], 0, 0, 0);
    }
    float* dst = ws + (ks == 0 ? OFF_CTX : OFF_HR);
#pragma unroll
    for (int i = 0; i < 2; i++)
#pragma unroll
        for (int r4 = 0; r4 < 4; r4++) {
            int lrow = wm + i * 16 + lq * 4 + r4;
            float ri = sI[lrow];
#pragma unroll
            for (int j = 0; j < 2; j++) {
                int gn = n0 + wn + j * 16 + lr;
                dst[(size_t)(m0 + lrow) * DD + h * DHD + gn] = acc[i][j][r4] * ri;
            }
        }
}

// attn_out = (ctx0+ctx1) @ out_w^T + out_b, + fused column pooling
__global__ __launch_bounds__(256) void k_oproj(
    const float* __restrict__ out_w, const float* __restrict__ out_b, float* ws)
{
    int m0 = blockIdx.y * 64, n0 = blockIdx.x * 64;
    __shared__ __bf16 As[64 * 40];
    __shared__ __bf16 Bs[64 * 40];
    __shared__ float ps[64];
    int tid = threadIdx.x;
    int r = tid >> 2, quad = tid & 3;
    int w = tid >> 6, lane = tid & 63;
    int wm = (w & 1) * 32, wn = (w >> 1) * 32;
    int lr = lane & 15, lq = lane >> 4;
    f32x4 acc[2][2];
#pragma unroll
    for (int i = 0; i < 2; i++)
#pragma unroll
        for (int j = 0; j < 2; j++) acc[i][j] = (f32x4){0.f, 0.f, 0.f, 0.f};
    if (tid < 64) ps[tid] = 0.f;

    const float* a0 = ws + OFF_CTX + (size_t)(m0 + r) * DD + quad * 8;
    const float* a1 = ws + OFF_HR  + (size_t)(m0 + r) * DD + quad * 8;
    const float* brow = out_w + (size_t)(n0 + r) * DD + quad * 8;
    __bf16* awr = &As[r * 40 + quad * 8];
    __bf16* bwr = &Bs[r * 40 + quad * 8];

    for (int k0 = 0; k0 < DD; k0 += 32) {
        __bf16 ta[8] __attribute__((aligned(16)));
        __bf16 tb[8] __attribute__((aligned(16)));
#pragma unroll
        for (int q = 0; q < 4; q++) {
            float2 x = *(const float2*)(a0 + k0 + 2 * q);
            float2 y = *(const float2*)(a1 + k0 + 2 * q);
            ta[2 * q]     = (__bf16)(x.x + y.x);
            ta[2 * q + 1] = (__bf16)(x.y + y.y);
            float2 f = *(const float2*)(brow + k0 + 2 * q);
            tb[2 * q] = (__bf16)f.x; tb[2 * q + 1] = (__bf16)f.y;
        }
        __syncthreads();
        *(bf16x8*)awr = *(bf16x8*)ta;
        *(bf16x8*)bwr = *(bf16x8*)tb;
        __syncthreads();
        bf16x8 af[2], bfr[2];
#pragma unroll
        for (int i = 0; i < 2; i++) af[i] = *(bf16x8*)&As[(wm + i * 16 + lr) * 40 + lq * 8];
#pragma unroll
        for (int j = 0; j < 2; j++) bfr[j] = *(bf16x8*)&Bs[(wn + j * 16 + lr) * 40 + lq * 8];
#pragma unroll
        for (int i = 0; i < 2; i++)
#pragma unroll
            for (int j = 0; j < 2; j++)
                acc[i][j] = __builtin_amdgcn_mfma_f32_16x16x32_bf16(af[i], bfr[j], acc[i][j], 0, 0, 0);
    }
    float* att = ws + OFF_ATT;
#pragma unroll
    for (int j = 0; j < 2; j++) {
        int gn = n0 + wn + j * 16 + lr;
        float b = out_b[gn];
        float colsum = 0.f;
#pragma unroll
        for (int i = 0; i < 2; i++)
#pragma unroll
            for (int r4 = 0; r4 < 4; r4++) {
                int gm = m0 + wm + i * 16 + lq * 4 + r4;
                float v = acc[i][j][r4] + b;
                att[(size_t)gm * DD + gn] = v;
                colsum += v;
            }
        atomicAdd(&ps[wn + j * 16 + lr], colsum);
    }
    __syncthreads();
    if (tid < 64) atomicAdd(&ws[OFF_POOL + n0 + tid], ps[tid]);
}

// triple GEMM sharing A = attn_out (K2 | Q0 | H0) + head block (bx==22)
__global__ __launch_bounds__(256) void k_trip(
    const float* __restrict__ in_w, const float* __restrict__ in_b,
    const float* __restrict__ ref_w1, const float* __restrict__ ref_b1,
    const float* __restrict__ icw1, const float* __restrict__ icb1,
    const float* __restrict__ icw2, const float* __restrict__ icb2,
    float* ws, float* out)
{
    __shared__ __bf16 As[64 * 40];
    __shared__ __bf16 Bs[64 * 40];
    __shared__ float h1[128];
    __shared__ float lg[MAXI];
    int bx = blockIdx.x, tid = threadIdx.x;
    if (bx == 22) {
        if (blockIdx.y != 0) return;
        int w = tid >> 6, lane = tid & 63;
        const float* pp = ws + OFF_POOL + lane * 8;
        float4 p0 = *(const float4*)pp, p1 = *(const float4*)(pp + 4);
        float p8[8] = {p0.x, p0.y, p0.z, p0.w, p1.x, p1.y, p1.z, p1.w};
        for (int t = 0; t < 32; t++) {
            int row = w * 32 + t;
            const float* wr = icw1 + (size_t)row * DD + lane * 8;
            float4 a = *(const float4*)wr, b = *(const float4*)(wr + 4);
            float d = a.x * p8[0] + a.y * p8[1] + a.z * p8[2] + a.w * p8[3]
                    + b.x * p8[4] + b.y * p8[5] + b.z * p8[6] + b.w * p8[7];
            for (int off = 32; off; off >>= 1) d += __shfl_xor(d, off);
            if (lane == 0) h1[row] = fmaxf(d * (1.0f / NT) + icb1[row], 0.f);
        }
        __syncthreads();
        if (tid < MAXI) {
            float s = icb2[tid];
            for (int j = 0; j < 128; j++) s += icw2[tid * 128 + j] * h1[j];
            lg[tid] = s;
        }
        __syncthreads();
        if (tid == 0) {
            int best = 0; float bv = lg[0];
            for (int m = 1; m < MAXI; m++) if (lg[m] > bv) { bv = lg[m]; best = m; }
            int ni = best + 1;
            for (int i = 0; i < MAXI; i++) out[10 + i] = (i < ni) ? 1.f : 0.f;
        }
        return;
    }
    const float* B; const float* bias; float* C; int ldb, ldc, n0;
    if (bx < 8)       { B = in_w + (size_t)DD * DD; ldb = DD;  bias = in_b + DD;   C = ws + OFF_K2; ldc = DD;  n0 = bx * 64; }
    else if (bx < 16) { B = ws + OFF_M2;            ldb = 512; bias = ws + OFF_B2; C = ws + OFF_Q0; ldc = DD;  n0 = (bx - 8) * 64; }
    else              { B = ref_w1;                 ldb = 514; bias = ref_b1;      C = ws + OFF_H0; ldc = 384; n0 = (bx - 16) * 64; }
    const float* A = ws + OFF_ATT;
    int m0 = blockIdx.y * 64;
    int r = tid >> 2, quad = tid & 3;
    int w = tid >> 6, lane = tid & 63;
    int wm = (w & 1) * 32, wn = (w >> 1) * 32;
    int lr = lane & 15, lq = lane >> 4;
    f32x4 acc[2][2];
#pragma unroll
    for (int i = 0; i < 2; i++)
#pragma unroll
        for (int j = 0; j < 2; j++) acc[i][j] = (f32x4){0.f, 0.f, 0.f, 0.f};

    const float* arow = A + (size_t)(m0 + r) * DD + quad * 8;
    const float* brow = B + (size_t)(n0 + r) * ldb + quad * 8;
    __bf16* awr = &As[r * 40 + quad * 8];
    __bf16* bwr = &Bs[r * 40 + quad * 8];

    for (int k0 = 0; k0 < DD; k0 += 32) {
        __bf16 ta[8] __attribute__((aligned(16)));
        __bf16 tb[8] __attribute__((aligned(16)));
#pragma unroll
        for (int q = 0; q < 4; q++) {
            float2 f = *(const float2*)(arow + k0 + 2 * q);
            ta[2 * q] = (__bf16)f.x; ta[2 * q + 1] = (__bf16)f.y;
            float2 g = *(const float2*)(brow + k0 + 2 * q);
            tb[2 * q] = (__bf16)g.x; tb[2 * q + 1] = (__bf16)g.y;
        }
        __syncthreads();
        *(bf16x8*)awr = *(bf16x8*)ta;
        *(bf16x8*)bwr = *(bf16x8*)tb;
        __syncthreads();
        bf16x8 af[2], bfr[2];
#pragma unroll
        for (int i = 0; i < 2; i++) af[i] = *(bf16x8*)&As[(wm + i * 16 + lr) * 40 + lq * 8];
#pragma unroll
        for (int j = 0; j < 2; j++) bfr[j] = *(bf16x8*)&Bs[(wn + j * 16 + lr) * 40 + lq * 8];
#pragma unroll
        for (int i = 0; i < 2; i++)
#pragma unroll
            for (int j = 0; j < 2; j++)
                acc[i][j] = __builtin_amdgcn_mfma_f32_16x16x32_bf16(af[i], bfr[j], acc[i][j], 0, 0, 0);
    }
#pragma unroll
    for (int i = 0; i < 2; i++)
#pragma unroll
        for (int r4 = 0; r4 < 4; r4++) {
            int gm = m0 + wm + i * 16 + lq * 4 + r4;
#pragma unroll
            for (int j = 0; j < 2; j++) {
                int gn = n0 + wn + j * 16 + lr;
                C[(size_t)gm * ldc + gn] = acc[i][j][r4] + bias[gn];
            }
        }
}

// per row: A/B dots from K2 + combine S0 tile-maxes -> RST
__global__ __launch_bounds__(256) void k_abc(float* ws) {
    int wave = threadIdx.x >> 6, lane = threadIdx.x & 63;
    int row = blockIdx.x * 4 + wave;
    int h = row / NT, n = row % NT;
    const float* k2 = ws + OFF_K2 + (size_t)n * DD + h * DHD;
    const float* av = ws + OFF_AV + h * DHD;
    const float* bv = ws + OFF_BV + h * DHD;
    int d = lane * 2;
    float a = av[d] * k2[d] + av[d + 1] * k2[d + 1];
    float b = bv[d] * k2[d] + bv[d + 1] * k2[d + 1];
    float tm = (lane < 12) ? ws[OFF_STAT + (size_t)row * 24 + lane * 2] : -1e30f;
    for (int off = 32; off; off >>= 1) { a += __shfl_xor(a, off); b += __shfl_xor(b, off); }
    for (int off = 1; off < 16; off <<= 1) tm = fmaxf(tm, __shfl_xor(tm, off));
    if (lane == 0) {
        ws[OFF_AARR + row] = a * RSQRT_DH;
        ws[OFF_BARR + row] = b * RSQRT_DH;
        ws[OFF_RST + row] = tm;
    }
}

// fused: logits = relu(H0+delta)@w2^T + b2 in LDS, then softdot -> so/eo
__global__ __launch_bounds__(256) void k_lgs(
    const float* __restrict__ rw1, const float* __restrict__ rw2,
    const float* __restrict__ rb2, const float* __restrict__ wp, int l, float* ws)
{
    __shared__ float dsh[128];
    __shared__ __bf16 As[64 * 136];
    __shared__ __bf16 Bs[64 * 136];
    __shared__ __bf16 Ls[64 * 208];
    int tid = threadIdx.x;
    int m0 = blockIdx.x * 64;
    int i_int = m0 / NT;
    int nbase = m0 % NT;
    if (blockIdx.x == 0 && tid < 11) ws[OFF_SCAL + SC_DSDE + tid] = 0.f;   // dsde[10] + ticket
    if (tid < 128) {
        float s_i = ws[OFF_SCAL + SC_START + i_int], e_i = ws[OFF_SCAL + SC_END + i_int];
        const float* wr = rw1 + (size_t)(l * 128 + tid) * 514;
        dsh[tid] = s_i * wr[512] + e_i * wr[513];
    }
    __syncthreads();
    int r = tid >> 2, quad = tid & 3;
    {
        const float* arow = ws + OFF_H0 + (size_t)(nbase + r) * 384 + l * 128 + quad * 32;
        __bf16 tmp[32] __attribute__((aligned(16)));
#pragma unroll
        for (int q = 0; q < 16; q++) {
            float2 f = *(const float2*)(arow + 2 * q);
            int jj = quad * 32 + 2 * q;
            tmp[2 * q]     = (__bf16)fmaxf(f.x + dsh[jj], 0.f);
            tmp[2 * q + 1] = (__bf16)fmaxf(f.y + dsh[jj + 1], 0.f);
        }
        __bf16* aw = &As[r * 136 + quad * 32];
#pragma unroll
        for (int q = 0; q < 4; q++) *(bf16x8*)(aw + q * 8) = *(bf16x8*)(tmp + q * 8);
    }
    int w = tid >> 6, lane = tid & 63;
    int wm = (w & 1) * 32, wn = (w >> 1) * 32;
    int lr = lane & 15, lq = lane >> 4;
    for (int nt = 0; nt < 4; nt++) {
        int n0 = nt * 64;
        int gnr = n0 + r;
        __bf16 tmp[32] __attribute__((aligned(16)));
        if (gnr < 200) {
            const float* brow = rw2 + (size_t)gnr * 128 + quad * 32;
#pragma unroll
            for (int q = 0; q < 16; q++) {
                float2 f = *(const float2*)(brow + 2 * q);
                tmp[2 * q] = (__bf16)f.x; tmp[2 * q + 1] = (__bf16)f.y;
            }
        } else {
#pragma unroll
            for (int q = 0; q < 32; q++) tmp[q] = (__bf16)0.f;
        }
        __syncthreads();
        {
            __bf16* bw = &Bs[r * 136 + quad * 32];
#pragma unroll
            for (int q = 0; q < 4; q++) *(bf16x8*)(bw + q * 8) = *(bf16x8*)(tmp + q * 8);
        }
        __syncthreads();
        f32x4 acc[2][2];
#pragma unroll
        for (int i = 0; i < 2; i++)
#pragma unroll
            for (int j = 0; j < 2; j++) acc[i][j] = (f32x4){0.f, 0.f, 0.f, 0.f};
#pragma unroll
        for (int kk = 0; kk < 4; kk++) {
            bf16x8 af[2], bfr[2];
#pragma unroll
            for (int i = 0; i < 2; i++) af[i] = *(bf16x8*)&As[(wm + i * 16 + lr) * 136 + kk * 32 + lq * 8];
#pragma unroll
            for (int j = 0; j < 2; j++) bfr[j] = *(bf16x8*)&Bs[(wn + j * 16 + lr) * 136 + kk * 32 + lq * 8];
#pragma unroll
            for (int i = 0; i < 2; i++)
#pragma unroll
                for (int j = 0; j < 2; j++)
                    acc[i][j] = __builtin_amdgcn_mfma_f32_16x16x32_bf16(af[i], bfr[j], acc[i][j], 0, 0, 0);
        }
#pragma unroll
        for (int i = 0; i < 2; i++)
#pragma unroll
            for (int r4 = 0; r4 < 4; r4++) {
                int rl = wm + i * 16 + lq * 4 + r4;
#pragma unroll
                for (int j = 0; j < 2; j++) {
                    int gn = n0 + wn + j * 16 + lr;
                    if (gn < 200) Ls[rl * 208 + gn] = (__bf16)(acc[i][j][r4] + rb2[gn]);
                }
            }
    }
    __syncthreads();
    {
        int rloc = tid >> 2, q = tid & 3;
        int c0 = q * 50;
        const unsigned short* lrow = (const unsigned short*)&Ls[rloc * 208];
        float m = -1e30f;
#pragma unroll
        for (int c = 0; c < 50; c++)
            m = fmaxf(m, __uint_as_float((unsigned)lrow[c0 + c] << 16));
        m = fmaxf(m, __shfl_xor(m, 1));
        float den = 0.f, num = 0.f;
#pragma unroll
        for (int c = 0; c < 50; c++) {
            float p = __expf(__uint_as_float((unsigned)lrow[c0 + c] << 16) - m);
            den += p;
            int wc = c0 + c; if (wc >= NBINS) wc -= NBINS;
            num += p * wp[wc];
        }
        den += __shfl_xor(den, 1);
        num += __shfl_xor(num, 1);
        int n = nbase + rloc;
        if (q == 0)      ws[OFF_SOFF + (size_t)i_int * NT + n] = num / den;
        else if (q == 2) ws[OFF_EOFF + (size_t)i_int * NT + n] = num / den;
    }
}

// P_ks = E0 @ U^T, E0 = exp(S0 - rowmax) computed in A-staging, U on the fly in B-staging
__global__ __launch_bounds__(256) void k_eg(const bf16* __restrict__ S0, float* ws) {
    int h = blockIdx.z;
    int m0 = blockIdx.y * 128;
    int ks = blockIdx.x;
    const int KCH = NT / 8;   // 192
    __shared__ __bf16 As[128 * 40];
    __shared__ __bf16 Bs[16 * 40];
    int tid = threadIdx.x;
    int w = tid >> 6, lane = tid & 63;
    int lr = lane & 15, lq = lane >> 4;
    int r = tid >> 1, half = tid & 1;
    const bf16* Sh = S0 + (size_t)h * NT * NT;
    const unsigned short* arow = (const unsigned short*)(Sh + (size_t)(m0 + r) * NT) + half * 16;
    float mrow = ws[OFF_RST + h * NT + m0 + r];
    int wm = w * 32;
    f32x4 acc[2];
    acc[0] = (f32x4){0.f, 0.f, 0.f, 0.f};
    acc[1] = (f32x4){0.f, 0.f, 0.f, 0.f};
    int bc = tid >> 3, bk = tid & 7;
    int valid = (tid < 128) && (bc < 15);
    int ii = bc / 3, tt = bc - ii * 3;
    if (ii > 4) ii = 4;
    float s_i = 0.f, e_i = 0.f;
    if (valid) { s_i = ws[OFF_SCAL + SC_START + ii]; e_i = ws[OFF_SCAL + SC_END + ii]; }
    const float* Ar = ws + OFF_AARR + h * NT;
    const float* Br = ws + OFF_BARR + h * NT;
    const float* fo = ws + (tt == 2 ? OFF_EOFF : OFF_SOFF) + (size_t)ii * NT;

    for (int k0 = ks * KCH; k0 < ks * KCH + KCH; k0 += 32) {
        union { uint4 u; unsigned short s[8]; } a0, a1, o0, o1;
        a0.u = *(const uint4*)(arow + k0);
        a1.u = *(const uint4*)(arow + k0 + 8);
#pragma unroll
        for (int q = 0; q < 8; q++) {
            __bf16 e0 = (__bf16)__expf(__uint_as_float((unsigned)a0.s[q] << 16) - mrow);
            __bf16 e1 = (__bf16)__expf(__uint_as_float((unsigned)a1.s[q] << 16) - mrow);
            o0.s[q] = *(unsigned short*)&e0;
            o1.s[q] = *(unsigned short*)&e1;
        }
        float bv[4] = {0.f, 0.f, 0.f, 0.f};
        if (valid) {
            float4 a4 = *(const float4*)(Ar + k0 + bk * 4);
            float4 b4 = *(const float4*)(Br + k0 + bk * 4);
            bv[0] = __expf(s_i * a4.x + e_i * b4.x);
            bv[1] = __expf(s_i * a4.y + e_i * b4.y);
            bv[2] = __expf(s_i * a4.z + e_i * b4.z);
            bv[3] = __expf(s_i * a4.w + e_i * b4.w);
            if (tt) {
                float4 f4 = *(const float4*)(fo + k0 + bk * 4);
                bv[0] *= f4.x; bv[1] *= f4.y; bv[2] *= f4.z; bv[3] *= f4.w;
            }
        }
        __syncthreads();
        *(uint4*)&As[r * 40 + half * 16] = o0.u;
        *(uint4*)&As[r * 40 + half * 16 + 8] = o1.u;
        if (tid < 128) {
            __bf16* bw = &Bs[bc * 40 + bk * 4];
            bw[0] = (__bf16)bv[0]; bw[1] = (__bf16)bv[1]; bw[2] = (__bf16)bv[2]; bw[3] = (__bf16)bv[3];
        }
        __syncthreads();
        bf16x8 bf0 = *(bf16x8*)&Bs[lr * 40 + lq * 8];
        bf16x8 af0 = *(bf16x8*)&As[(wm + lr) * 40 + lq * 8];
        bf16x8 af1 = *(bf16x8*)&As[(wm + 16 + lr) * 40 + lq * 8];
        acc[0] = __builtin_amdgcn_mfma_f32_16x16x32_bf16(af0, bf0, acc[0], 0, 0, 0);
        acc[1] = __builtin_amdgcn_mfma_f32_16x16x32_bf16(af1, bf0, acc[1], 0, 0, 0);
    }
    float* P = ws + OFF_LG + (size_t)ks * PSLICE;
    if (lr < 15) {
#pragma unroll
        for (int i = 0; i < 2; i++)
#pragma unroll
            for (int r4 = 0; r4 < 4; r4++) {
                int gm = m0 + wm + i * 16 + lq * 4 + r4;
                P[(size_t)(h * NT + gm) * 16 + lr] = acc[i][r4];
            }
    }
}

// sum 8 slices, ratios, reduce; last block applies update (+ writes out on last layer)
__global__ __launch_bounds__(256) void k_fin(float* ws, float* out, int l) {
    __shared__ float part[4][10];
    int tid = threadIdx.x;
    int w = tid >> 6, lane = tid & 63;
    int row = blockIdx.x * 256 + tid;
    float acc[15];
#pragma unroll
    for (int c = 0; c < 15; c++) acc[c] = 0.f;
    for (int ks = 0; ks < 8; ks++) {
        const float* Pr = ws + OFF_LG + (size_t)ks * PSLICE + (size_t)row * 16;
#pragma unroll
        for (int c = 0; c < 15; c++) acc[c] += Pr[c];
    }
    float loc[10];
#pragma unroll
    for (int i = 0; i < MAXI; i++) {
        float den = acc[i * 3];
        loc[i]        = acc[i * 3 + 1] / den;
        loc[MAXI + i] = acc[i * 3 + 2] / den;
    }
#pragma unroll
    for (int c = 0; c < 10; c++)
        for (int off = 32; off; off >>= 1) loc[c] += __shfl_xor(loc[c], off);
    if (lane == 0) {
#pragma unroll
        for (int c = 0; c < 10; c++) part[w][c] = loc[c];
    }
    __syncthreads();
    if (tid < 10) {
        float s = part[0][tid] + part[1][tid] + part[2][tid] + part[3][tid];
        atomicAdd(&ws[OFF_SCAL + SC_DSDE + tid], s);
    }
    __threadfence();
    __syncthreads();
    if (tid == 0) {
        unsigned old = atomicAdd((unsigned*)&ws[OFF_SCAL + SC_CNT], 1u);
        if (old == 23) {
            for (int i = 0; i < MAXI; i++) {
                float ds = atomicAdd(&ws[OFF_SCAL + SC_DSDE + i], 0.f);
                float de = atomicAdd(&ws[OFF_SCAL + SC_DSDE + MAXI + i], 0.f);
                float ns = ws[OFF_SCAL + SC_START + i] + ds * 0.25f;   // 1/H
                float ne = ws[OFF_SCAL + SC_END + i]   + de * 0.25f;
                ws[OFF_SCAL + SC_START + i] = ns;
                ws[OFF_SCAL + SC_END + i]   = ne;
                if (l == NL - 1) { out[2 * i] = ns; out[2 * i + 1] = ne; }
            }
        }
    }
}

// -------------------------------------------------------------------------
extern "C" void kernel_launch(void* const* d_in, const int* in_sizes, int n_in,
                              void* d_out, int out_size, void* d_ws, size_t ws_size,
                              hipStream_t stream) {
    const float* emb    = (const float*)d_in[0];
    const float* tpos   = (const float*)d_in[1];
    const float* W_time = (const float*)d_in[3];
    const float* b_time = (const float*)d_in[4];
    const float* in_w   = (const float*)d_in[5];
    const float* in_b   = (const float*)d_in[6];
    const float* out_w  = (const float*)d_in[7];
    const float* out_b  = (const float*)d_in[8];
    const float* ic_w1  = (const float*)d_in[9];
    const float* ic_b1  = (const float*)d_in[10];
    const float* ic_w2  = (const float*)d_in[11];
    const float* ic_b2  = (const float*)d_in[12];
    const float* ref_w1 = (const float*)d_in[13];
    const float* ref_b1 = (const float*)d_in[14];
    const float* ref_w2 = (const float*)d_in[15];
    const float* ref_b2 = (const float*)d_in[16];
    const float* wp     = (const float*)d_in[17];
    const float* qp_w   = (const float*)d_in[18];
    const float* qp_b   = (const float*)d_in[19];
    float* ws  = (float*)d_ws;
    float* out = (float*)d_out;
    bf16* S = (bf16*)(ws + OFF_S);

    // prologue: M2 | uv | pre in one dispatch
    k_misc<<<73, 256, 0, stream>>>(tpos, in_w, in_b, qp_w, qp_b, ws);

    // qkv (+x fusion, +Vt direct transpose)
    k_qkv<<<dim3(24, 24), 256, 0, stream>>>(emb, tpos, W_time, b_time, in_w, in_b, ws);
    // scores -> S + tile stats
    k_score<<<dim3(12, 12, NH), 256, 0, stream>>>(
        ws + OFF_QKV, 3 * DD, DHD, ws + OFF_QKV + DD, 3 * DD, DHD, S, ws + OFF_STAT);
    k_pv<<<dim3(4, NT / 64, NH), 256, 0, stream>>>(S, ws);
    k_oproj<<<dim3(8, 24), 256, 0, stream>>>(out_w, out_b, ws);

    // K2 | Q0 | H0 | head in one dispatch
    k_trip<<<dim3(23, 24), 256, 0, stream>>>(in_w, in_b, ref_w1, ref_b1,
                                             ic_w1, ic_b1, ic_w2, ic_b2, ws, out);

    // S0 -> S + tile stats
    k_score<<<dim3(12, 12, NH), 256, 0, stream>>>(
        ws + OFF_Q0, DD, DHD, ws + OFF_K2, DD, DHD, S, ws + OFF_STAT);
    // A/B dots + rowmax combine
    k_abc<<<NH * NT / 4, 256, 0, stream>>>(ws);

    for (int l = 0; l < NL; l++) {
        k_lgs<<<120, 256, 0, stream>>>(ref_w1, ref_w2 + (size_t)l * 200 * 128,
                                       ref_b2 + l * 200, wp, l, ws);
        k_eg<<<dim3(8, NT / 128, NH), 256, 0, stream>>>(S, ws);
        k_fin<<<NH * NT / 256, 256, 0, stream>>>(ws, out, l);
    }
}

// Round 8
// 305.931 us; speedup vs baseline: 6.7434x; 1.1697x over previous
//
#include <hip/hip_runtime.h>
#include <hip/hip_bf16.h>

typedef __hip_bfloat16 bf16;
typedef __bf16 bf16x8 __attribute__((ext_vector_type(8)));
typedef float f32x4 __attribute__((ext_vector_type(4)));

#define DD   512
#define NT   1536
#define NH   4
#define DHD  128
#define NBINS 100
#define MAXI 5
#define NL   3
#define RSQRT_DH 0.08838834764831845f   // 1/sqrt(128)

// ---- fp32 workspace layout (float offsets) ----
#define OFF_ATT    ((size_t)0)                        // attn_out N x D (fp32, pool/head)
#define OFF_CTX    (OFF_ATT  + (size_t)NT*DD)        // pv partial ks=0
#define OFF_CTX1   (OFF_CTX  + (size_t)NT*DD)        // pv partial ks=1
#define OFF_H0     (OFF_CTX1 + (size_t)NT*DD)        // N x 384 fp32
#define OFF_LG     (OFF_H0   + (size_t)NT*384)       // P slices [8][NH*NT][16]
#define OFF_AARR   (OFF_LG   + (size_t)8*NH*NT*16)
#define OFF_BARR   (OFF_AARR + (size_t)NH*NT)
#define OFF_AV     (OFF_BARR + (size_t)NH*NT)
#define OFF_BV     (OFF_AV   + (size_t)DD)
#define OFF_B2     (OFF_BV   + (size_t)DD)
#define OFF_SOFF   (OFF_B2   + (size_t)DD)
#define OFF_EOFF   (OFF_SOFF + (size_t)MAXI*NT)
#define OFF_STAT   (OFF_EOFF + (size_t)MAXI*NT)      // [NH*NT][12] expsums (MHA1)
#define OFF_POOL   (OFF_STAT + (size_t)NH*NT*12)
#define OFF_SCAL   (OFF_POOL + (size_t)DD)
#define OFF_E      (OFF_SCAL + (size_t)64)           // bf16 E region NH*NT*NT
#define SC_START 0
#define SC_END   5
#define SC_DSDE  10
#define SC_CNT   20
#define PSLICE   ((size_t)NH*NT*16)
// ---- bf16 pool (element offsets), starts after E ----
#define BF_BASE  (OFF_E + (size_t)NH*NT*NT/2)
#define BQKB   ((size_t)0)                   // [NT][1024] Q|K
#define BVT    (BQKB  + (size_t)NT*1024)     // [NH][128][NT]
#define BATT   (BVT   + (size_t)NH*128*NT)   // [NT][512]
#define BK2    (BATT  + (size_t)NT*512)
#define BQ0    (BK2   + (size_t)NT*512)
#define BM2    (BQ0   + (size_t)NT*512)      // [512][512]
#define BINW   (BM2   + (size_t)512*512)     // [1536][512]
#define BOUTW  (BINW  + (size_t)1536*512)    // [512][512]
#define BRW1   (BOUTW + (size_t)512*512)     // [384][512]
#define BRW2   (BRW1  + (size_t)384*512)     // [3][200][128]

__device__ __forceinline__ void cvt8(const float* s, bf16* d) {
    float4 f0 = *(const float4*)s, f1 = *(const float4*)(s + 4);
    union { uint4 u; unsigned short us[8]; } o;
    bf16 t;
    t = __float2bfloat16(f0.x); o.us[0] = *(unsigned short*)&t;
    t = __float2bfloat16(f0.y); o.us[1] = *(unsigned short*)&t;
    t = __float2bfloat16(f0.z); o.us[2] = *(unsigned short*)&t;
    t = __float2bfloat16(f0.w); o.us[3] = *(unsigned short*)&t;
    t = __float2bfloat16(f1.x); o.us[4] = *(unsigned short*)&t;
    t = __float2bfloat16(f1.y); o.us[5] = *(unsigned short*)&t;
    t = __float2bfloat16(f1.z); o.us[6] = *(unsigned short*)&t;
    t = __float2bfloat16(f1.w); o.us[7] = *(unsigned short*)&t;
    *(uint4*)d = o.u;
}

// -------------------------------------------------------------------------
// prologue: M2B GEMM (0-63) | uv (64-71) | pre (72) | weight converts (73-97)
__global__ __launch_bounds__(256) void k_misc(
    const float* __restrict__ tpos, const float* __restrict__ in_w,
    const float* __restrict__ in_b, const float* __restrict__ out_w,
    const float* __restrict__ ref_w1, const float* __restrict__ ref_w2,
    const float* __restrict__ qp_w, const float* __restrict__ qp_b, float* ws)
{
    __shared__ __bf16 As[64 * 40];
    __shared__ __bf16 Bs[64 * 40];
    __shared__ float smn[256], smx[256];
    bf16* bp = (bf16*)(ws + BF_BASE);
    int bx = blockIdx.x, tid = threadIdx.x;
    if (bx < 64) {
        // M2B[m,n] = sum_c wq[m,c] * qp_w[c,n]   (NN, B transposed in staging)
        int m0 = (bx >> 3) * 64, n0 = (bx & 7) * 64;
        int r = tid >> 2, quad = tid & 3;
        int w = tid >> 6, lane = tid & 63;
        int wm = (w & 1) * 32, wn = (w >> 1) * 32;
        int lr = lane & 15, lq = lane >> 4;
        f32x4 acc[2][2];
#pragma unroll
        for (int i = 0; i < 2; i++)
#pragma unroll
            for (int j = 0; j < 2; j++) acc[i][j] = (f32x4){0.f, 0.f, 0.f, 0.f};
        const float* arow = in_w + (size_t)(m0 + r) * DD + quad * 8;
        int kk = tid >> 3, g = tid & 7;
        for (int k0 = 0; k0 < DD; k0 += 32) {
            __bf16 ta[8] __attribute__((aligned(16)));
#pragma unroll
            for (int q = 0; q < 4; q++) {
                float2 f = *(const float2*)(arow + k0 + 2 * q);
                ta[2 * q] = (__bf16)f.x; ta[2 * q + 1] = (__bf16)f.y;
            }
            const float* bsrc = qp_w + (size_t)(k0 + kk) * 514 + n0 + g * 8;
            float4 b0 = *(const float4*)bsrc;
            float4 b1 = *(const float4*)(bsrc + 4);
            float bb[8] = {b0.x, b0.y, b0.z, b0.w, b1.x, b1.y, b1.z, b1.w};
            __syncthreads();
            *(bf16x8*)&As[r * 40 + quad * 8] = *(bf16x8*)ta;
#pragma unroll
            for (int q = 0; q < 8; q++) Bs[(g * 8 + q) * 40 + kk] = (__bf16)bb[q];
            __syncthreads();
            bf16x8 af[2], bfr[2];
#pragma unroll
            for (int i = 0; i < 2; i++) af[i] = *(bf16x8*)&As[(wm + i * 16 + lr) * 40 + lq * 8];
#pragma unroll
            for (int j = 0; j < 2; j++) bfr[j] = *(bf16x8*)&Bs[(wn + j * 16 + lr) * 40 + lq * 8];
#pragma unroll
            for (int i = 0; i < 2; i++)
#pragma unroll
                for (int j = 0; j < 2; j++)
                    acc[i][j] = __builtin_amdgcn_mfma_f32_16x16x32_bf16(af[i], bfr[j], acc[i][j], 0, 0, 0);
        }
        bf16* M2B = bp + BM2;
#pragma unroll
        for (int i = 0; i < 2; i++)
#pragma unroll
            for (int r4 = 0; r4 < 4; r4++) {
                int gm = m0 + wm + i * 16 + lq * 4 + r4;
#pragma unroll
                for (int j = 0; j < 2; j++)
                    M2B[(size_t)gm * 512 + n0 + wn + j * 16 + lr] = __float2bfloat16(acc[i][j][r4]);
            }
    } else if (bx < 72) {
        int w = tid >> 6, lane = tid & 63;
        float su8[8], sv8[8], sb8[8];
#pragma unroll
        for (int q = 0; q < 8; q++) {
            int c = lane * 8 + q;
            su8[q] = qp_w[(size_t)c * 514 + 512];
            sv8[q] = qp_w[(size_t)c * 514 + 513];
            sb8[q] = qp_b[c];
        }
        int base = (bx - 64) * 64 + w * 16;
        for (int t = 0; t < 16; t++) {
            int row = base + t;
            const float* wr = in_w + (size_t)row * DD + lane * 8;
            float4 x0 = *(const float4*)wr, x1 = *(const float4*)(wr + 4);
            float xa[8] = {x0.x, x0.y, x0.z, x0.w, x1.x, x1.y, x1.z, x1.w};
            float a = 0.f, b = 0.f, c2 = 0.f;
#pragma unroll
            for (int q = 0; q < 8; q++) { a += xa[q] * su8[q]; b += xa[q] * sv8[q]; c2 += xa[q] * sb8[q]; }
            for (int off = 32; off; off >>= 1) {
                a += __shfl_xor(a, off); b += __shfl_xor(b, off); c2 += __shfl_xor(c2, off);
            }
            if (lane == 0) {
                ws[OFF_AV + row] = a; ws[OFF_BV + row] = b; ws[OFF_B2 + row] = c2 + in_b[row];
            }
        }
    } else if (bx == 72) {
        ws[OFF_POOL + tid] = 0.f; ws[OFF_POOL + 256 + tid] = 0.f;
        float mn = 1e30f, mx = -1e30f;
        for (int i = tid; i < NT; i += 256) { float v = tpos[i]; mn = fminf(mn, v); mx = fmaxf(mx, v); }
        smn[tid] = mn; smx[tid] = mx; __syncthreads();
        for (int s = 128; s; s >>= 1) {
            if (tid < s) { smn[tid] = fminf(smn[tid], smn[tid + s]); smx[tid] = fmaxf(smx[tid], smx[tid + s]); }
            __syncthreads();
        }
        if (tid == 0) {
            float tmin = smn[0], tmax = smx[0];
            for (int i = 0; i < MAXI; i++) {
                ws[OFF_SCAL + SC_START + i] = tmin + (tmax - tmin) * (float)i / 5.0f;
                ws[OFF_SCAL + SC_END + i]   = tmin + (tmax - tmin) * (float)(i + 1) / 5.0f;
            }
        }
    } else if (bx < 89) {
        // in_wB: 786432 elems, 16 blocks x 24 iters x 8
        size_t start = (size_t)(bx - 73) * 6144;
        for (int it = 0; it < 24; it++) {
            size_t g = start + it * 256 + tid;
            cvt8(in_w + g * 8, bp + BINW + g * 8);
        }
    } else if (bx < 93) {
        // out_wB: 262144 elems, 4 blocks x 32 iters x 8
        size_t start = (size_t)(bx - 89) * 8192;
        for (int it = 0; it < 32; it++) {
            size_t g = start + it * 256 + tid;
            cvt8(out_w + g * 8, bp + BOUTW + g * 8);
        }
    } else if (bx < 97) {
        // rw1B: [384][512] from ref_w1 ld 514; 4 blocks x 24 iters
        size_t start = (size_t)(bx - 93) * 6144;
        for (int it = 0; it < 24; it++) {
            size_t g = start + it * 256 + tid;
            int row = (int)(g >> 6), col = (int)(g & 63) * 8;
            const float* s = ref_w1 + (size_t)row * 514 + col;
            float buf[8];
#pragma unroll
            for (int q = 0; q < 4; q++) { float2 f = *(const float2*)(s + 2 * q); buf[2 * q] = f.x; buf[2 * q + 1] = f.y; }
            cvt8(buf, bp + BRW1 + (size_t)row * 512 + col);
        }
    } else {
        // rw2B: 76800 elems, 1 block x 38 iters (guard)
        for (int it = 0; it < 38; it++) {
            size_t g = (size_t)it * 256 + tid;
            if (g < 9600) cvt8(ref_w2 + g * 8, bp + BRW2 + g * 8);
        }
    }
}

// ---------------- E-GEMM: E = exp(alphaScale * A@B^T), bf16 in/out, 128x128 ----------------
template <int STATS>
__global__ __launch_bounds__(256) void k_score(
    const bf16* __restrict__ Ab, int lda, int aZ,
    const bf16* __restrict__ Bb, int ldb, int bZ,
    bf16* __restrict__ E, float* __restrict__ stat)
{
    int z = blockIdx.z;
    const __bf16* A = (const __bf16*)Ab + (size_t)z * aZ;
    const __bf16* B = (const __bf16*)Bb + (size_t)z * bZ;
    int m0 = blockIdx.y * 128, n0 = blockIdx.x * 128;
    __shared__ __bf16 As[128 * 40];
    __shared__ __bf16 Bs[128 * 40];
    __shared__ float sSum[4][64];
    int tid = threadIdx.x;
    int r = tid >> 1, hh = tid & 1;
    int w = tid >> 6, lane = tid & 63;
    int wm = (w & 1) * 64, wn = (w >> 1) * 64;
    int lr = lane & 15, lq = lane >> 4;
    f32x4 acc[4][4];
#pragma unroll
    for (int i = 0; i < 4; i++)
#pragma unroll
        for (int j = 0; j < 4; j++) acc[i][j] = (f32x4){0.f, 0.f, 0.f, 0.f};

    const __bf16* arow = A + (size_t)(m0 + r) * lda + hh * 16;
    const __bf16* brow = B + (size_t)(n0 + r) * ldb + hh * 16;
    __bf16* awr = &As[r * 40 + hh * 16];
    __bf16* bwr = &Bs[r * 40 + hh * 16];

    for (int k0 = 0; k0 < DHD; k0 += 32) {
        uint4 a0 = *(const uint4*)(arow + k0);
        uint4 a1 = *(const uint4*)(arow + k0 + 8);
        uint4 b0 = *(const uint4*)(brow + k0);
        uint4 b1 = *(const uint4*)(brow + k0 + 8);
        __syncthreads();
        *(uint4*)awr = a0; *(uint4*)(awr + 8) = a1;
        *(uint4*)bwr = b0; *(uint4*)(bwr + 8) = b1;
        __syncthreads();
        bf16x8 af[4], bfr[4];
#pragma unroll
        for (int i = 0; i < 4; i++) af[i] = *(bf16x8*)&As[(wm + i * 16 + lr) * 40 + lq * 8];
#pragma unroll
        for (int j = 0; j < 4; j++) bfr[j] = *(bf16x8*)&Bs[(wn + j * 16 + lr) * 40 + lq * 8];
#pragma unroll
        for (int i = 0; i < 4; i++)
#pragma unroll
            for (int j = 0; j < 4; j++)
                acc[i][j] = __builtin_amdgcn_mfma_f32_16x16x32_bf16(af[i], bfr[j], acc[i][j], 0, 0, 0);
    }
    bf16* Ez = E + (size_t)z * NT * NT;
#pragma unroll
    for (int i = 0; i < 4; i++)
#pragma unroll
        for (int r4 = 0; r4 < 4; r4++) {
            int gm = m0 + wm + i * 16 + lq * 4 + r4;
            float s = 0.f;
#pragma unroll
            for (int j = 0; j < 4; j++) {
                float e = __expf(acc[i][j][r4] * RSQRT_DH);
                Ez[(size_t)gm * NT + n0 + wn + j * 16 + lr] = __float2bfloat16(e);
                s += e;
            }
            if (STATS) {
                for (int off = 1; off < 16; off <<= 1) s += __shfl_xor(s, off);
                if (lr == 0) sSum[w][i * 16 + lq * 4 + r4] = s;
            }
        }
    if (STATS) {
        __syncthreads();
        if (tid < 128) {
            int lidx = tid & 63, wb = tid >> 6;
            stat[((size_t)z * NT + m0 + tid) * 12 + blockIdx.x] = sSum[wb][lidx] + sSum[wb + 2][lidx];
        }
    }
}

// qkv = (emb + t*wt + bt) @ in_w^T + in_b -> QKB bf16 (Q|K), VtB bf16 transposed
__global__ __launch_bounds__(256) void k_qkv(
    const float* __restrict__ emb, const float* __restrict__ t,
    const float* __restrict__ wt, const float* __restrict__ bt,
    const float* __restrict__ in_b, float* ws)
{
    bf16* bp = (bf16*)(ws + BF_BASE);
    int m0 = blockIdx.y * 64, n0 = blockIdx.x * 64;
    __shared__ __bf16 As[64 * 40];
    __shared__ __bf16 Bs[64 * 40];
    int tid = threadIdx.x;
    int r = tid >> 2, quad = tid & 3;
    int w = tid >> 6, lane = tid & 63;
    int wm = (w & 1) * 32, wn = (w >> 1) * 32;
    int lr = lane & 15, lq = lane >> 4;
    f32x4 acc[2][2];
#pragma unroll
    for (int i = 0; i < 2; i++)
#pragma unroll
        for (int j = 0; j < 2; j++) acc[i][j] = (f32x4){0.f, 0.f, 0.f, 0.f};

    float trow = t[m0 + r];
    const float* arow = emb + (size_t)(m0 + r) * DD + quad * 8;
    const __bf16* brow = (const __bf16*)(bp + BINW) + (size_t)(n0 + r) * 512 + quad * 8;
    __bf16* awr = &As[r * 40 + quad * 8];
    __bf16* bwr = &Bs[r * 40 + quad * 8];

    for (int k0 = 0; k0 < DD; k0 += 32) {
        __bf16 ta[8] __attribute__((aligned(16)));
#pragma unroll
        for (int q = 0; q < 4; q++) {
            float2 e = *(const float2*)(arow + k0 + 2 * q);
            float2 wv = *(const float2*)(wt + k0 + quad * 8 + 2 * q);
            float2 bv = *(const float2*)(bt + k0 + quad * 8 + 2 * q);
            ta[2 * q]     = (__bf16)(e.x + trow * wv.x + bv.x);
            ta[2 * q + 1] = (__bf16)(e.y + trow * wv.y + bv.y);
        }
        uint4 bbv = *(const uint4*)(brow + k0);
        __syncthreads();
        *(bf16x8*)awr = *(bf16x8*)ta;
        *(uint4*)bwr = bbv;
        __syncthreads();
        bf16x8 af[2], bfr[2];
#pragma unroll
        for (int i = 0; i < 2; i++) af[i] = *(bf16x8*)&As[(wm + i * 16 + lr) * 40 + lq * 8];
#pragma unroll
        for (int j = 0; j < 2; j++) bfr[j] = *(bf16x8*)&Bs[(wn + j * 16 + lr) * 40 + lq * 8];
#pragma unroll
        for (int i = 0; i < 2; i++)
#pragma unroll
            for (int j = 0; j < 2; j++)
                acc[i][j] = __builtin_amdgcn_mfma_f32_16x16x32_bf16(af[i], bfr[j], acc[i][j], 0, 0, 0);
    }
    bf16* QKB = bp + BQKB;
    bf16* VtB = bp + BVT;
#pragma unroll
    for (int i = 0; i < 2; i++)
#pragma unroll
        for (int j = 0; j < 2; j++) {
            int gn = n0 + wn + j * 16 + lr;
            int gmb = m0 + wm + i * 16 + lq * 4;
            float b = in_b[gn];
            if (gn < 2 * DD) {
#pragma unroll
                for (int r4 = 0; r4 < 4; r4++)
                    QKB[(size_t)(gmb + r4) * 1024 + gn] = __float2bfloat16(acc[i][j][r4] + b);
            } else {
                union { uint2 u; unsigned short us[4]; } o;
#pragma unroll
                for (int r4 = 0; r4 < 4; r4++) {
                    bf16 t2 = __float2bfloat16(acc[i][j][r4] + b);
                    o.us[r4] = *(unsigned short*)&t2;
                }
                *(uint2*)&VtB[(size_t)(gn - 2 * DD) * NT + gmb] = o.u;
            }
        }
}

// P@V: 64m x 128n tiles, split-K=2 disjoint partials, E staged by copy, den from stats
__global__ __launch_bounds__(256) void k_pv(const bf16* __restrict__ E, float* ws) {
    bf16* bp = (bf16*)(ws + BF_BASE);
    int h = blockIdx.z;
    int m0 = blockIdx.y * 64;
    int ks = blockIdx.x;
    const int KCH = NT / 2;
    int kbeg = ks * KCH;
    __shared__ __bf16 As[64 * 40];
    __shared__ __bf16 Bs[128 * 40];
    __shared__ float sI[64];
    int tid = threadIdx.x;
    if (tid < 64) {
        const float* st = ws + OFF_STAT + (size_t)(h * NT + m0 + tid) * 12;
        float den = 0.f;
#pragma unroll
        for (int t2 = 0; t2 < 12; t2++) den += st[t2];
        sI[tid] = 1.f / den;
    }
    int rA = tid >> 2, quadA = tid & 3;
    int rB = tid >> 1, hhB = tid & 1;
    int w = tid >> 6, lane = tid & 63;
    int wm = (w & 1) * 32, wn = (w >> 1) * 64;
    int lr = lane & 15, lq = lane >> 4;
    const __bf16* Eh = (const __bf16*)E + (size_t)h * NT * NT;
    const __bf16* arow = Eh + (size_t)(m0 + rA) * NT + quadA * 8;
    const __bf16* brow = (const __bf16*)(bp + BVT) + ((size_t)h * 128 + rB) * NT + hhB * 16;
    __bf16* awr = &As[rA * 40 + quadA * 8];
    __bf16* bwr = &Bs[rB * 40 + hhB * 16];
    f32x4 acc[2][4];
#pragma unroll
    for (int i = 0; i < 2; i++)
#pragma unroll
        for (int j = 0; j < 4; j++) acc[i][j] = (f32x4){0.f, 0.f, 0.f, 0.f};

    for (int k0 = kbeg; k0 < kbeg + KCH; k0 += 32) {
        uint4 av = *(const uint4*)(arow + k0);
        uint4 b0 = *(const uint4*)(brow + k0);
        uint4 b1 = *(const uint4*)(brow + k0 + 8);
        __syncthreads();
        *(uint4*)awr = av;
        *(uint4*)bwr = b0; *(uint4*)(bwr + 8) = b1;
        __syncthreads();
        bf16x8 af[2], bfr[4];
#pragma unroll
        for (int i = 0; i < 2; i++) af[i] = *(bf16x8*)&As[(wm + i * 16 + lr) * 40 + lq * 8];
#pragma unroll
        for (int j = 0; j < 4; j++) bfr[j] = *(bf16x8*)&Bs[(wn + j * 16 + lr) * 40 + lq * 8];
#pragma unroll
        for (int i = 0; i < 2; i++)
#pragma unroll
            for (int j = 0; j < 4; j++)
                acc[i][j] = __builtin_amdgcn_mfma_f32_16x16x32_bf16(af[i], bfr[j], acc[i][j], 0, 0, 0);
    }
    float* dst = ws + (ks == 0 ? OFF_CTX : OFF_CTX1);
#pragma unroll
    for (int i = 0; i < 2; i++)
#pragma unroll
        for (int r4 = 0; r4 < 4; r4++) {
            int lrow = wm + i * 16 + lq * 4 + r4;
            float ri = sI[lrow];
#pragma unroll
            for (int j = 0; j < 4; j++) {
                int gn = wn + j * 16 + lr;
                dst[(size_t)(m0 + lrow) * DD + h * DHD + gn] = acc[i][j][r4] * ri;
            }
        }
}

// attn_out = (ctx0+ctx1) @ out_w^T + out_b -> att fp32 + attB bf16, + fused pooling
__global__ __launch_bounds__(256) void k_oproj(const float* __restrict__ out_b, float* ws) {
    bf16* bp = (bf16*)(ws + BF_BASE);
    int m0 = blockIdx.y * 64, n0 = blockIdx.x * 64;
    __shared__ __bf16 As[64 * 40];
    __shared__ __bf16 Bs[64 * 40];
    __shared__ float ps[64];
    int tid = threadIdx.x;
    int r = tid >> 2, quad = tid & 3;
    int w = tid >> 6, lane = tid & 63;
    int wm = (w & 1) * 32, wn = (w >> 1) * 32;
    int lr = lane & 15, lq = lane >> 4;
    f32x4 acc[2][2];
#pragma unroll
    for (int i = 0; i < 2; i++)
#pragma unroll
        for (int j = 0; j < 2; j++) acc[i][j] = (f32x4){0.f, 0.f, 0.f, 0.f};
    if (tid < 64) ps[tid] = 0.f;

    const float* a0 = ws + OFF_CTX  + (size_t)(m0 + r) * DD + quad * 8;
    const float* a1 = ws + OFF_CTX1 + (size_t)(m0 + r) * DD + quad * 8;
    const __bf16* brow = (const __bf16*)(bp + BOUTW) + (size_t)(n0 + r) * 512 + quad * 8;
    __bf16* awr = &As[r * 40 + quad * 8];
    __bf16* bwr = &Bs[r * 40 + quad * 8];

    for (int k0 = 0; k0 < DD; k0 += 32) {
        __bf16 ta[8] __attribute__((aligned(16)));
#pragma unroll
        for (int q = 0; q < 4; q++) {
            float2 x = *(const float2*)(a0 + k0 + 2 * q);
            float2 y = *(const float2*)(a1 + k0 + 2 * q);
            ta[2 * q]     = (__bf16)(x.x + y.x);
            ta[2 * q + 1] = (__bf16)(x.y + y.y);
        }
        uint4 bbv = *(const uint4*)(brow + k0);
        __syncthreads();
        *(bf16x8*)awr = *(bf16x8*)ta;
        *(uint4*)bwr = bbv;
        __syncthreads();
        bf16x8 af[2], bfr[2];
#pragma unroll
        for (int i = 0; i < 2; i++) af[i] = *(bf16x8*)&As[(wm + i * 16 + lr) * 40 + lq * 8];
#pragma unroll
        for (int j = 0; j < 2; j++) bfr[j] = *(bf16x8*)&Bs[(wn + j * 16 + lr) * 40 + lq * 8];
#pragma unroll
        for (int i = 0; i < 2; i++)
#pragma unroll
            for (int j = 0; j < 2; j++)
                acc[i][j] = __builtin_amdgcn_mfma_f32_16x16x32_bf16(af[i], bfr[j], acc[i][j], 0, 0, 0);
    }
    float* att = ws + OFF_ATT;
    bf16* attB = bp + BATT;
#pragma unroll
    for (int j = 0; j < 2; j++) {
        int gn = n0 + wn + j * 16 + lr;
        float b = out_b[gn];
        float colsum = 0.f;
#pragma unroll
        for (int i = 0; i < 2; i++)
#pragma unroll
            for (int r4 = 0; r4 < 4; r4++) {
                int gm = m0 + wm + i * 16 + lq * 4 + r4;
                float v = acc[i][j][r4] + b;
                att[(size_t)gm * DD + gn] = v;
                attB[(size_t)gm * 512 + gn] = __float2bfloat16(v);
                colsum += v;
            }
        atomicAdd(&ps[wn + j * 16 + lr], colsum);
    }
    __syncthreads();
    if (tid < 64) atomicAdd(&ws[OFF_POOL + n0 + tid], ps[tid]);
}

// triple GEMM A=attB: K2B (0-7) | Q0B (8-15) | H0 fp32 (16-21) + head block (22)
__global__ __launch_bounds__(256) void k_trip(
    const float* __restrict__ in_b, const float* __restrict__ ref_b1,
    const float* __restrict__ icw1, const float* __restrict__ icb1,
    const float* __restrict__ icw2, const float* __restrict__ icb2,
    float* ws, float* out)
{
    bf16* bp = (bf16*)(ws + BF_BASE);
    __shared__ __bf16 As[64 * 40];
    __shared__ __bf16 Bs[64 * 40];
    __shared__ float h1[128];
    __shared__ float lg[MAXI];
    int bx = blockIdx.x, tid = threadIdx.x;
    if (bx == 22) {
        if (blockIdx.y != 0) return;
        int w = tid >> 6, lane = tid & 63;
        const float* pp = ws + OFF_POOL + lane * 8;
        float4 p0 = *(const float4*)pp, p1 = *(const float4*)(pp + 4);
        float p8[8] = {p0.x, p0.y, p0.z, p0.w, p1.x, p1.y, p1.z, p1.w};
        for (int t = 0; t < 32; t++) {
            int row = w * 32 + t;
            const float* wr = icw1 + (size_t)row * DD + lane * 8;
            float4 a = *(const float4*)wr, b = *(const float4*)(wr + 4);
            float d = a.x * p8[0] + a.y * p8[1] + a.z * p8[2] + a.w * p8[3]
                    + b.x * p8[4] + b.y * p8[5] + b.z * p8[6] + b.w * p8[7];
            for (int off = 32; off; off >>= 1) d += __shfl_xor(d, off);
            if (lane == 0) h1[row] = fmaxf(d * (1.0f / NT) + icb1[row], 0.f);
        }
        __syncthreads();
        if (tid < MAXI) {
            float s = icb2[tid];
            for (int j = 0; j < 128; j++) s += icw2[tid * 128 + j] * h1[j];
            lg[tid] = s;
        }
        __syncthreads();
        if (tid == 0) {
            int best = 0; float bv = lg[0];
            for (int m = 1; m < MAXI; m++) if (lg[m] > bv) { bv = lg[m]; best = m; }
            int ni = best + 1;
            for (int i = 0; i < MAXI; i++) out[10 + i] = (i < ni) ? 1.f : 0.f;
        }
        return;
    }
    const __bf16* B; const float* bias; int n0, mode;
    bf16* Cb = nullptr; float* Cf = nullptr;
    if (bx < 8)       { B = (const __bf16*)(bp + BINW) + (size_t)512 * 512; bias = in_b + DD;     Cb = bp + BK2; n0 = bx * 64; mode = 0; }
    else if (bx < 16) { B = (const __bf16*)(bp + BM2);                      bias = ws + OFF_B2;   Cb = bp + BQ0; n0 = (bx - 8) * 64; mode = 0; }
    else              { B = (const __bf16*)(bp + BRW1);                     bias = ref_b1;        Cf = ws + OFF_H0; n0 = (bx - 16) * 64; mode = 1; }
    int m0 = blockIdx.y * 64;
    int r = tid >> 2, quad = tid & 3;
    int w = tid >> 6, lane = tid & 63;
    int wm = (w & 1) * 32, wn = (w >> 1) * 32;
    int lr = lane & 15, lq = lane >> 4;
    f32x4 acc[2][2];
#pragma unroll
    for (int i = 0; i < 2; i++)
#pragma unroll
        for (int j = 0; j < 2; j++) acc[i][j] = (f32x4){0.f, 0.f, 0.f, 0.f};

    const __bf16* arow = (const __bf16*)(bp + BATT) + (size_t)(m0 + r) * 512 + quad * 8;
    const __bf16* brow = B + (size_t)(n0 + r) * 512 + quad * 8;
    __bf16* awr = &As[r * 40 + quad * 8];
    __bf16* bwr = &Bs[r * 40 + quad * 8];

    for (int k0 = 0; k0 < DD; k0 += 32) {
        uint4 av = *(const uint4*)(arow + k0);
        uint4 bv = *(const uint4*)(brow + k0);
        __syncthreads();
        *(uint4*)awr = av;
        *(uint4*)bwr = bv;
        __syncthreads();
        bf16x8 af[2], bfr[2];
#pragma unroll
        for (int i = 0; i < 2; i++) af[i] = *(bf16x8*)&As[(wm + i * 16 + lr) * 40 + lq * 8];
#pragma unroll
        for (int j = 0; j < 2; j++) bfr[j] = *(bf16x8*)&Bs[(wn + j * 16 + lr) * 40 + lq * 8];
#pragma unroll
        for (int i = 0; i < 2; i++)
#pragma unroll
            for (int j = 0; j < 2; j++)
                acc[i][j] = __builtin_amdgcn_mfma_f32_16x16x32_bf16(af[i], bfr[j], acc[i][j], 0, 0, 0);
    }
#pragma unroll
    for (int i = 0; i < 2; i++)
#pragma unroll
        for (int r4 = 0; r4 < 4; r4++) {
            int gm = m0 + wm + i * 16 + lq * 4 + r4;
#pragma unroll
            for (int j = 0; j < 2; j++) {
                int gn = n0 + wn + j * 16 + lr;
                float v = acc[i][j][r4] + bias[gn];
                if (mode == 0) Cb[(size_t)gm * 512 + gn] = __float2bfloat16(v);
                else           Cf[(size_t)gm * 384 + gn] = v;
            }
        }
}

// per row: A/B dots from K2B
__global__ __launch_bounds__(256) void k_abc(float* ws) {
    bf16* bp = (bf16*)(ws + BF_BASE);
    int wave = threadIdx.x >> 6, lane = threadIdx.x & 63;
    int row = blockIdx.x * 4 + wave;
    int h = row / NT, n = row % NT;
    const unsigned short* k2 = (const unsigned short*)(bp + BK2 + (size_t)n * 512 + h * DHD);
    const float* av = ws + OFF_AV + h * DHD;
    const float* bv = ws + OFF_BV + h * DHD;
    int d = lane * 2;
    float k0 = __uint_as_float((unsigned)k2[d] << 16);
    float k1 = __uint_as_float((unsigned)k2[d + 1] << 16);
    float a = av[d] * k0 + av[d + 1] * k1;
    float b = bv[d] * k0 + bv[d + 1] * k1;
    for (int off = 32; off; off >>= 1) { a += __shfl_xor(a, off); b += __shfl_xor(b, off); }
    if (lane == 0) { ws[OFF_AARR + row] = a * RSQRT_DH; ws[OFF_BARR + row] = b * RSQRT_DH; }
}

// fused: logits = relu(H0+delta)@rw2B^T + b2 in LDS, then softdot -> so/eo
__global__ __launch_bounds__(256) void k_lgs(
    const float* __restrict__ rw1, const float* __restrict__ rb2,
    const float* __restrict__ wp, int l, float* ws)
{
    bf16* bp = (bf16*)(ws + BF_BASE);
    __shared__ float dsh[128];
    __shared__ __bf16 As[64 * 136];
    __shared__ __bf16 Bs[64 * 136];
    __shared__ __bf16 Ls[64 * 208];
    int tid = threadIdx.x;
    int m0 = blockIdx.x * 64;
    int i_int = m0 / NT;
    int nbase = m0 % NT;
    if (blockIdx.x == 0 && tid < 11) ws[OFF_SCAL + SC_DSDE + tid] = 0.f;
    if (tid < 128) {
        float s_i = ws[OFF_SCAL + SC_START + i_int], e_i = ws[OFF_SCAL + SC_END + i_int];
        const float* wr = rw1 + (size_t)(l * 128 + tid) * 514;
        dsh[tid] = s_i * wr[512] + e_i * wr[513];
    }
    __syncthreads();
    int r = tid >> 2, quad = tid & 3;
    {
        const float* arow = ws + OFF_H0 + (size_t)(nbase + r) * 384 + l * 128 + quad * 32;
        __bf16 tmp[32] __attribute__((aligned(16)));
#pragma unroll
        for (int q = 0; q < 16; q++) {
            float2 f = *(const float2*)(arow + 2 * q);
            int jj = quad * 32 + 2 * q;
            tmp[2 * q]     = (__bf16)fmaxf(f.x + dsh[jj], 0.f);
            tmp[2 * q + 1] = (__bf16)fmaxf(f.y + dsh[jj + 1], 0.f);
        }
        __bf16* aw = &As[r * 136 + quad * 32];
#pragma unroll
        for (int q = 0; q < 4; q++) *(bf16x8*)(aw + q * 8) = *(bf16x8*)(tmp + q * 8);
    }
    int w = tid >> 6, lane = tid & 63;
    int wm = (w & 1) * 32, wn = (w >> 1) * 32;
    int lr = lane & 15, lq = lane >> 4;
    const __bf16* rw2b = (const __bf16*)(bp + BRW2) + (size_t)l * 200 * 128;
    for (int nt = 0; nt < 4; nt++) {
        int n0 = nt * 64;
        int gnr = n0 + r;
        uint4 b0 = {0, 0, 0, 0}, b1 = {0, 0, 0, 0}, b2v = {0, 0, 0, 0}, b3 = {0, 0, 0, 0};
        if (gnr < 200) {
            const __bf16* brow = rw2b + (size_t)gnr * 128 + quad * 32;
            b0 = *(const uint4*)brow; b1 = *(const uint4*)(brow + 8);
            b2v = *(const uint4*)(brow + 16); b3 = *(const uint4*)(brow + 24);
        }
        __syncthreads();
        {
            __bf16* bw = &Bs[r * 136 + quad * 32];
            *(uint4*)bw = b0; *(uint4*)(bw + 8) = b1;
            *(uint4*)(bw + 16) = b2v; *(uint4*)(bw + 24) = b3;
        }
        __syncthreads();
        f32x4 acc[2][2];
#pragma unroll
        for (int i = 0; i < 2; i++)
#pragma unroll
            for (int j = 0; j < 2; j++) acc[i][j] = (f32x4){0.f, 0.f, 0.f, 0.f};
#pragma unroll
        for (int kk = 0; kk < 4; kk++) {
            bf16x8 af[2], bfr[2];
#pragma unroll
            for (int i = 0; i < 2; i++) af[i] = *(bf16x8*)&As[(wm + i * 16 + lr) * 136 + kk * 32 + lq * 8];
#pragma unroll
            for (int j = 0; j < 2; j++) bfr[j] = *(bf16x8*)&Bs[(wn + j * 16 + lr) * 136 + kk * 32 + lq * 8];
#pragma unroll
            for (int i = 0; i < 2; i++)
#pragma unroll
                for (int j = 0; j < 2; j++)
                    acc[i][j] = __builtin_amdgcn_mfma_f32_16x16x32_bf16(af[i], bfr[j], acc[i][j], 0, 0, 0);
        }
#pragma unroll
        for (int i = 0; i < 2; i++)
#pragma unroll
            for (int r4 = 0; r4 < 4; r4++) {
                int rl = wm + i * 16 + lq * 4 + r4;
#pragma unroll
                for (int j = 0; j < 2; j++) {
                    int gn = n0 + wn + j * 16 + lr;
                    if (gn < 200) Ls[rl * 208 + gn] = (__bf16)(acc[i][j][r4] + rb2[gn]);
                }
            }
    }
    __syncthreads();
    {
        int rloc = tid >> 2, q = tid & 3;
        int c0 = q * 50;
        const unsigned short* lrow = (const unsigned short*)&Ls[rloc * 208];
        float m = -1e30f;
#pragma unroll
        for (int c = 0; c < 50; c++)
            m = fmaxf(m, __uint_as_float((unsigned)lrow[c0 + c] << 16));
        m = fmaxf(m, __shfl_xor(m, 1));
        float den = 0.f, num = 0.f;
#pragma unroll
        for (int c = 0; c < 50; c++) {
            float p = __expf(__uint_as_float((unsigned)lrow[c0 + c] << 16) - m);
            den += p;
            int wc = c0 + c; if (wc >= NBINS) wc -= NBINS;
            num += p * wp[wc];
        }
        den += __shfl_xor(den, 1);
        num += __shfl_xor(num, 1);
        int n = nbase + rloc;
        if (q == 0)      ws[OFF_SOFF + (size_t)i_int * NT + n] = num / den;
        else if (q == 2) ws[OFF_EOFF + (size_t)i_int * NT + n] = num / den;
    }
}

// P_ks = E0 @ U^T, E0 staged by pure copy, U computed on the fly in B-staging
__global__ __launch_bounds__(256) void k_eg(const bf16* __restrict__ E0, float* ws) {
    int h = blockIdx.z;
    int m0 = blockIdx.y * 128;
    int ks = blockIdx.x;
    const int KCH = NT / 8;
    __shared__ __bf16 As[128 * 40];
    __shared__ __bf16 Bs[16 * 40];
    int tid = threadIdx.x;
    int w = tid >> 6, lane = tid & 63;
    int lr = lane & 15, lq = lane >> 4;
    int r = tid >> 1, half = tid & 1;
    const unsigned short* arow =
        (const unsigned short*)((const __bf16*)E0 + (size_t)h * NT * NT + (size_t)(m0 + r) * NT) + half * 16;
    int wm = w * 32;
    f32x4 acc[2];
    acc[0] = (f32x4){0.f, 0.f, 0.f, 0.f};
    acc[1] = (f32x4){0.f, 0.f, 0.f, 0.f};
    int bc = tid >> 3, bk = tid & 7;
    int valid = (tid < 128) && (bc < 15);
    int ii = bc / 3, tt = bc - ii * 3;
    if (ii > 4) ii = 4;
    float s_i = 0.f, e_i = 0.f;
    if (valid) { s_i = ws[OFF_SCAL + SC_START + ii]; e_i = ws[OFF_SCAL + SC_END + ii]; }
    const float* Ar = ws + OFF_AARR + h * NT;
    const float* Br = ws + OFF_BARR + h * NT;
    const float* fo = ws + (tt == 2 ? OFF_EOFF : OFF_SOFF) + (size_t)ii * NT;

    for (int k0 = ks * KCH; k0 < ks * KCH + KCH; k0 += 32) {
        uint4 a0 = *(const uint4*)(arow + k0);
        uint4 a1 = *(const uint4*)(arow + k0 + 8);
        float bv[4] = {0.f, 0.f, 0.f, 0.f};
        if (valid) {
            float4 a4 = *(const float4*)(Ar + k0 + bk * 4);
            float4 b4 = *(const float4*)(Br + k0 + bk * 4);
            bv[0] = __expf(s_i * a4.x + e_i * b4.x);
            bv[1] = __expf(s_i * a4.y + e_i * b4.y);
            bv[2] = __expf(s_i * a4.z + e_i * b4.z);
            bv[3] = __expf(s_i * a4.w + e_i * b4.w);
            if (tt) {
                float4 f4 = *(const float4*)(fo + k0 + bk * 4);
                bv[0] *= f4.x; bv[1] *= f4.y; bv[2] *= f4.z; bv[3] *= f4.w;
            }
        }
        __syncthreads();
        *(uint4*)&As[r * 40 + half * 16] = a0;
        *(uint4*)&As[r * 40 + half * 16 + 8] = a1;
        if (tid < 128) {
            __bf16* bw = &Bs[bc * 40 + bk * 4];
            bw[0] = (__bf16)bv[0]; bw[1] = (__bf16)bv[1]; bw[2] = (__bf16)bv[2]; bw[3] = (__bf16)bv[3];
        }
        __syncthreads();
        bf16x8 bf0 = *(bf16x8*)&Bs[lr * 40 + lq * 8];
        bf16x8 af0 = *(bf16x8*)&As[(wm + lr) * 40 + lq * 8];
        bf16x8 af1 = *(bf16x8*)&As[(wm + 16 + lr) * 40 + lq * 8];
        acc[0] = __builtin_amdgcn_mfma_f32_16x16x32_bf16(af0, bf0, acc[0], 0, 0, 0);
        acc[1] = __builtin_amdgcn_mfma_f32_16x16x32_bf16(af1, bf0, acc[1], 0, 0, 0);
    }
    float* P = ws + OFF_LG + (size_t)ks * PSLICE;
    if (lr < 15) {
#pragma unroll
        for (int i = 0; i < 2; i++)
#pragma unroll
            for (int r4 = 0; r4 < 4; r4++) {
                int gm = m0 + wm + i * 16 + lq * 4 + r4;
                P[(size_t)(h * NT + gm) * 16 + lr] = acc[i][r4];
            }
    }
}

// sum 8 slices, ratios, reduce; last block applies update (+ writes out on last layer)
__global__ __launch_bounds__(256) void k_fin(float* ws, float* out, int l) {
    __shared__ float part[4][10];
    int tid = threadIdx.x;
    int w = tid >> 6, lane = tid & 63;
    int row = blockIdx.x * 256 + tid;
    float acc[15];
#pragma unroll
    for (int c = 0; c < 15; c++) acc[c] = 0.f;
    for (int ks = 0; ks < 8; ks++) {
        const float* Pr = ws + OFF_LG + (size_t)ks * PSLICE + (size_t)row * 16;
#pragma unroll
        for (int c = 0; c < 15; c++) acc[c] += Pr[c];
    }
    float loc[10];
#pragma unroll
    for (int i = 0; i < MAXI; i++) {
        float den = acc[i * 3];
        loc[i]        = acc[i * 3 + 1] / den;
        loc[MAXI + i] = acc[i * 3 + 2] / den;
    }
#pragma unroll
    for (int c = 0; c < 10; c++)
        for (int off = 32; off; off >>= 1) loc[c] += __shfl_xor(loc[c], off);
    if (lane == 0) {
#pragma unroll
        for (int c = 0; c < 10; c++) part[w][c] = loc[c];
    }
    __syncthreads();
    if (tid < 10) {
        float s = part[0][tid] + part[1][tid] + part[2][tid] + part[3][tid];
        atomicAdd(&ws[OFF_SCAL + SC_DSDE + tid], s);
    }
    __threadfence();
    __syncthreads();
    if (tid == 0) {
        unsigned old = atomicAdd((unsigned*)&ws[OFF_SCAL + SC_CNT], 1u);
        if (old == 23) {
            for (int i = 0; i < MAXI; i++) {
                float ds = atomicAdd(&ws[OFF_SCAL + SC_DSDE + i], 0.f);
                float de = atomicAdd(&ws[OFF_SCAL + SC_DSDE + MAXI + i], 0.f);
                float ns = ws[OFF_SCAL + SC_START + i] + ds * 0.25f;   // 1/H
                float ne = ws[OFF_SCAL + SC_END + i]   + de * 0.25f;
                ws[OFF_SCAL + SC_START + i] = ns;
                ws[OFF_SCAL + SC_END + i]   = ne;
                if (l == NL - 1) { out[2 * i] = ns; out[2 * i + 1] = ne; }
            }
        }
    }
}

// -------------------------------------------------------------------------
extern "C" void kernel_launch(void* const* d_in, const int* in_sizes, int n_in,
                              void* d_out, int out_size, void* d_ws, size_t ws_size,
                              hipStream_t stream) {
    const float* emb    = (const float*)d_in[0];
    const float* tpos   = (const float*)d_in[1];
    const float* W_time = (const float*)d_in[3];
    const float* b_time = (const float*)d_in[4];
    const float* in_w   = (const float*)d_in[5];
    const float* in_b   = (const float*)d_in[6];
    const float* out_w  = (const float*)d_in[7];
    const float* out_b  = (const float*)d_in[8];
    const float* ic_w1  = (const float*)d_in[9];
    const float* ic_b1  = (const float*)d_in[10];
    const float* ic_w2  = (const float*)d_in[11];
    const float* ic_b2  = (const float*)d_in[12];
    const float* ref_w1 = (const float*)d_in[13];
    const float* ref_b1 = (const float*)d_in[14];
    const float* ref_w2 = (const float*)d_in[15];
    const float* ref_b2 = (const float*)d_in[16];
    const float* wp     = (const float*)d_in[17];
    const float* qp_w   = (const float*)d_in[18];
    const float* qp_b   = (const float*)d_in[19];
    float* ws  = (float*)d_ws;
    float* out = (float*)d_out;
    bf16* E = (bf16*)(ws + OFF_E);
    bf16* bp = (bf16*)(ws + BF_BASE);

    // prologue: M2B | uv | pre | weight-to-bf16 converts
    k_misc<<<98, 256, 0, stream>>>(tpos, in_w, in_b, out_w, ref_w1, ref_w2, qp_w, qp_b, ws);

    // qkv (+x fusion) -> QKB bf16, VtB bf16
    k_qkv<<<dim3(24, 24), 256, 0, stream>>>(emb, tpos, W_time, b_time, in_b, ws);
    // E1 = exp(QK^T/sqrt(dh)) + per-tile expsums
    k_score<1><<<dim3(12, 12, NH), 256, 0, stream>>>(
        bp + BQKB, 1024, DHD, bp + BQKB + 512, 1024, DHD, E, ws + OFF_STAT);
    k_pv<<<dim3(2, NT / 64, NH), 256, 0, stream>>>(E, ws);
    k_oproj<<<dim3(8, 24), 256, 0, stream>>>(out_b, ws);

    // K2B | Q0B | H0 | head
    k_trip<<<dim3(23, 24), 256, 0, stream>>>(in_b, ref_b1, ic_w1, ic_b1, ic_w2, ic_b2, ws, out);

    // E0 = exp(Q0 K2^T / sqrt(dh)) (no stats needed)
    k_score<0><<<dim3(12, 12, NH), 256, 0, stream>>>(
        bp + BQ0, 512, DHD, bp + BK2, 512, DHD, E, nullptr);
    k_abc<<<NH * NT / 4, 256, 0, stream>>>(ws);

    for (int l = 0; l < NL; l++) {
        k_lgs<<<120, 256, 0, stream>>>(ref_w1, ref_b2 + l * 200, wp, l, ws);
        k_eg<<<dim3(8, NT / 128, NH), 256, 0, stream>>>(E, ws);
        k_fin<<<NH * NT / 256, 256, 0, stream>>>(ws, out, l);
    }
}